// Round 1
// baseline (5917.865 us; speedup 1.0000x reference)
//
#include <hip/hip_runtime.h>
#include <math.h>

#define BB 2
#define SS 4096
#define DD 768
#define HH 12
#define DHH 64
#define WW 256
#define CC 16
#define FF 3072
#define SCALE 0.125f

__device__ __forceinline__ float gelu_f(float x) {
    float x3 = x * x * x;
    return 0.5f * x * (1.0f + tanhf(0.7978845608028654f * (x + 0.044715f * x3)));
}

// ---------------- embedding + LayerNorm ----------------
__global__ __launch_bounds__(256) void embed_ln_k(const int* __restrict__ ids,
        const float* __restrict__ wemb, const float* __restrict__ pemb,
        const float* __restrict__ g, const float* __restrict__ bta,
        float* __restrict__ x)
{
    int row = blockIdx.x;            // b*SS + s
    int s = row & (SS - 1);
    int tid = threadIdx.x;
    __shared__ float r1[256], r2[256];
    const float* we = wemb + (size_t)ids[row] * DD;
    const float* pe = pemb + (size_t)s * DD;
    float v[3]; float sum = 0.f, sq = 0.f;
#pragma unroll
    for (int i = 0; i < 3; i++) {
        int c = tid + i * 256;
        v[i] = we[c] + pe[c];
        sum += v[i]; sq += v[i] * v[i];
    }
    r1[tid] = sum; r2[tid] = sq; __syncthreads();
    for (int o = 128; o > 0; o >>= 1) {
        if (tid < o) { r1[tid] += r1[tid + o]; r2[tid] += r2[tid + o]; }
        __syncthreads();
    }
    float mean = r1[0] * (1.f / DD);
    float var = r2[0] * (1.f / DD) - mean * mean;
    float rstd = rsqrtf(var + 1e-5f);
    float* xr = x + (size_t)row * DD;
#pragma unroll
    for (int i = 0; i < 3; i++) {
        int c = tid + i * 256;
        xr[c] = (v[i] - mean) * rstd * g[c] + bta[c];
    }
}

// ---------------- residual add + LayerNorm ----------------
__global__ __launch_bounds__(256) void add_ln_k(const float* __restrict__ xin,
        const float* __restrict__ hin, const float* __restrict__ g,
        const float* __restrict__ bta, float* __restrict__ xout)
{
    int row = blockIdx.x;
    int tid = threadIdx.x;
    __shared__ float r1[256], r2[256];
    const float* xr = xin + (size_t)row * DD;
    const float* hr = hin + (size_t)row * DD;
    float v[3]; float sum = 0.f, sq = 0.f;
#pragma unroll
    for (int i = 0; i < 3; i++) {
        int c = tid + i * 256;
        v[i] = xr[c] + hr[c];
        sum += v[i]; sq += v[i] * v[i];
    }
    r1[tid] = sum; r2[tid] = sq; __syncthreads();
    for (int o = 128; o > 0; o >>= 1) {
        if (tid < o) { r1[tid] += r1[tid + o]; r2[tid] += r2[tid + o]; }
        __syncthreads();
    }
    float mean = r1[0] * (1.f / DD);
    float var = r2[0] * (1.f / DD) - mean * mean;
    float rstd = rsqrtf(var + 1e-5f);
    float* orow = xout + (size_t)row * DD;
#pragma unroll
    for (int i = 0; i < 3; i++) {
        int c = tid + i * 256;
        orow[c] = (v[i] - mean) * rstd * g[c] + bta[c];
    }
}

// ---------------- generic tiled fp32 GEMM: C = A[M,K] @ W[K,N] + bias, opt gelu ----------------
__global__ __launch_bounds__(256) void gemm_bias_k(const float* __restrict__ A,
        const float* __restrict__ W, const float* __restrict__ bias,
        float* __restrict__ C, int M, int N, int K, int act)
{
    __shared__ float As[16][64];
    __shared__ float Bs[16][68];   // 68*4B = 272B rows, 16B-aligned for float4
    int tid = threadIdx.x;
    int tm = tid >> 4, tn = tid & 15;
    int bm = blockIdx.x * 64, bn = blockIdx.y * 64;
    int arow = tid >> 2;
    int akq = (tid & 3) << 2;
    int bk = tid >> 4;
    int bnq = (tid & 15) << 2;
    const float* Aptr = A + (size_t)(bm + arow) * K + akq;
    const float* Wptr = W + (size_t)bk * N + bn + bnq;
    float acc[4][4];
#pragma unroll
    for (int i = 0; i < 4; i++)
#pragma unroll
        for (int j = 0; j < 4; j++) acc[i][j] = 0.f;

    for (int k0 = 0; k0 < K; k0 += 16) {
        float4 a4 = *(const float4*)(Aptr + k0);
        float4 b4 = *(const float4*)(Wptr + (size_t)k0 * N);
        __syncthreads();
        As[akq + 0][arow] = a4.x;
        As[akq + 1][arow] = a4.y;
        As[akq + 2][arow] = a4.z;
        As[akq + 3][arow] = a4.w;
        *(float4*)&Bs[bk][bnq] = b4;
        __syncthreads();
#pragma unroll
        for (int kk = 0; kk < 16; kk++) {
            float4 av = *(const float4*)&As[kk][tm << 2];
            float4 bv = *(const float4*)&Bs[kk][tn << 2];
            float a_[4] = { av.x, av.y, av.z, av.w };
            float b_[4] = { bv.x, bv.y, bv.z, bv.w };
#pragma unroll
            for (int i = 0; i < 4; i++)
#pragma unroll
                for (int j = 0; j < 4; j++)
                    acc[i][j] = fmaf(a_[i], b_[j], acc[i][j]);
        }
    }
    int row0 = bm + (tm << 2), col0 = bn + (tn << 2);
    float4 bv4 = *(const float4*)&bias[col0];
    float bias_[4] = { bv4.x, bv4.y, bv4.z, bv4.w };
#pragma unroll
    for (int i = 0; i < 4; i++) {
        float o[4];
#pragma unroll
        for (int j = 0; j < 4; j++) o[j] = acc[i][j] + bias_[j];
        if (act == 1) {
#pragma unroll
            for (int j = 0; j < 4; j++) o[j] = gelu_f(o[j]);
        }
        float4 ov = { o[0], o[1], o[2], o[3] };
        *(float4*)&C[(size_t)(row0 + i) * N + col0] = ov;
    }
}

// ---------------- sliding-window attention (one block per b,h,chunk) ----------------
__global__ __launch_bounds__(256) void swin_attn_k(const float* __restrict__ Q,
        const float* __restrict__ K, const float* __restrict__ V,
        const int* __restrict__ mask, float* __restrict__ O)
{
    int c = blockIdx.x, h = blockIdx.y, b = blockIdx.z;
    int qi = threadIdx.x;                      // query index within chunk
    __shared__ float kb[64][64];
    __shared__ float vb[64][64];
    __shared__ float gk[64];
    __shared__ float gv[64];
    __shared__ int mv[64];
    size_t headoff = (size_t)h * DHH;
    const float* qrow = Q + ((size_t)(b * SS + c * WW + qi)) * DD + headoff;
    float qreg[64];
#pragma unroll
    for (int d4 = 0; d4 < 16; d4++) {
        float4 t = *(const float4*)(qrow + d4 * 4);
        qreg[d4 * 4 + 0] = t.x; qreg[d4 * 4 + 1] = t.y;
        qreg[d4 * 4 + 2] = t.z; qreg[d4 * 4 + 3] = t.w;
    }
    if (qi < 64)       gk[qi] = K[((size_t)b * SS) * DD + headoff + qi];
    else if (qi < 128) gv[qi - 64] = V[((size_t)b * SS) * DD + headoff + (qi - 64)];

    float m = -1e30f, l = 0.f;
    float acc[64];
#pragma unroll
    for (int d = 0; d < 64; d++) acc[d] = 0.f;

    int jrow = qi >> 2;
    int f4 = qi & 3;
    for (int t0 = 0; t0 < 3 * WW; t0 += 64) {
        __syncthreads();
        int kpos = c * WW - WW + t0 + jrow;
        bool inr = (kpos >= 0) && (kpos < SS);
        if (f4 == 0) mv[jrow] = (inr && mask[b * SS + kpos] > 0) ? 1 : 0;
        if (inr) {
            const float* kr = K + ((size_t)(b * SS + kpos)) * DD + headoff;
            const float* vr = V + ((size_t)(b * SS + kpos)) * DD + headoff;
#pragma unroll
            for (int u = 0; u < 4; u++) {
                int p = f4 + u * 4;
                *(float4*)&kb[jrow][p * 4] = *(const float4*)(kr + p * 4);
                *(float4*)&vb[jrow][p * 4] = *(const float4*)(vr + p * 4);
            }
        }
        __syncthreads();
        for (int j = 0; j < 64; j++) {
            int rel = t0 + j - WW - qi;          // key offset relative to query
            if (mv[j] && rel <= WW && rel >= -WW) {
                float s = 0.f;
#pragma unroll
                for (int d4 = 0; d4 < 16; d4++) {
                    float4 kv = *(const float4*)&kb[j][d4 * 4];
                    s = fmaf(qreg[d4 * 4 + 0], kv.x, s);
                    s = fmaf(qreg[d4 * 4 + 1], kv.y, s);
                    s = fmaf(qreg[d4 * 4 + 2], kv.z, s);
                    s = fmaf(qreg[d4 * 4 + 3], kv.w, s);
                }
                s *= SCALE;
                if (s <= m) {
                    float e = __expf(s - m);
                    l += e;
#pragma unroll
                    for (int d4 = 0; d4 < 16; d4++) {
                        float4 vv = *(const float4*)&vb[j][d4 * 4];
                        acc[d4 * 4 + 0] = fmaf(e, vv.x, acc[d4 * 4 + 0]);
                        acc[d4 * 4 + 1] = fmaf(e, vv.y, acc[d4 * 4 + 1]);
                        acc[d4 * 4 + 2] = fmaf(e, vv.z, acc[d4 * 4 + 2]);
                        acc[d4 * 4 + 3] = fmaf(e, vv.w, acc[d4 * 4 + 3]);
                    }
                } else {
                    float r = __expf(m - s);
                    m = s;
                    l = fmaf(l, r, 1.f);
#pragma unroll
                    for (int d4 = 0; d4 < 16; d4++) {
                        float4 vv = *(const float4*)&vb[j][d4 * 4];
                        acc[d4 * 4 + 0] = fmaf(acc[d4 * 4 + 0], r, vv.x);
                        acc[d4 * 4 + 1] = fmaf(acc[d4 * 4 + 1], r, vv.y);
                        acc[d4 * 4 + 2] = fmaf(acc[d4 * 4 + 2], r, vv.z);
                        acc[d4 * 4 + 3] = fmaf(acc[d4 * 4 + 3], r, vv.w);
                    }
                }
            }
        }
    }
    // global token (sequence position 0) — always attended, unmasked (matches reference)
    {
        float s = 0.f;
#pragma unroll
        for (int d = 0; d < 64; d++) s = fmaf(qreg[d], gk[d], s);
        s *= SCALE;
        if (s <= m) {
            float e = __expf(s - m);
            l += e;
#pragma unroll
            for (int d = 0; d < 64; d++) acc[d] = fmaf(e, gv[d], acc[d]);
        } else {
            float r = __expf(m - s);
            m = s;
            l = fmaf(l, r, 1.f);
#pragma unroll
            for (int d = 0; d < 64; d++) acc[d] = fmaf(acc[d], r, gv[d]);
        }
    }
    float inv = 1.f / l;
    float* orow = O + ((size_t)(b * SS + c * WW + qi)) * DD + headoff;
#pragma unroll
    for (int d4 = 0; d4 < 16; d4++) {
        float4 ov = { acc[d4 * 4 + 0] * inv, acc[d4 * 4 + 1] * inv,
                      acc[d4 * 4 + 2] * inv, acc[d4 * 4 + 3] * inv };
        *(float4*)(orow + d4 * 4) = ov;
    }
}

// ---------------- qg = x[:,0,:] @ Wqg + bqg  (M=2 tiny GEMM) ----------------
__global__ __launch_bounds__(64) void qg_k(const float* __restrict__ x,
        const float* __restrict__ Wg, const float* __restrict__ bg,
        float* __restrict__ qg)
{
    int b = blockIdx.y;
    int col = blockIdx.x * 64 + threadIdx.x;
    const float* xr = x + (size_t)b * SS * DD;
    float a = bg[col];
    for (int k2 = 0; k2 < DD; k2++)
        a = fmaf(xr[k2], Wg[(size_t)k2 * DD + col], a);
    qg[b * DD + col] = a;
}

// ---------------- global-token full attention; writes row 0 of O ----------------
__global__ __launch_bounds__(256) void gattn_k(const float* __restrict__ qg,
        const float* __restrict__ kg, const float* __restrict__ vg,
        const int* __restrict__ mask, float* __restrict__ O)
{
    int h = blockIdx.x, b = blockIdx.y;
    int tid = threadIdx.x;
    __shared__ float sc[SS];
    __shared__ float gq[64];
    __shared__ float red[256];
    __shared__ float ored[4][64];
    if (tid < 64) gq[tid] = qg[b * DD + h * DHH + tid];
    __syncthreads();
    float lmax = -1e30f;
    for (int s = tid; s < SS; s += 256) {
        const float* kr = kg + ((size_t)(b * SS + s)) * DD + h * DHH;
        float a = 0.f;
#pragma unroll
        for (int d4 = 0; d4 < 16; d4++) {
            float4 kv = *(const float4*)(kr + d4 * 4);
            a = fmaf(gq[d4 * 4 + 0], kv.x, a);
            a = fmaf(gq[d4 * 4 + 1], kv.y, a);
            a = fmaf(gq[d4 * 4 + 2], kv.z, a);
            a = fmaf(gq[d4 * 4 + 3], kv.w, a);
        }
        a *= SCALE;
        float sv = (mask[b * SS + s] > 0) ? a : -1e9f;
        sc[s] = sv;
        lmax = fmaxf(lmax, sv);
    }
    red[tid] = lmax; __syncthreads();
    for (int o = 128; o > 0; o >>= 1) {
        if (tid < o) red[tid] = fmaxf(red[tid], red[tid + o]);
        __syncthreads();
    }
    float mx = red[0]; __syncthreads();
    float lsum = 0.f;
    for (int s = tid; s < SS; s += 256) {
        float p = __expf(sc[s] - mx);
        sc[s] = p;
        lsum += p;
    }
    red[tid] = lsum; __syncthreads();
    for (int o = 128; o > 0; o >>= 1) {
        if (tid < o) red[tid] += red[tid + o];
        __syncthreads();
    }
    float denom = red[0];
    int d = tid & 63, grp = tid >> 6;
    float oa = 0.f;
    for (int s = grp; s < SS; s += 4)
        oa = fmaf(sc[s], vg[((size_t)(b * SS + s)) * DD + h * DHH + d], oa);
    ored[grp][d] = oa; __syncthreads();
    if (tid < 64) {
        float o = (ored[0][tid] + ored[1][tid] + ored[2][tid] + ored[3][tid]) / denom;
        O[((size_t)b * SS) * DD + h * DHH + tid] = o;
    }
}

// ---------------- pooler (tanh) + classifier ----------------
__global__ __launch_bounds__(256) void pooler_cls_k(const float* __restrict__ x,
        const float* __restrict__ Wp, const float* __restrict__ bp,
        const float* __restrict__ Wc, const float* __restrict__ bc,
        float* __restrict__ out)
{
    int b = blockIdx.x;
    int tid = threadIdx.x;
    __shared__ float pooled[DD];
    const float* xr = x + (size_t)b * SS * DD;     // CLS row
    for (int col = tid; col < DD; col += 256) {
        float a = bp[col];
        for (int k2 = 0; k2 < DD; k2++)
            a = fmaf(xr[k2], Wp[(size_t)k2 * DD + col], a);
        pooled[col] = tanhf(a);
    }
    __syncthreads();
    if (tid < 2) {
        float a = bc[tid];
        for (int k2 = 0; k2 < DD; k2++)
            a = fmaf(pooled[k2], Wc[k2 * 2 + tid], a);
        out[b * 2 + tid] = a;
    }
}

extern "C" void kernel_launch(void* const* d_in, const int* in_sizes, int n_in,
                              void* d_out, int out_size, void* d_ws, size_t ws_size,
                              hipStream_t stream) {
    const int*   input_ids = (const int*)d_in[0];
    const int*   amask     = (const int*)d_in[1];
    const float* word_emb  = (const float*)d_in[2];
    const float* pos_emb   = (const float*)d_in[3];
    const float* ln_e_g    = (const float*)d_in[4];
    const float* ln_e_b    = (const float*)d_in[5];
    const float* Wq  = (const float*)d_in[6];  const float* bq  = (const float*)d_in[7];
    const float* Wk  = (const float*)d_in[8];  const float* bk  = (const float*)d_in[9];
    const float* Wv  = (const float*)d_in[10]; const float* bv  = (const float*)d_in[11];
    const float* Wqg = (const float*)d_in[12]; const float* bqg = (const float*)d_in[13];
    const float* Wkg = (const float*)d_in[14]; const float* bkg = (const float*)d_in[15];
    const float* Wvg = (const float*)d_in[16]; const float* bvg = (const float*)d_in[17];
    const float* Wo  = (const float*)d_in[18]; const float* bo  = (const float*)d_in[19];
    const float* ln1_g = (const float*)d_in[20]; const float* ln1_b = (const float*)d_in[21];
    const float* W1  = (const float*)d_in[22]; const float* bf1 = (const float*)d_in[23];
    const float* W2  = (const float*)d_in[24]; const float* bf2 = (const float*)d_in[25];
    const float* ln2_g = (const float*)d_in[26]; const float* ln2_b = (const float*)d_in[27];
    const float* Wp  = (const float*)d_in[28]; const float* bp  = (const float*)d_in[29];
    const float* Wc  = (const float*)d_in[30]; const float* bc  = (const float*)d_in[31];
    float* out = (float*)d_out;

    const size_t NT = (size_t)BB * SS * DD;   // 6,291,456 floats per [B,S,D] buffer
    float* ws   = (float*)d_ws;
    float* x    = ws;
    float* qb   = ws + 1 * NT;
    float* kb   = ws + 2 * NT;
    float* vb   = ws + 3 * NT;
    float* kgb  = ws + 4 * NT;
    float* vgb  = ws + 5 * NT;
    float* aout = ws + 6 * NT;
    float* qg   = ws + 7 * NT;                // BB*DD floats
    float* mid  = vb;                          // FFN mid [B,S,F] aliases slots 3..6

    const int M = BB * SS;                     // 8192
    dim3 g768(M / 64, DD / 64);                // (128, 12)
    dim3 g3072(M / 64, FF / 64);               // (128, 48)

    embed_ln_k<<<M, 256, 0, stream>>>(input_ids, word_emb, pos_emb, ln_e_g, ln_e_b, x);

    for (int l = 0; l < 2; l++) {
        const float* Wq_l  = Wq  + (size_t)l * DD * DD; const float* bq_l  = bq  + (size_t)l * DD;
        const float* Wk_l  = Wk  + (size_t)l * DD * DD; const float* bk_l  = bk  + (size_t)l * DD;
        const float* Wv_l  = Wv  + (size_t)l * DD * DD; const float* bv_l  = bv  + (size_t)l * DD;
        const float* Wqg_l = Wqg + (size_t)l * DD * DD; const float* bqg_l = bqg + (size_t)l * DD;
        const float* Wkg_l = Wkg + (size_t)l * DD * DD; const float* bkg_l = bkg + (size_t)l * DD;
        const float* Wvg_l = Wvg + (size_t)l * DD * DD; const float* bvg_l = bvg + (size_t)l * DD;
        const float* Wo_l  = Wo  + (size_t)l * DD * DD; const float* bo_l  = bo  + (size_t)l * DD;
        const float* W1_l  = W1  + (size_t)l * DD * FF; const float* bf1_l = bf1 + (size_t)l * FF;
        const float* W2_l  = W2  + (size_t)l * FF * DD; const float* bf2_l = bf2 + (size_t)l * DD;
        const float* g1_l  = ln1_g + (size_t)l * DD;    const float* b1_l  = ln1_b + (size_t)l * DD;
        const float* g2_l  = ln2_g + (size_t)l * DD;    const float* b2_l  = ln2_b + (size_t)l * DD;

        gemm_bias_k<<<g768, 256, 0, stream>>>(x, Wq_l,  bq_l,  qb,  M, DD, DD, 0);
        gemm_bias_k<<<g768, 256, 0, stream>>>(x, Wk_l,  bk_l,  kb,  M, DD, DD, 0);
        gemm_bias_k<<<g768, 256, 0, stream>>>(x, Wv_l,  bv_l,  vb,  M, DD, DD, 0);
        gemm_bias_k<<<g768, 256, 0, stream>>>(x, Wkg_l, bkg_l, kgb, M, DD, DD, 0);
        gemm_bias_k<<<g768, 256, 0, stream>>>(x, Wvg_l, bvg_l, vgb, M, DD, DD, 0);
        qg_k<<<dim3(DD / 64, BB), 64, 0, stream>>>(x, Wqg_l, bqg_l, qg);

        swin_attn_k<<<dim3(CC, HH, BB), 256, 0, stream>>>(qb, kb, vb, amask, aout);
        gattn_k<<<dim3(HH, BB), 256, 0, stream>>>(qg, kgb, vgb, amask, aout);

        gemm_bias_k<<<g768, 256, 0, stream>>>(aout, Wo_l, bo_l, kb, M, DD, DD, 0);  // h -> kb
        add_ln_k<<<M, 256, 0, stream>>>(x, kb, g1_l, b1_l, x);

        gemm_bias_k<<<g3072, 256, 0, stream>>>(x, W1_l, bf1_l, mid, M, FF, DD, 1);  // gelu fused
        gemm_bias_k<<<g768, 256, 0, stream>>>(mid, W2_l, bf2_l, qb, M, DD, FF, 0);
        add_ln_k<<<M, 256, 0, stream>>>(x, qb, g2_l, b2_l, x);
    }

    pooler_cls_k<<<BB, 256, 0, stream>>>(x, Wp, bp, Wc, bc, out);
}

// Round 2
// 2817.202 us; speedup vs baseline: 2.1006x; 2.1006x over previous
//
#include <hip/hip_runtime.h>
#include <hip/hip_bf16.h>
#include <math.h>

#define BB 2
#define SS 4096
#define DD 768
#define HH 12
#define DHH 64
#define WW 256
#define CC 16
#define FF 3072
#define SCALE 0.125f

typedef __attribute__((ext_vector_type(8))) short bf16x8;
typedef __attribute__((ext_vector_type(4))) float f32x4;

__device__ __forceinline__ float gelu_f(float x) {
    float x3 = x * x * x;
    return 0.5f * x * (1.0f + tanhf(0.7978845608028654f * (x + 0.044715f * x3)));
}

__device__ __forceinline__ unsigned short bfb(float f) {
    __hip_bfloat16 h = __float2bfloat16(f);
    return *(unsigned short*)&h;
}

__device__ __forceinline__ void gload16(const void* g, void* l) {
    __builtin_amdgcn_global_load_lds(
        (const __attribute__((address_space(1))) unsigned int*)g,
        (__attribute__((address_space(3))) unsigned int*)l, 16, 0, 0);
}

// ---------------- weight fp32 [K][N] -> bf16 W^T [N][K] ----------------
__global__ __launch_bounds__(256) void transpose_bf16_k(const float* __restrict__ Wsrc,
        unsigned short* __restrict__ Wt, int K, int N)
{
    __shared__ float t[32][33];
    int n0 = blockIdx.x * 32, k0 = blockIdx.y * 32;
    int tx = threadIdx.x & 31, ty = threadIdx.x >> 5;   // 32 x 8
#pragma unroll
    for (int i = 0; i < 32; i += 8)
        t[ty + i][tx] = Wsrc[(size_t)(k0 + ty + i) * N + n0 + tx];
    __syncthreads();
#pragma unroll
    for (int i = 0; i < 32; i += 8)
        Wt[(size_t)(n0 + ty + i) * K + k0 + tx] = bfb(t[tx][ty + i]);
}

// ---------------- embedding + LayerNorm (writes fp32 x and bf16 x) ----------------
__global__ __launch_bounds__(256) void embed_ln_k(const int* __restrict__ ids,
        const float* __restrict__ wemb, const float* __restrict__ pemb,
        const float* __restrict__ g, const float* __restrict__ bta,
        float* __restrict__ x, unsigned short* __restrict__ xbf)
{
    int row = blockIdx.x;
    int s = row & (SS - 1);
    int tid = threadIdx.x;
    __shared__ float r1[256], r2[256];
    const float* we = wemb + (size_t)ids[row] * DD;
    const float* pe = pemb + (size_t)s * DD;
    float v[3]; float sum = 0.f, sq = 0.f;
#pragma unroll
    for (int i = 0; i < 3; i++) {
        int c = tid + i * 256;
        v[i] = we[c] + pe[c];
        sum += v[i]; sq += v[i] * v[i];
    }
    r1[tid] = sum; r2[tid] = sq; __syncthreads();
    for (int o = 128; o > 0; o >>= 1) {
        if (tid < o) { r1[tid] += r1[tid + o]; r2[tid] += r2[tid + o]; }
        __syncthreads();
    }
    float mean = r1[0] * (1.f / DD);
    float var = r2[0] * (1.f / DD) - mean * mean;
    float rstd = rsqrtf(var + 1e-5f);
#pragma unroll
    for (int i = 0; i < 3; i++) {
        int c = tid + i * 256;
        float o = (v[i] - mean) * rstd * g[c] + bta[c];
        x[(size_t)row * DD + c] = o;
        xbf[(size_t)row * DD + c] = bfb(o);
    }
}

// ---------------- residual add + LayerNorm (dual write) ----------------
__global__ __launch_bounds__(256) void add_ln_k(const float* __restrict__ xin,
        const float* __restrict__ hin, const float* __restrict__ g,
        const float* __restrict__ bta, float* __restrict__ xout,
        unsigned short* __restrict__ xbf)
{
    int row = blockIdx.x;
    int tid = threadIdx.x;
    __shared__ float r1[256], r2[256];
    const float* xr = xin + (size_t)row * DD;
    const float* hr = hin + (size_t)row * DD;
    float v[3]; float sum = 0.f, sq = 0.f;
#pragma unroll
    for (int i = 0; i < 3; i++) {
        int c = tid + i * 256;
        v[i] = xr[c] + hr[c];
        sum += v[i]; sq += v[i] * v[i];
    }
    r1[tid] = sum; r2[tid] = sq; __syncthreads();
    for (int o = 128; o > 0; o >>= 1) {
        if (tid < o) { r1[tid] += r1[tid + o]; r2[tid] += r2[tid + o]; }
        __syncthreads();
    }
    float mean = r1[0] * (1.f / DD);
    float var = r2[0] * (1.f / DD) - mean * mean;
    float rstd = rsqrtf(var + 1e-5f);
#pragma unroll
    for (int i = 0; i < 3; i++) {
        int c = tid + i * 256;
        float o = (v[i] - mean) * rstd * g[c] + bta[c];
        xout[(size_t)row * DD + c] = o;
        xbf[(size_t)row * DD + c] = bfb(o);
    }
}

// ---------------- bf16 MFMA GEMM: C = A[M,K] @ Bt[N,K]^T + bias  (m97 structure) ----------------
template<int OUT_BF16, int ACT_GELU>
__global__ __launch_bounds__(256) void mfma_gemm_k(
        const unsigned short* __restrict__ A,    // [M][K] bf16
        const unsigned short* __restrict__ Bt,   // [N][K] bf16 (B transposed)
        const float* __restrict__ bias,          // [N]
        void* __restrict__ Cv, int M, int N, int K)
{
    __shared__ short As[128 * 32];
    __shared__ short Bs[128 * 32];
    const int tid = threadIdx.x;
    const int lane = tid & 63, wv = tid >> 6;
    const int bm = blockIdx.x * 128, bn = blockIdx.y * 128;
    const int wm = wv >> 1, wn = wv & 1;

    // staging: 8192B tile = 2 issues x 4 waves x 64 lanes x 16B, linear LDS
    const int off0 = wv * 1024 + lane * 16;
    const int off1 = off0 + 4096;
    const int r0 = off0 >> 6, c0 = (off0 & 63) >> 1;
    const int r1 = off1 >> 6, c1 = (off1 & 63) >> 1;
    const unsigned short* Abase = A + (size_t)bm * K;
    const unsigned short* Bbase = Bt + (size_t)bn * K;

    f32x4 acc[4][4];
#pragma unroll
    for (int i = 0; i < 4; i++)
#pragma unroll
        for (int j = 0; j < 4; j++) acc[i][j] = (f32x4){0.f, 0.f, 0.f, 0.f};

    const int lr = lane & 15;
    const int lk = (lane >> 4) * 8;

    for (int k0 = 0; k0 < K; k0 += 32) {
        __syncthreads();
        gload16(Abase + (size_t)r0 * K + k0 + c0, (char*)As + off0);
        gload16(Abase + (size_t)r1 * K + k0 + c1, (char*)As + off1);
        gload16(Bbase + (size_t)r0 * K + k0 + c0, (char*)Bs + off0);
        gload16(Bbase + (size_t)r1 * K + k0 + c1, (char*)Bs + off1);
        __syncthreads();
        bf16x8 af[4], bfr[4];
#pragma unroll
        for (int i = 0; i < 4; i++)
            af[i] = *(const bf16x8*)&As[(wm * 64 + i * 16 + lr) * 32 + lk];
#pragma unroll
        for (int j = 0; j < 4; j++)
            bfr[j] = *(const bf16x8*)&Bs[(wn * 64 + j * 16 + lr) * 32 + lk];
#pragma unroll
        for (int i = 0; i < 4; i++)
#pragma unroll
            for (int j = 0; j < 4; j++)
                acc[i][j] = __builtin_amdgcn_mfma_f32_16x16x32_bf16(af[i], bfr[j], acc[i][j], 0, 0, 0);
    }

    const int rq = lane >> 4;
#pragma unroll
    for (int j = 0; j < 4; j++) {
        int col = bn + wn * 64 + j * 16 + lr;
        float bv = bias[col];
#pragma unroll
        for (int i = 0; i < 4; i++) {
            int rowb = bm + wm * 64 + i * 16 + rq * 4;
#pragma unroll
            for (int r = 0; r < 4; r++) {
                float o = acc[i][j][r] + bv;
                if (ACT_GELU) o = gelu_f(o);
                if (OUT_BF16)
                    ((unsigned short*)Cv)[(size_t)(rowb + r) * N + col] = bfb(o);
                else
                    ((float*)Cv)[(size_t)(rowb + r) * N + col] = o;
            }
        }
    }
}

// ---------------- sliding-window attention (fp32 in, bf16 out) ----------------
__global__ __launch_bounds__(256) void swin_attn_k(const float* __restrict__ Q,
        const float* __restrict__ K, const float* __restrict__ V,
        const int* __restrict__ mask, unsigned short* __restrict__ O)
{
    int c = blockIdx.x, h = blockIdx.y, b = blockIdx.z;
    int qi = threadIdx.x;
    __shared__ float kb[64][64];
    __shared__ float vb[64][64];
    __shared__ float gk[64];
    __shared__ float gv[64];
    __shared__ int mv[64];
    size_t headoff = (size_t)h * DHH;
    const float* qrow = Q + ((size_t)(b * SS + c * WW + qi)) * DD + headoff;
    float qreg[64];
#pragma unroll
    for (int d4 = 0; d4 < 16; d4++) {
        float4 t = *(const float4*)(qrow + d4 * 4);
        qreg[d4 * 4 + 0] = t.x; qreg[d4 * 4 + 1] = t.y;
        qreg[d4 * 4 + 2] = t.z; qreg[d4 * 4 + 3] = t.w;
    }
    if (qi < 64)       gk[qi] = K[((size_t)b * SS) * DD + headoff + qi];
    else if (qi < 128) gv[qi - 64] = V[((size_t)b * SS) * DD + headoff + (qi - 64)];

    float m = -1e30f, l = 0.f;
    float acc[64];
#pragma unroll
    for (int d = 0; d < 64; d++) acc[d] = 0.f;

    int jrow = qi >> 2;
    int f4 = qi & 3;
    for (int t0 = 0; t0 < 3 * WW; t0 += 64) {
        __syncthreads();
        int kpos = c * WW - WW + t0 + jrow;
        bool inr = (kpos >= 0) && (kpos < SS);
        if (f4 == 0) mv[jrow] = (inr && mask[b * SS + kpos] > 0) ? 1 : 0;
        if (inr) {
            const float* kr = K + ((size_t)(b * SS + kpos)) * DD + headoff;
            const float* vr = V + ((size_t)(b * SS + kpos)) * DD + headoff;
#pragma unroll
            for (int u = 0; u < 4; u++) {
                int p = f4 + u * 4;
                *(float4*)&kb[jrow][p * 4] = *(const float4*)(kr + p * 4);
                *(float4*)&vb[jrow][p * 4] = *(const float4*)(vr + p * 4);
            }
        }
        __syncthreads();
        for (int j = 0; j < 64; j++) {
            int rel = t0 + j - WW - qi;
            if (mv[j] && rel <= WW && rel >= -WW) {
                float s = 0.f;
#pragma unroll
                for (int d4 = 0; d4 < 16; d4++) {
                    float4 kv = *(const float4*)&kb[j][d4 * 4];
                    s = fmaf(qreg[d4 * 4 + 0], kv.x, s);
                    s = fmaf(qreg[d4 * 4 + 1], kv.y, s);
                    s = fmaf(qreg[d4 * 4 + 2], kv.z, s);
                    s = fmaf(qreg[d4 * 4 + 3], kv.w, s);
                }
                s *= SCALE;
                if (s <= m) {
                    float e = __expf(s - m);
                    l += e;
#pragma unroll
                    for (int d4 = 0; d4 < 16; d4++) {
                        float4 vv = *(const float4*)&vb[j][d4 * 4];
                        acc[d4 * 4 + 0] = fmaf(e, vv.x, acc[d4 * 4 + 0]);
                        acc[d4 * 4 + 1] = fmaf(e, vv.y, acc[d4 * 4 + 1]);
                        acc[d4 * 4 + 2] = fmaf(e, vv.z, acc[d4 * 4 + 2]);
                        acc[d4 * 4 + 3] = fmaf(e, vv.w, acc[d4 * 4 + 3]);
                    }
                } else {
                    float r = __expf(m - s);
                    m = s;
                    l = fmaf(l, r, 1.f);
#pragma unroll
                    for (int d4 = 0; d4 < 16; d4++) {
                        float4 vv = *(const float4*)&vb[j][d4 * 4];
                        acc[d4 * 4 + 0] = fmaf(acc[d4 * 4 + 0], r, vv.x);
                        acc[d4 * 4 + 1] = fmaf(acc[d4 * 4 + 1], r, vv.y);
                        acc[d4 * 4 + 2] = fmaf(acc[d4 * 4 + 2], r, vv.z);
                        acc[d4 * 4 + 3] = fmaf(acc[d4 * 4 + 3], r, vv.w);
                    }
                }
            }
        }
    }
    {
        float s = 0.f;
#pragma unroll
        for (int d = 0; d < 64; d++) s = fmaf(qreg[d], gk[d], s);
        s *= SCALE;
        if (s <= m) {
            float e = __expf(s - m);
            l += e;
#pragma unroll
            for (int d = 0; d < 64; d++) acc[d] = fmaf(e, gv[d], acc[d]);
        } else {
            float r = __expf(m - s);
            m = s;
            l = fmaf(l, r, 1.f);
#pragma unroll
            for (int d = 0; d < 64; d++) acc[d] = fmaf(acc[d], r, gv[d]);
        }
    }
    float inv = 1.f / l;
    unsigned short* orow = O + ((size_t)(b * SS + c * WW + qi)) * DD + headoff;
#pragma unroll
    for (int d4 = 0; d4 < 16; d4++) {
        ushort4 ov;
        ov.x = bfb(acc[d4 * 4 + 0] * inv);
        ov.y = bfb(acc[d4 * 4 + 1] * inv);
        ov.z = bfb(acc[d4 * 4 + 2] * inv);
        ov.w = bfb(acc[d4 * 4 + 3] * inv);
        *(ushort4*)&orow[d4 * 4] = ov;
    }
}

// ---------------- qg = x[:,0,:] @ Wqg + bqg ----------------
__global__ __launch_bounds__(64) void qg_k(const float* __restrict__ x,
        const float* __restrict__ Wg, const float* __restrict__ bg,
        float* __restrict__ qg)
{
    int b = blockIdx.y;
    int col = blockIdx.x * 64 + threadIdx.x;
    const float* xr = x + (size_t)b * SS * DD;
    float a = bg[col];
    for (int k2 = 0; k2 < DD; k2++)
        a = fmaf(xr[k2], Wg[(size_t)k2 * DD + col], a);
    qg[b * DD + col] = a;
}

// ---------------- global-token full attention; writes row 0 of O (bf16) ----------------
__global__ __launch_bounds__(256) void gattn_k(const float* __restrict__ qg,
        const float* __restrict__ kg, const float* __restrict__ vg,
        const int* __restrict__ mask, unsigned short* __restrict__ O)
{
    int h = blockIdx.x, b = blockIdx.y;
    int tid = threadIdx.x;
    __shared__ float sc[SS];
    __shared__ float gq[64];
    __shared__ float red[256];
    __shared__ float ored[4][64];
    if (tid < 64) gq[tid] = qg[b * DD + h * DHH + tid];
    __syncthreads();
    float lmax = -1e30f;
    for (int s = tid; s < SS; s += 256) {
        const float* kr = kg + ((size_t)(b * SS + s)) * DD + h * DHH;
        float a = 0.f;
#pragma unroll
        for (int d4 = 0; d4 < 16; d4++) {
            float4 kv = *(const float4*)(kr + d4 * 4);
            a = fmaf(gq[d4 * 4 + 0], kv.x, a);
            a = fmaf(gq[d4 * 4 + 1], kv.y, a);
            a = fmaf(gq[d4 * 4 + 2], kv.z, a);
            a = fmaf(gq[d4 * 4 + 3], kv.w, a);
        }
        a *= SCALE;
        float sv = (mask[b * SS + s] > 0) ? a : -1e9f;
        sc[s] = sv;
        lmax = fmaxf(lmax, sv);
    }
    red[tid] = lmax; __syncthreads();
    for (int o = 128; o > 0; o >>= 1) {
        if (tid < o) red[tid] = fmaxf(red[tid], red[tid + o]);
        __syncthreads();
    }
    float mx = red[0]; __syncthreads();
    float lsum = 0.f;
    for (int s = tid; s < SS; s += 256) {
        float p = __expf(sc[s] - mx);
        sc[s] = p;
        lsum += p;
    }
    red[tid] = lsum; __syncthreads();
    for (int o = 128; o > 0; o >>= 1) {
        if (tid < o) red[tid] += red[tid + o];
        __syncthreads();
    }
    float denom = red[0];
    int d = tid & 63, grp = tid >> 6;
    float oa = 0.f;
    for (int s = grp; s < SS; s += 4)
        oa = fmaf(sc[s], vg[((size_t)(b * SS + s)) * DD + h * DHH + d], oa);
    ored[grp][d] = oa; __syncthreads();
    if (tid < 64) {
        float o = (ored[0][tid] + ored[1][tid] + ored[2][tid] + ored[3][tid]) / denom;
        O[((size_t)b * SS) * DD + h * DHH + tid] = bfb(o);
    }
}

// ---------------- pooler (tanh) + classifier ----------------
__global__ __launch_bounds__(256) void pooler_cls_k(const float* __restrict__ x,
        const float* __restrict__ Wp, const float* __restrict__ bp,
        const float* __restrict__ Wc, const float* __restrict__ bc,
        float* __restrict__ out)
{
    int b = blockIdx.x;
    int tid = threadIdx.x;
    __shared__ float pooled[DD];
    const float* xr = x + (size_t)b * SS * DD;
    for (int col = tid; col < DD; col += 256) {
        float a = bp[col];
        for (int k2 = 0; k2 < DD; k2++)
            a = fmaf(xr[k2], Wp[(size_t)k2 * DD + col], a);
        pooled[col] = tanhf(a);
    }
    __syncthreads();
    if (tid < 2) {
        float a = bc[tid];
        for (int k2 = 0; k2 < DD; k2++)
            a = fmaf(pooled[k2], Wc[k2 * 2 + tid], a);
        out[b * 2 + tid] = a;
    }
}

extern "C" void kernel_launch(void* const* d_in, const int* in_sizes, int n_in,
                              void* d_out, int out_size, void* d_ws, size_t ws_size,
                              hipStream_t stream) {
    const int*   input_ids = (const int*)d_in[0];
    const int*   amask     = (const int*)d_in[1];
    const float* word_emb  = (const float*)d_in[2];
    const float* pos_emb   = (const float*)d_in[3];
    const float* ln_e_g    = (const float*)d_in[4];
    const float* ln_e_b    = (const float*)d_in[5];
    const float* Wq  = (const float*)d_in[6];  const float* bq  = (const float*)d_in[7];
    const float* Wk  = (const float*)d_in[8];  const float* bk  = (const float*)d_in[9];
    const float* Wv  = (const float*)d_in[10]; const float* bv  = (const float*)d_in[11];
    const float* Wqg = (const float*)d_in[12]; const float* bqg = (const float*)d_in[13];
    const float* Wkg = (const float*)d_in[14]; const float* bkg = (const float*)d_in[15];
    const float* Wvg = (const float*)d_in[16]; const float* bvg = (const float*)d_in[17];
    const float* Wo  = (const float*)d_in[18]; const float* bo  = (const float*)d_in[19];
    const float* ln1_g = (const float*)d_in[20]; const float* ln1_b = (const float*)d_in[21];
    const float* W1  = (const float*)d_in[22]; const float* bf1 = (const float*)d_in[23];
    const float* W2  = (const float*)d_in[24]; const float* bf2 = (const float*)d_in[25];
    const float* ln2_g = (const float*)d_in[26]; const float* ln2_b = (const float*)d_in[27];
    const float* Wp  = (const float*)d_in[28]; const float* bp  = (const float*)d_in[29];
    const float* Wc  = (const float*)d_in[30]; const float* bc  = (const float*)d_in[31];
    float* out = (float*)d_out;

    const size_t NTB = (size_t)BB * SS * DD * 4;    // 25,165,824 bytes (one fp32 [B,S,D])
    char* wsb = (char*)d_ws;
    float* x   = (float*)(wsb + 0 * NTB);
    float* qf  = (float*)(wsb + 1 * NTB);
    float* kf  = (float*)(wsb + 2 * NTB);
    float* vf  = (float*)(wsb + 3 * NTB);
    float* kgf = (float*)(wsb + 4 * NTB);
    float* vgf = (float*)(wsb + 5 * NTB);
    unsigned short* xbf  = (unsigned short*)(wsb + 6 * NTB);
    unsigned short* aout = (unsigned short*)(wsb + 6 * NTB + NTB / 2);
    float* hf = kgf;                               // alias: kg dead after gattn
    unsigned short* mid = (unsigned short*)qf;     // alias q..k: dead after swin_attn
    char* wt = wsb + 7 * NTB;                      // bf16 transposed weights (33 MB)
    float* qg = (float*)(wsb + 7 * NTB + 34u * 1024 * 1024);

    // transposed bf16 weight pointers
    const size_t SQ = (size_t)DD * DD * 2;         // 1,179,648 B per 768x768 bf16
    const size_t SF = (size_t)DD * FF * 2;         // 4,718,592 B per 768x3072 bf16
    const size_t PER_L = 6 * SQ + 2 * SF;
    unsigned short* Wt_q[2], *Wt_k[2], *Wt_v[2], *Wt_kg[2], *Wt_vg[2], *Wt_o[2], *Wt_1[2], *Wt_2[2];
    for (int l = 0; l < 2; l++) {
        char* base = wt + (size_t)l * PER_L;
        Wt_q[l]  = (unsigned short*)(base + 0 * SQ);
        Wt_k[l]  = (unsigned short*)(base + 1 * SQ);
        Wt_v[l]  = (unsigned short*)(base + 2 * SQ);
        Wt_kg[l] = (unsigned short*)(base + 3 * SQ);
        Wt_vg[l] = (unsigned short*)(base + 4 * SQ);
        Wt_o[l]  = (unsigned short*)(base + 5 * SQ);
        Wt_1[l]  = (unsigned short*)(base + 6 * SQ);
        Wt_2[l]  = (unsigned short*)(base + 6 * SQ + SF);
    }

    const int M = BB * SS;                          // 8192
    dim3 tq(DD / 32, DD / 32);                      // 768x768 transpose
    dim3 t1(FF / 32, DD / 32);                      // W1 [768][3072]
    dim3 t2(DD / 32, FF / 32);                      // W2 [3072][768]
    for (int l = 0; l < 2; l++) {
        transpose_bf16_k<<<tq, 256, 0, stream>>>(Wq  + (size_t)l * DD * DD, Wt_q[l],  DD, DD);
        transpose_bf16_k<<<tq, 256, 0, stream>>>(Wk  + (size_t)l * DD * DD, Wt_k[l],  DD, DD);
        transpose_bf16_k<<<tq, 256, 0, stream>>>(Wv  + (size_t)l * DD * DD, Wt_v[l],  DD, DD);
        transpose_bf16_k<<<tq, 256, 0, stream>>>(Wkg + (size_t)l * DD * DD, Wt_kg[l], DD, DD);
        transpose_bf16_k<<<tq, 256, 0, stream>>>(Wvg + (size_t)l * DD * DD, Wt_vg[l], DD, DD);
        transpose_bf16_k<<<tq, 256, 0, stream>>>(Wo  + (size_t)l * DD * DD, Wt_o[l],  DD, DD);
        transpose_bf16_k<<<t1, 256, 0, stream>>>(W1  + (size_t)l * DD * FF, Wt_1[l],  DD, FF);
        transpose_bf16_k<<<t2, 256, 0, stream>>>(W2  + (size_t)l * FF * DD, Wt_2[l],  FF, DD);
    }

    embed_ln_k<<<M, 256, 0, stream>>>(input_ids, word_emb, pos_emb, ln_e_g, ln_e_b, x, xbf);

    dim3 g768(M / 128, DD / 128);                   // (64, 6)
    dim3 g3072(M / 128, FF / 128);                  // (64, 24)

    for (int l = 0; l < 2; l++) {
        const float* bq_l  = bq  + (size_t)l * DD;
        const float* bk_l  = bk  + (size_t)l * DD;
        const float* bv_l  = bv  + (size_t)l * DD;
        const float* Wqg_l = Wqg + (size_t)l * DD * DD; const float* bqg_l = bqg + (size_t)l * DD;
        const float* bkg_l = bkg + (size_t)l * DD;
        const float* bvg_l = bvg + (size_t)l * DD;
        const float* bo_l  = bo  + (size_t)l * DD;
        const float* bf1_l = bf1 + (size_t)l * FF;
        const float* bf2_l = bf2 + (size_t)l * DD;
        const float* g1_l  = ln1_g + (size_t)l * DD; const float* b1_l = ln1_b + (size_t)l * DD;
        const float* g2_l  = ln2_g + (size_t)l * DD; const float* b2_l = ln2_b + (size_t)l * DD;

        mfma_gemm_k<0, 0><<<g768, 256, 0, stream>>>(xbf, Wt_q[l],  bq_l,  qf,  M, DD, DD);
        mfma_gemm_k<0, 0><<<g768, 256, 0, stream>>>(xbf, Wt_k[l],  bk_l,  kf,  M, DD, DD);
        mfma_gemm_k<0, 0><<<g768, 256, 0, stream>>>(xbf, Wt_v[l],  bv_l,  vf,  M, DD, DD);
        mfma_gemm_k<0, 0><<<g768, 256, 0, stream>>>(xbf, Wt_kg[l], bkg_l, kgf, M, DD, DD);
        mfma_gemm_k<0, 0><<<g768, 256, 0, stream>>>(xbf, Wt_vg[l], bvg_l, vgf, M, DD, DD);
        qg_k<<<dim3(DD / 64, BB), 64, 0, stream>>>(x, Wqg_l, bqg_l, qg);

        swin_attn_k<<<dim3(CC, HH, BB), 256, 0, stream>>>(qf, kf, vf, amask, aout);
        gattn_k<<<dim3(HH, BB), 256, 0, stream>>>(qg, kgf, vgf, amask, aout);

        mfma_gemm_k<0, 0><<<g768, 256, 0, stream>>>(aout, Wt_o[l], bo_l, hf, M, DD, DD);
        add_ln_k<<<M, 256, 0, stream>>>(x, hf, g1_l, b1_l, x, xbf);

        mfma_gemm_k<1, 1><<<g3072, 256, 0, stream>>>(xbf, Wt_1[l], bf1_l, mid, M, FF, DD);
        mfma_gemm_k<0, 0><<<g768, 256, 0, stream>>>(mid, Wt_2[l], bf2_l, hf, M, DD, FF);
        add_ln_k<<<M, 256, 0, stream>>>(x, hf, g2_l, b2_l, x, xbf);
    }

    pooler_cls_k<<<BB, 256, 0, stream>>>(x, Wp, bp, Wc, bc, out);
}

// Round 4
// 1153.020 us; speedup vs baseline: 5.1325x; 2.4433x over previous
//
#include <hip/hip_runtime.h>
#include <hip/hip_bf16.h>
#include <math.h>

#define BB 2
#define SS 4096
#define DD 768
#define HH 12
#define DHH 64
#define WW 256
#define CC 16
#define FF 3072

typedef __attribute__((ext_vector_type(8))) short bf16x8;
typedef __attribute__((ext_vector_type(4))) float f32x4;

__device__ __forceinline__ float gelu_f(float x) {
    float x3 = x * x * x;
    return 0.5f * x * (1.0f + tanhf(0.7978845608028654f * (x + 0.044715f * x3)));
}

__device__ __forceinline__ unsigned short bfb(float f) {
    __hip_bfloat16 h = __float2bfloat16(f);
    return *(unsigned short*)&h;
}

__device__ __forceinline__ float bf2f(unsigned short u) {
    return __uint_as_float(((unsigned int)u) << 16);
}

__device__ __forceinline__ void gload16(const void* g, void* l) {
    __builtin_amdgcn_global_load_lds(
        (const __attribute__((address_space(1))) unsigned int*)g,
        (__attribute__((address_space(3))) unsigned int*)l, 16, 0, 0);
}

// ---------------- weight fp32 [K][N] -> bf16 W^T [N][K] ----------------
__global__ __launch_bounds__(256) void transpose_bf16_k(const float* __restrict__ Wsrc,
        unsigned short* __restrict__ Wt, int K, int N)
{
    __shared__ float t[32][33];
    int n0 = blockIdx.x * 32, k0 = blockIdx.y * 32;
    int tx = threadIdx.x & 31, ty = threadIdx.x >> 5;   // 32 x 8
#pragma unroll
    for (int i = 0; i < 32; i += 8)
        t[ty + i][tx] = Wsrc[(size_t)(k0 + ty + i) * N + n0 + tx];
    __syncthreads();
#pragma unroll
    for (int i = 0; i < 32; i += 8)
        Wt[(size_t)(n0 + ty + i) * K + k0 + tx] = bfb(t[tx][ty + i]);
}

// ---------------- pack 5 bias vectors [2][768] each -> [2][3840] ----------------
__global__ __launch_bounds__(256) void pack_bias5_k(const float* __restrict__ b0,
        const float* __restrict__ b1, const float* __restrict__ b2,
        const float* __restrict__ b3, const float* __restrict__ b4,
        float* __restrict__ dst)
{
    int gid = blockIdx.x * 256 + threadIdx.x;
    if (gid >= 2 * 5 * DD) return;
    int l = gid / (5 * DD), r = gid % (5 * DD), seg = r / DD, i = r % DD;
    const float* srcs[5] = { b0, b1, b2, b3, b4 };
    dst[gid] = srcs[seg][l * DD + i];
}

// ---------------- embedding + LayerNorm (fp32 x + bf16 x) ----------------
__global__ __launch_bounds__(256) void embed_ln_k(const int* __restrict__ ids,
        const float* __restrict__ wemb, const float* __restrict__ pemb,
        const float* __restrict__ g, const float* __restrict__ bta,
        float* __restrict__ x, unsigned short* __restrict__ xbf)
{
    int row = blockIdx.x;
    int s = row & (SS - 1);
    int tid = threadIdx.x;
    __shared__ float r1[256], r2[256];
    const float* we = wemb + (size_t)ids[row] * DD;
    const float* pe = pemb + (size_t)s * DD;
    float v[3]; float sum = 0.f, sq = 0.f;
#pragma unroll
    for (int i = 0; i < 3; i++) {
        int c = tid + i * 256;
        v[i] = we[c] + pe[c];
        sum += v[i]; sq += v[i] * v[i];
    }
    r1[tid] = sum; r2[tid] = sq; __syncthreads();
    for (int o = 128; o > 0; o >>= 1) {
        if (tid < o) { r1[tid] += r1[tid + o]; r2[tid] += r2[tid + o]; }
        __syncthreads();
    }
    float mean = r1[0] * (1.f / DD);
    float var = r2[0] * (1.f / DD) - mean * mean;
    float rstd = rsqrtf(var + 1e-5f);
#pragma unroll
    for (int i = 0; i < 3; i++) {
        int c = tid + i * 256;
        float o = (v[i] - mean) * rstd * g[c] + bta[c];
        x[(size_t)row * DD + c] = o;
        xbf[(size_t)row * DD + c] = bfb(o);
    }
}

// ---------------- residual add + LayerNorm (dual write) ----------------
__global__ __launch_bounds__(256) void add_ln_k(const float* __restrict__ xin,
        const float* __restrict__ hin, const float* __restrict__ g,
        const float* __restrict__ bta, float* __restrict__ xout,
        unsigned short* __restrict__ xbf)
{
    int row = blockIdx.x;
    int tid = threadIdx.x;
    __shared__ float r1[256], r2[256];
    const float* xr = xin + (size_t)row * DD;
    const float* hr = hin + (size_t)row * DD;
    float v[3]; float sum = 0.f, sq = 0.f;
#pragma unroll
    for (int i = 0; i < 3; i++) {
        int c = tid + i * 256;
        v[i] = xr[c] + hr[c];
        sum += v[i]; sq += v[i] * v[i];
    }
    r1[tid] = sum; r2[tid] = sq; __syncthreads();
    for (int o = 128; o > 0; o >>= 1) {
        if (tid < o) { r1[tid] += r1[tid + o]; r2[tid] += r2[tid + o]; }
        __syncthreads();
    }
    float mean = r1[0] * (1.f / DD);
    float var = r2[0] * (1.f / DD) - mean * mean;
    float rstd = rsqrtf(var + 1e-5f);
#pragma unroll
    for (int i = 0; i < 3; i++) {
        int c = tid + i * 256;
        float o = (v[i] - mean) * rstd * g[c] + bta[c];
        xout[(size_t)row * DD + c] = o;
        xbf[(size_t)row * DD + c] = bfb(o);
    }
}

// ---------------- bf16 MFMA GEMM: C = A[M,K] @ Bt[N,K]^T + bias ----------------
template<int OUT_BF16, int ACT_GELU>
__global__ __launch_bounds__(256) void mfma_gemm_k(
        const unsigned short* __restrict__ A,
        const unsigned short* __restrict__ Bt,
        const float* __restrict__ bias,
        void* __restrict__ Cv, int M, int N, int K)
{
    __shared__ short As[128 * 32];
    __shared__ short Bs[128 * 32];
    const int tid = threadIdx.x;
    const int lane = tid & 63, wv = tid >> 6;
    const int bm = blockIdx.x * 128, bn = blockIdx.y * 128;
    const int wm = wv >> 1, wn = wv & 1;

    const int off0 = wv * 1024 + lane * 16;
    const int off1 = off0 + 4096;
    const int r0 = off0 >> 6, c0 = (off0 & 63) >> 1;
    const int r1 = off1 >> 6, c1 = (off1 & 63) >> 1;
    const unsigned short* Abase = A + (size_t)bm * K;
    const unsigned short* Bbase = Bt + (size_t)bn * K;

    f32x4 acc[4][4];
#pragma unroll
    for (int i = 0; i < 4; i++)
#pragma unroll
        for (int j = 0; j < 4; j++) acc[i][j] = (f32x4){0.f, 0.f, 0.f, 0.f};

    const int lr = lane & 15;
    const int lk = (lane >> 4) * 8;

    for (int k0 = 0; k0 < K; k0 += 32) {
        __syncthreads();
        gload16(Abase + (size_t)r0 * K + k0 + c0, (char*)As + off0);
        gload16(Abase + (size_t)r1 * K + k0 + c1, (char*)As + off1);
        gload16(Bbase + (size_t)r0 * K + k0 + c0, (char*)Bs + off0);
        gload16(Bbase + (size_t)r1 * K + k0 + c1, (char*)Bs + off1);
        __syncthreads();
        bf16x8 af[4], bfr[4];
#pragma unroll
        for (int i = 0; i < 4; i++)
            af[i] = *(const bf16x8*)&As[(wm * 64 + i * 16 + lr) * 32 + lk];
#pragma unroll
        for (int j = 0; j < 4; j++)
            bfr[j] = *(const bf16x8*)&Bs[(wn * 64 + j * 16 + lr) * 32 + lk];
#pragma unroll
        for (int i = 0; i < 4; i++)
#pragma unroll
            for (int j = 0; j < 4; j++)
                acc[i][j] = __builtin_amdgcn_mfma_f32_16x16x32_bf16(af[i], bfr[j], acc[i][j], 0, 0, 0);
    }

    const int rq = lane >> 4;
#pragma unroll
    for (int j = 0; j < 4; j++) {
        int col = bn + wn * 64 + j * 16 + lr;
        float bv = bias[col];
#pragma unroll
        for (int i = 0; i < 4; i++) {
            int rowb = bm + wm * 64 + i * 16 + rq * 4;
#pragma unroll
            for (int r = 0; r < 4; r++) {
                float o = acc[i][j][r] + bv;
                if (ACT_GELU) o = gelu_f(o);
                if (OUT_BF16)
                    ((unsigned short*)Cv)[(size_t)(rowb + r) * N + col] = bfb(o);
                else
                    ((float*)Cv)[(size_t)(rowb + r) * N + col] = o;
            }
        }
    }
}

// ---------------- V head-transpose: packed[.,VOFF+h*64+d] -> vt[(b*H+h)*64+d][s] ----------------
// 64x64 tile = 4096 elems; 256 threads x 8 elems x 2 halves.
__global__ __launch_bounds__(256) void vtrans_k(const unsigned short* __restrict__ packed,
        unsigned short* __restrict__ vt)
{
    int s0 = blockIdx.x * 64, h = blockIdx.y, b = blockIdx.z;
    int tid = threadIdx.x;
    __shared__ unsigned short t[64][72];
    int r = tid >> 3, dc = (tid & 7) * 8;
#pragma unroll
    for (int half = 0; half < 2; half++) {
        int rr = r + half * 32;
        const unsigned short* src = packed + (size_t)(b * SS + s0 + rr) * 3840 + 2 * DD + h * 64 + dc;
        *(uint4*)&t[rr][dc] = *(const uint4*)src;
    }
    __syncthreads();
    int d = tid >> 3, sc = (tid & 7) * 8;
#pragma unroll
    for (int half = 0; half < 2; half++) {
        int dd2 = d + half * 32;
        unsigned short v[8];
#pragma unroll
        for (int e = 0; e < 8; e++) v[e] = t[sc + e][dd2];
        unsigned short* dst = vt + (size_t)((b * HH + h) * 64 + dd2) * SS + s0 + sc;
        *(uint4*)dst = *(uint4*)v;
    }
}

// ---------------- MFMA sliding-window flash attention ----------------
// packed: [B*S][3840] bf16 (q|k|v|kg|vg); vt: [B*H*64][S] bf16 (per-head V^T)
__global__ __launch_bounds__(256) void swin_mfma_k(
        const unsigned short* __restrict__ packed,
        const unsigned short* __restrict__ vt,
        const int* __restrict__ mask,
        unsigned short* __restrict__ O)
{
    __shared__ __align__(16) char smem[51456];
    const int c = blockIdx.x, h = blockIdx.y, b = blockIdx.z;
    const int tid = threadIdx.x;
    const int lane = tid & 63, wv = tid >> 6;
    const int l15 = lane & 15, g = lane >> 4;
    const int bh = b * HH + h;

    char* KT = smem;                       // 8192 B: K-tile [64 k][128B dh], swizzled
    char* VT = smem + 8192;                // 8192 B: V^T-tile [64 d][128B k], swizzled
    char* PB = smem + 16384 + wv * 8192;   // per-wave P [64 q][128B k], swizzled
    float* maskf = (float*)(smem + 49152); // 64 floats
    float* sA = (float*)(smem + 49408);    // [4 waves][64 q]
    float* sB = (float*)(smem + 50432);    // [4 waves][64 q]

    // Q fragments (B-operand: lane&15 = q row, elems = dh)
    bf16x8 qf[4][2];
#pragma unroll
    for (int j = 0; j < 4; j++)
#pragma unroll
        for (int kk = 0; kk < 2; kk++)
            qf[j][kk] = *(const bf16x8*)(packed +
                (size_t)(b * SS + c * WW + wv * 64 + j * 16 + l15) * 3840 + h * 64 + kk * 32 + g * 8);
    // global key (row 0) fragments, same element layout as qf
    bf16x8 gkf[2];
#pragma unroll
    for (int kk = 0; kk < 2; kk++)
        gkf[kk] = *(const bf16x8*)(packed + (size_t)(b * SS) * 3840 + DD + h * 64 + kk * 32 + g * 8);
    // global value v0[d] for d = jd*16 + l15
    float v0r[4];
#pragma unroll
    for (int jd = 0; jd < 4; jd++)
        v0r[jd] = bf2f(vt[(size_t)(bh * 64 + jd * 16 + l15) * SS]);

    f32x4 o_[4][4];
#pragma unroll
    for (int i = 0; i < 4; i++)
#pragma unroll
        for (int j = 0; j < 4; j++) o_[i][j] = (f32x4){0.f, 0.f, 0.f, 0.f};
    float m_[4] = { -1e20f, -1e20f, -1e20f, -1e20f };
    float l_[4] = { 0.f, 0.f, 0.f, 0.f };

    const int rswz = (l15 & 7) << 4;
    const int kt_s = (c == 0) ? 4 : 0;
    const int kt_e = (c == CC - 1) ? 8 : 12;

    for (int kt = kt_s; kt < kt_e; kt++) {
        const int kpos0 = c * WW - WW + kt * 64;   // always fully in-range given kt_s/kt_e
        // ---- stage K-tile / V^T-tile (pre-swizzled source, linear LDS dest) ----
        {
            int off = tid * 16;
#pragma unroll
            for (int ch = 0; ch < 2; ch++) {
                int o2 = off + ch * 4096;
                int row = o2 >> 7, bc = o2 & 127;
                int srcc = bc ^ ((row & 7) << 4);
                gload16((const char*)packed + (size_t)(b * SS + kpos0 + row) * 7680 + 1536 + h * 128 + srcc,
                        KT + o2);
                gload16((const char*)vt + (size_t)(bh * 64 + row) * 8192 + (size_t)(kpos0 * 2 + srcc),
                        VT + o2);
            }
            if (tid < 64) {
                int kp = kpos0 + tid;
                float mv = (mask[b * SS + kp] > 0) ? 0.f : -1e30f;
                maskf[tid] = mv;
            }
        }
        __syncthreads();

        f32x4 mrd[4];
#pragma unroll
        for (int i = 0; i < 4; i++)
            mrd[i] = *(const f32x4*)&maskf[i * 16 + g * 4];

        // ---- S^T = K . Q^T : D[k][q] (swapped) ----
        f32x4 s_[4][4];
#pragma unroll
        for (int i = 0; i < 4; i++)
#pragma unroll
            for (int j = 0; j < 4; j++) s_[i][j] = (f32x4){0.f, 0.f, 0.f, 0.f};
#pragma unroll
        for (int kk = 0; kk < 2; kk++) {
            bf16x8 af[4];
#pragma unroll
            for (int i = 0; i < 4; i++)
                af[i] = *(const bf16x8*)(KT + (i * 16 + l15) * 128 + ((kk * 64 + g * 16) ^ rswz));
#pragma unroll
            for (int i = 0; i < 4; i++)
#pragma unroll
                for (int j = 0; j < 4; j++)
                    s_[i][j] = __builtin_amdgcn_mfma_f32_16x16x32_bf16(af[i], qf[j][kk], s_[i][j], 0, 0, 0);
        }

        // ---- online softmax per q (q = j*16 + l15), write P (bf16) ----
#pragma unroll
        for (int j = 0; j < 4; j++) {
            float tm = -1e30f;
#pragma unroll
            for (int i = 0; i < 4; i++) {
#pragma unroll
                for (int r = 0; r < 4; r++) {
                    float v = fmaf(s_[i][j][r], 0.125f, mrd[i][r]);
                    int rel = kt * 64 - WW + i * 16 + g * 4 + r - wv * 64 - j * 16 - l15;
                    v = (rel > WW || rel < -WW) ? -1e30f : v;
                    s_[i][j][r] = v;
                    tm = fmaxf(tm, v);
                }
            }
            tm = fmaxf(tm, __shfl_xor(tm, 16));
            tm = fmaxf(tm, __shfl_xor(tm, 32));
            float mn = fmaxf(m_[j], tm);
            float fac = __expf(m_[j] - mn);
            m_[j] = mn;
            float ls = 0.f;
            int q = j * 16 + l15;
#pragma unroll
            for (int i = 0; i < 4; i++) {
                float p0 = __expf(s_[i][j][0] - mn);
                float p1 = __expf(s_[i][j][1] - mn);
                float p2 = __expf(s_[i][j][2] - mn);
                float p3 = __expf(s_[i][j][3] - mn);
                ls += (p0 + p1) + (p2 + p3);
                uint2 pw;
                pw.x = (unsigned int)bfb(p0) | ((unsigned int)bfb(p1) << 16);
                pw.y = (unsigned int)bfb(p2) | ((unsigned int)bfb(p3) << 16);
                *(uint2*)(PB + q * 128 + ((i * 32 + g * 8) ^ rswz)) = pw;
            }
            ls += __shfl_xor(ls, 16);
            ls += __shfl_xor(ls, 32);
            l_[j] = l_[j] * fac + ls;
            if (g == 0) sA[wv * 64 + q] = fac;
        }

        // ---- PV: rescale O, then O += P . V  (D[q][d]) ----
#pragma unroll
        for (int iq = 0; iq < 4; iq++) {
            f32x4 fc = *(const f32x4*)&sA[wv * 64 + iq * 16 + g * 4];
#pragma unroll
            for (int jd = 0; jd < 4; jd++)
#pragma unroll
                for (int r = 0; r < 4; r++) o_[iq][jd][r] *= fc[r];
        }
#pragma unroll
        for (int kk = 0; kk < 2; kk++) {
            bf16x8 pa[4], vb[4];
#pragma unroll
            for (int iq = 0; iq < 4; iq++)
                pa[iq] = *(const bf16x8*)(PB + (iq * 16 + l15) * 128 + ((kk * 64 + g * 16) ^ rswz));
#pragma unroll
            for (int jd = 0; jd < 4; jd++)
                vb[jd] = *(const bf16x8*)(VT + (jd * 16 + l15) * 128 + ((kk * 64 + g * 16) ^ rswz));
#pragma unroll
            for (int iq = 0; iq < 4; iq++)
#pragma unroll
                for (int jd = 0; jd < 4; jd++)
                    o_[iq][jd] = __builtin_amdgcn_mfma_f32_16x16x32_bf16(pa[iq], vb[jd], o_[iq][jd], 0, 0, 0);
        }
        __syncthreads();
    }

    // ---- global key column (unmasked) + finalize ----
#pragma unroll
    for (int j = 0; j < 4; j++) {
        float pd = 0.f;
#pragma unroll
        for (int kk = 0; kk < 2; kk++)
#pragma unroll
            for (int e = 0; e < 8; e++)
                pd += bf2f((unsigned short)qf[j][kk][e]) * bf2f((unsigned short)gkf[kk][e]);
        pd += __shfl_xor(pd, 16);
        pd += __shfl_xor(pd, 32);
        float sg = pd * 0.125f;
        float mf = fmaxf(m_[j], sg);
        float fac = __expf(m_[j] - mf);
        float pg = __expf(sg - mf);
        float lf = l_[j] * fac + pg;
        float inv = 1.f / lf;
        if (g == 0) {
            sA[wv * 64 + j * 16 + l15] = fac * inv;
            sB[wv * 64 + j * 16 + l15] = pg * inv;
        }
    }
#pragma unroll
    for (int iq = 0; iq < 4; iq++) {
        f32x4 fA = *(const f32x4*)&sA[wv * 64 + iq * 16 + g * 4];
        f32x4 fB = *(const f32x4*)&sB[wv * 64 + iq * 16 + g * 4];
#pragma unroll
        for (int jd = 0; jd < 4; jd++) {
#pragma unroll
            for (int r = 0; r < 4; r++) {
                float val = o_[iq][jd][r] * fA[r] + fB[r] * v0r[jd];
                int row = b * SS + c * WW + wv * 64 + iq * 16 + g * 4 + r;
                O[(size_t)row * DD + h * 64 + jd * 16 + l15] = bfb(val);
            }
        }
    }
}

// ---------------- global-token attention, phase 1: per-chunk partials ----------------
__global__ __launch_bounds__(256) void gattn1_k(const float* __restrict__ qg,
        const unsigned short* __restrict__ packed, const int* __restrict__ mask,
        float* __restrict__ pm, float* __restrict__ pl, float* __restrict__ po)
{
    int cc = blockIdx.x, h = blockIdx.y, b = blockIdx.z;
    int tid = threadIdx.x;
    __shared__ float qs[64], red[256], ps[256], ored[4][64];
    if (tid < 64) qs[tid] = qg[b * DD + h * 64 + tid];
    __syncthreads();
    int s = cc * 256 + tid;
    const unsigned short* kr = packed + (size_t)(b * SS + s) * 3840 + 3 * DD + h * 64;
    float a = 0.f;
#pragma unroll
    for (int d8 = 0; d8 < 8; d8++) {
        bf16x8 kv = *(const bf16x8*)(kr + d8 * 8);
#pragma unroll
        for (int e = 0; e < 8; e++)
            a = fmaf(qs[d8 * 8 + e], bf2f((unsigned short)kv[e]), a);
    }
    a *= 0.125f;
    float sv = (mask[b * SS + s] > 0) ? a : -1e9f;
    red[tid] = sv; __syncthreads();
    for (int o = 128; o > 0; o >>= 1) {
        if (tid < o) red[tid] = fmaxf(red[tid], red[tid + o]);
        __syncthreads();
    }
    float mx = red[0]; __syncthreads();
    float p = __expf(sv - mx);
    ps[tid] = p;
    red[tid] = p; __syncthreads();
    for (int o = 128; o > 0; o >>= 1) {
        if (tid < o) red[tid] += red[tid + o];
        __syncthreads();
    }
    float ls = red[0];
    int d = tid & 63, grp = tid >> 6;
    const unsigned short* vgb = packed + 4 * DD + h * 64 + d;
    float oa = 0.f;
    for (int t = 0; t < 64; t++) {
        int srow = cc * 256 + grp * 64 + t;
        oa = fmaf(ps[grp * 64 + t], bf2f(vgb[(size_t)(b * SS + srow) * 3840]), oa);
    }
    ored[grp][d] = oa; __syncthreads();
    if (tid < 64) {
        int idx = (b * HH + h) * 16 + cc;
        po[(size_t)idx * 64 + tid] = ored[0][tid] + ored[1][tid] + ored[2][tid] + ored[3][tid];
        if (tid == 0) { pm[idx] = mx; pl[idx] = ls; }
    }
}

// ---------------- global-token attention, phase 2: combine + write row 0 ----------------
__global__ __launch_bounds__(64) void gattn2_k(const float* __restrict__ pm,
        const float* __restrict__ pl, const float* __restrict__ po,
        unsigned short* __restrict__ O)
{
    int h = blockIdx.x, b = blockIdx.y;
    int tid = threadIdx.x;
    int base = (b * HH + h) * 16;
    float mx = -1e30f;
    for (int c2 = 0; c2 < 16; c2++) mx = fmaxf(mx, pm[base + c2]);
    float den = 0.f, oa = 0.f;
    for (int c2 = 0; c2 < 16; c2++) {
        float w = __expf(pm[base + c2] - mx);
        den = fmaf(pl[base + c2], w, den);
        oa = fmaf(po[(size_t)(base + c2) * 64 + tid], w, oa);
    }
    O[(size_t)(b * SS) * DD + h * 64 + tid] = bfb(oa / den);
}

// ---------------- qg = x[:,0,:] @ Wqg + bqg ----------------
__global__ __launch_bounds__(64) void qg_k(const float* __restrict__ x,
        const float* __restrict__ Wg, const float* __restrict__ bg,
        float* __restrict__ qg)
{
    int b = blockIdx.y;
    int col = blockIdx.x * 64 + threadIdx.x;
    const float* xr = x + (size_t)b * SS * DD;
    float a = bg[col];
    for (int k2 = 0; k2 < DD; k2++)
        a = fmaf(xr[k2], Wg[(size_t)k2 * DD + col], a);
    qg[b * DD + col] = a;
}

// ---------------- pooler (tanh) + classifier ----------------
__global__ __launch_bounds__(256) void pooler_cls_k(const float* __restrict__ x,
        const float* __restrict__ Wp, const float* __restrict__ bp,
        const float* __restrict__ Wc, const float* __restrict__ bc,
        float* __restrict__ out)
{
    int b = blockIdx.x;
    int tid = threadIdx.x;
    __shared__ float pooled[DD];
    const float* xr = x + (size_t)b * SS * DD;
    for (int col = tid; col < DD; col += 256) {
        float a = bp[col];
        for (int k2 = 0; k2 < DD; k2++)
            a = fmaf(xr[k2], Wp[(size_t)k2 * DD + col], a);
        pooled[col] = tanhf(a);
    }
    __syncthreads();
    if (tid < 2) {
        float a = bc[tid];
        for (int k2 = 0; k2 < DD; k2++)
            a = fmaf(pooled[k2], Wc[k2 * 2 + tid], a);
        out[b * 2 + tid] = a;
    }
}

extern "C" void kernel_launch(void* const* d_in, const int* in_sizes, int n_in,
                              void* d_out, int out_size, void* d_ws, size_t ws_size,
                              hipStream_t stream) {
    const int*   input_ids = (const int*)d_in[0];
    const int*   amask     = (const int*)d_in[1];
    const float* word_emb  = (const float*)d_in[2];
    const float* pos_emb   = (const float*)d_in[3];
    const float* ln_e_g    = (const float*)d_in[4];
    const float* ln_e_b    = (const float*)d_in[5];
    const float* Wq  = (const float*)d_in[6];  const float* bq  = (const float*)d_in[7];
    const float* Wk  = (const float*)d_in[8];  const float* bk  = (const float*)d_in[9];
    const float* Wv  = (const float*)d_in[10]; const float* bv  = (const float*)d_in[11];
    const float* Wqg = (const float*)d_in[12]; const float* bqg = (const float*)d_in[13];
    const float* Wkg = (const float*)d_in[14]; const float* bkg = (const float*)d_in[15];
    const float* Wvg = (const float*)d_in[16]; const float* bvg = (const float*)d_in[17];
    const float* Wo  = (const float*)d_in[18]; const float* bo  = (const float*)d_in[19];
    const float* ln1_g = (const float*)d_in[20]; const float* ln1_b = (const float*)d_in[21];
    const float* W1  = (const float*)d_in[22]; const float* bf1 = (const float*)d_in[23];
    const float* W2  = (const float*)d_in[24]; const float* bf2 = (const float*)d_in[25];
    const float* ln2_g = (const float*)d_in[26]; const float* ln2_b = (const float*)d_in[27];
    const float* Wp  = (const float*)d_in[28]; const float* bp  = (const float*)d_in[29];
    const float* Wc  = (const float*)d_in[30]; const float* bc  = (const float*)d_in[31];
    float* out = (float*)d_out;

    char* wsb = (char*)d_ws;
    float*          x      = (float*)(wsb + 0);                 // 25165824
    unsigned short* xbf    = (unsigned short*)(wsb + 25165824); // 12582912
    unsigned short* packed = (unsigned short*)(wsb + 37748736); // 62914560  [8192][3840]
    unsigned short* vtb    = (unsigned short*)(wsb + 100663296);// 12582912  [24*64][4096]
    unsigned short* aout   = (unsigned short*)(wsb + 113246208);// 12582912
    float*          hf     = (float*)(wsb + 125829120);         // 25165824
    char*           wts    = wsb + 150994944;                   // 33030144
    float*          b5     = (float*)(wsb + 184025088);         // 30720
    float*          qg     = (float*)(wsb + 184055808);         // 6144
    float*          pm     = (float*)(wsb + 184061952);         // 1536
    float*          pl     = (float*)(wsb + 184063488);         // 1536
    float*          po     = (float*)(wsb + 184065024);         // 98304
    unsigned short* mid    = packed;                            // FFN mid aliases packed

    const size_t SQ = (size_t)DD * DD;
    const size_t PER_L = (5 * SQ + SQ + (size_t)DD * FF + (size_t)DD * FF) * 2;
    unsigned short* Wt5[2], *Wo_t[2], *W1_t[2], *W2_t[2];
    for (int l = 0; l < 2; l++) {
        char* base = wts + (size_t)l * PER_L;
        Wt5[l]  = (unsigned short*)base;
        Wo_t[l] = (unsigned short*)(base + 5 * SQ * 2);
        W1_t[l] = (unsigned short*)(base + 6 * SQ * 2);
        W2_t[l] = (unsigned short*)(base + 6 * SQ * 2 + (size_t)DD * FF * 2);
    }

    const int M = BB * SS;
    dim3 tq(DD / 32, DD / 32);
    dim3 t1(FF / 32, DD / 32);
    dim3 t2(DD / 32, FF / 32);
    for (int l = 0; l < 2; l++) {
        transpose_bf16_k<<<tq, 256, 0, stream>>>(Wq  + (size_t)l * SQ, Wt5[l] + 0 * SQ, DD, DD);
        transpose_bf16_k<<<tq, 256, 0, stream>>>(Wk  + (size_t)l * SQ, Wt5[l] + 1 * SQ, DD, DD);
        transpose_bf16_k<<<tq, 256, 0, stream>>>(Wv  + (size_t)l * SQ, Wt5[l] + 2 * SQ, DD, DD);
        transpose_bf16_k<<<tq, 256, 0, stream>>>(Wkg + (size_t)l * SQ, Wt5[l] + 3 * SQ, DD, DD);
        transpose_bf16_k<<<tq, 256, 0, stream>>>(Wvg + (size_t)l * SQ, Wt5[l] + 4 * SQ, DD, DD);
        transpose_bf16_k<<<tq, 256, 0, stream>>>(Wo  + (size_t)l * SQ, Wo_t[l], DD, DD);
        transpose_bf16_k<<<t1, 256, 0, stream>>>(W1  + (size_t)l * DD * FF, W1_t[l], DD, FF);
        transpose_bf16_k<<<t2, 256, 0, stream>>>(W2  + (size_t)l * FF * DD, W2_t[l], FF, DD);
    }
    pack_bias5_k<<<(2 * 5 * DD + 255) / 256, 256, 0, stream>>>(bq, bk, bv, bkg, bvg, b5);

    embed_ln_k<<<M, 256, 0, stream>>>(input_ids, word_emb, pos_emb, ln_e_g, ln_e_b, x, xbf);

    dim3 gqkv(M / 128, 3840 / 128);
    dim3 g768(M / 128, DD / 128);
    dim3 g3072(M / 128, FF / 128);

    for (int l = 0; l < 2; l++) {
        const float* Wqg_l = Wqg + (size_t)l * SQ; const float* bqg_l = bqg + (size_t)l * DD;
        const float* bo_l  = bo  + (size_t)l * DD;
        const float* bf1_l = bf1 + (size_t)l * FF;
        const float* bf2_l = bf2 + (size_t)l * DD;
        const float* g1_l  = ln1_g + (size_t)l * DD; const float* b1_l = ln1_b + (size_t)l * DD;
        const float* g2_l  = ln2_g + (size_t)l * DD; const float* b2_l = ln2_b + (size_t)l * DD;

        mfma_gemm_k<1, 0><<<gqkv, 256, 0, stream>>>(xbf, Wt5[l], b5 + (size_t)l * 3840,
                                                    packed, M, 3840, DD);
        vtrans_k<<<dim3(SS / 64, HH, BB), 256, 0, stream>>>(packed, vtb);
        qg_k<<<dim3(DD / 64, BB), 64, 0, stream>>>(x, Wqg_l, bqg_l, qg);

        swin_mfma_k<<<dim3(CC, HH, BB), 256, 0, stream>>>(packed, vtb, amask, aout);
        gattn1_k<<<dim3(16, HH, BB), 256, 0, stream>>>(qg, packed, amask, pm, pl, po);
        gattn2_k<<<dim3(HH, BB), 64, 0, stream>>>(pm, pl, po, aout);

        mfma_gemm_k<0, 0><<<g768, 256, 0, stream>>>(aout, Wo_t[l], bo_l, hf, M, DD, DD);
        add_ln_k<<<M, 256, 0, stream>>>(x, hf, g1_l, b1_l, x, xbf);

        mfma_gemm_k<1, 1><<<g3072, 256, 0, stream>>>(xbf, W1_t[l], bf1_l, mid, M, FF, DD);
        mfma_gemm_k<0, 0><<<g768, 256, 0, stream>>>(mid, W2_t[l], bf2_l, hf, M, DD, FF);
        add_ln_k<<<M, 256, 0, stream>>>(x, hf, g2_l, b2_l, x, xbf);
    }

    pooler_cls_k<<<BB, 256, 0, stream>>>(x, Wp, bp, Wc, bc, out);
}

// Round 5
// 885.546 us; speedup vs baseline: 6.6827x; 1.3020x over previous
//
#include <hip/hip_runtime.h>
#include <hip/hip_bf16.h>
#include <math.h>

#define BB 2
#define SS 4096
#define DD 768
#define HH 12
#define DHH 64
#define WW 256
#define CC 16
#define FF 3072

typedef __attribute__((ext_vector_type(8))) short bf16x8;
typedef __attribute__((ext_vector_type(4))) float f32x4;

__device__ __forceinline__ float gelu_f(float x) {
    float x3 = x * x * x;
    return 0.5f * x * (1.0f + tanhf(0.7978845608028654f * (x + 0.044715f * x3)));
}

__device__ __forceinline__ unsigned short bfb(float f) {
    __hip_bfloat16 h = __float2bfloat16(f);
    return *(unsigned short*)&h;
}

__device__ __forceinline__ float bf2f(unsigned short u) {
    return __uint_as_float(((unsigned int)u) << 16);
}

__device__ __forceinline__ void gload16(const void* g, void* l) {
    __builtin_amdgcn_global_load_lds(
        (const __attribute__((address_space(1))) unsigned int*)g,
        (__attribute__((address_space(3))) unsigned int*)l, 16, 0, 0);
}

// ---------------- weight fp32 [K][N] -> bf16 W^T [N][K] ----------------
__global__ __launch_bounds__(256) void transpose_bf16_k(const float* __restrict__ Wsrc,
        unsigned short* __restrict__ Wt, int K, int N)
{
    __shared__ float t[32][33];
    int n0 = blockIdx.x * 32, k0 = blockIdx.y * 32;
    int tx = threadIdx.x & 31, ty = threadIdx.x >> 5;   // 32 x 8
#pragma unroll
    for (int i = 0; i < 32; i += 8)
        t[ty + i][tx] = Wsrc[(size_t)(k0 + ty + i) * N + n0 + tx];
    __syncthreads();
#pragma unroll
    for (int i = 0; i < 32; i += 8)
        Wt[(size_t)(n0 + ty + i) * K + k0 + tx] = bfb(t[tx][ty + i]);
}

// ---------------- pack 5 bias vectors [2][768] each -> [2][3840] ----------------
__global__ __launch_bounds__(256) void pack_bias5_k(const float* __restrict__ b0,
        const float* __restrict__ b1, const float* __restrict__ b2,
        const float* __restrict__ b3, const float* __restrict__ b4,
        float* __restrict__ dst)
{
    int gid = blockIdx.x * 256 + threadIdx.x;
    if (gid >= 2 * 5 * DD) return;
    int l = gid / (5 * DD), r = gid % (5 * DD), seg = r / DD, i = r % DD;
    const float* srcs[5] = { b0, b1, b2, b3, b4 };
    dst[gid] = srcs[seg][l * DD + i];
}

// ---------------- embedding + LayerNorm (fp32 x + bf16 x) ----------------
__global__ __launch_bounds__(256) void embed_ln_k(const int* __restrict__ ids,
        const float* __restrict__ wemb, const float* __restrict__ pemb,
        const float* __restrict__ g, const float* __restrict__ bta,
        float* __restrict__ x, unsigned short* __restrict__ xbf)
{
    int row = blockIdx.x;
    int s = row & (SS - 1);
    int tid = threadIdx.x;
    __shared__ float r1[256], r2[256];
    const float* we = wemb + (size_t)ids[row] * DD;
    const float* pe = pemb + (size_t)s * DD;
    float v[3]; float sum = 0.f, sq = 0.f;
#pragma unroll
    for (int i = 0; i < 3; i++) {
        int c = tid + i * 256;
        v[i] = we[c] + pe[c];
        sum += v[i]; sq += v[i] * v[i];
    }
    r1[tid] = sum; r2[tid] = sq; __syncthreads();
    for (int o = 128; o > 0; o >>= 1) {
        if (tid < o) { r1[tid] += r1[tid + o]; r2[tid] += r2[tid + o]; }
        __syncthreads();
    }
    float mean = r1[0] * (1.f / DD);
    float var = r2[0] * (1.f / DD) - mean * mean;
    float rstd = rsqrtf(var + 1e-5f);
#pragma unroll
    for (int i = 0; i < 3; i++) {
        int c = tid + i * 256;
        float o = (v[i] - mean) * rstd * g[c] + bta[c];
        x[(size_t)row * DD + c] = o;
        xbf[(size_t)row * DD + c] = bfb(o);
    }
}

// ---------------- residual add + LayerNorm (dual write) ----------------
__global__ __launch_bounds__(256) void add_ln_k(const float* __restrict__ xin,
        const float* __restrict__ hin, const float* __restrict__ g,
        const float* __restrict__ bta, float* __restrict__ xout,
        unsigned short* __restrict__ xbf)
{
    int row = blockIdx.x;
    int tid = threadIdx.x;
    __shared__ float r1[256], r2[256];
    const float* xr = xin + (size_t)row * DD;
    const float* hr = hin + (size_t)row * DD;
    float v[3]; float sum = 0.f, sq = 0.f;
#pragma unroll
    for (int i = 0; i < 3; i++) {
        int c = tid + i * 256;
        v[i] = xr[c] + hr[c];
        sum += v[i]; sq += v[i] * v[i];
    }
    r1[tid] = sum; r2[tid] = sq; __syncthreads();
    for (int o = 128; o > 0; o >>= 1) {
        if (tid < o) { r1[tid] += r1[tid + o]; r2[tid] += r2[tid + o]; }
        __syncthreads();
    }
    float mean = r1[0] * (1.f / DD);
    float var = r2[0] * (1.f / DD) - mean * mean;
    float rstd = rsqrtf(var + 1e-5f);
#pragma unroll
    for (int i = 0; i < 3; i++) {
        int c = tid + i * 256;
        float o = (v[i] - mean) * rstd * g[c] + bta[c];
        xout[(size_t)row * DD + c] = o;
        xbf[(size_t)row * DD + c] = bfb(o);
    }
}

// ---------------- bf16 MFMA GEMM: C = A[M,K] @ Bt[N,K]^T + bias ----------------
template<int OUT_BF16, int ACT_GELU>
__global__ __launch_bounds__(256) void mfma_gemm_k(
        const unsigned short* __restrict__ A,
        const unsigned short* __restrict__ Bt,
        const float* __restrict__ bias,
        void* __restrict__ Cv, int M, int N, int K)
{
    __shared__ short As[128 * 32];
    __shared__ short Bs[128 * 32];
    const int tid = threadIdx.x;
    const int lane = tid & 63, wv = tid >> 6;
    const int bm = blockIdx.x * 128, bn = blockIdx.y * 128;
    const int wm = wv >> 1, wn = wv & 1;

    const int off0 = wv * 1024 + lane * 16;
    const int off1 = off0 + 4096;
    const int r0 = off0 >> 6, c0 = (off0 & 63) >> 1;
    const int r1 = off1 >> 6, c1 = (off1 & 63) >> 1;
    const unsigned short* Abase = A + (size_t)bm * K;
    const unsigned short* Bbase = Bt + (size_t)bn * K;

    f32x4 acc[4][4];
#pragma unroll
    for (int i = 0; i < 4; i++)
#pragma unroll
        for (int j = 0; j < 4; j++) acc[i][j] = (f32x4){0.f, 0.f, 0.f, 0.f};

    const int lr = lane & 15;
    const int lk = (lane >> 4) * 8;

    for (int k0 = 0; k0 < K; k0 += 32) {
        __syncthreads();
        gload16(Abase + (size_t)r0 * K + k0 + c0, (char*)As + off0);
        gload16(Abase + (size_t)r1 * K + k0 + c1, (char*)As + off1);
        gload16(Bbase + (size_t)r0 * K + k0 + c0, (char*)Bs + off0);
        gload16(Bbase + (size_t)r1 * K + k0 + c1, (char*)Bs + off1);
        __syncthreads();
        bf16x8 af[4], bfr[4];
#pragma unroll
        for (int i = 0; i < 4; i++)
            af[i] = *(const bf16x8*)&As[(wm * 64 + i * 16 + lr) * 32 + lk];
#pragma unroll
        for (int j = 0; j < 4; j++)
            bfr[j] = *(const bf16x8*)&Bs[(wn * 64 + j * 16 + lr) * 32 + lk];
#pragma unroll
        for (int i = 0; i < 4; i++)
#pragma unroll
            for (int j = 0; j < 4; j++)
                acc[i][j] = __builtin_amdgcn_mfma_f32_16x16x32_bf16(af[i], bfr[j], acc[i][j], 0, 0, 0);
    }

    const int rq = lane >> 4;
#pragma unroll
    for (int j = 0; j < 4; j++) {
        int col = bn + wn * 64 + j * 16 + lr;
        float bv = bias[col];
#pragma unroll
        for (int i = 0; i < 4; i++) {
            int rowb = bm + wm * 64 + i * 16 + rq * 4;
#pragma unroll
            for (int r = 0; r < 4; r++) {
                float o = acc[i][j][r] + bv;
                if (ACT_GELU) o = gelu_f(o);
                if (OUT_BF16)
                    ((unsigned short*)Cv)[(size_t)(rowb + r) * N + col] = bfb(o);
                else
                    ((float*)Cv)[(size_t)(rowb + r) * N + col] = o;
            }
        }
    }
}

// ---------------- V head-transpose ----------------
__global__ __launch_bounds__(256) void vtrans_k(const unsigned short* __restrict__ packed,
        unsigned short* __restrict__ vt)
{
    int s0 = blockIdx.x * 64, h = blockIdx.y, b = blockIdx.z;
    int tid = threadIdx.x;
    __shared__ unsigned short t[64][72];
    int r = tid >> 3, dc = (tid & 7) * 8;
#pragma unroll
    for (int half = 0; half < 2; half++) {
        int rr = r + half * 32;
        const unsigned short* src = packed + (size_t)(b * SS + s0 + rr) * 3840 + 2 * DD + h * 64 + dc;
        *(uint4*)&t[rr][dc] = *(const uint4*)src;
    }
    __syncthreads();
    int d = tid >> 3, sc = (tid & 7) * 8;
#pragma unroll
    for (int half = 0; half < 2; half++) {
        int dd2 = d + half * 32;
        unsigned short v[8];
#pragma unroll
        for (int e = 0; e < 8; e++) v[e] = t[sc + e][dd2];
        unsigned short* dst = vt + (size_t)((b * HH + h) * 64 + dd2) * SS + s0 + sc;
        *(uint4*)dst = *(uint4*)v;
    }
}

// ---------------- MFMA sliding-window flash attention ----------------
__global__ __launch_bounds__(256) void swin_mfma_k(
        const unsigned short* __restrict__ packed,
        const unsigned short* __restrict__ vt,
        const int* __restrict__ mask,
        unsigned short* __restrict__ O)
{
    __shared__ __align__(16) char smem[51456];
    const int c = blockIdx.x, h = blockIdx.y, b = blockIdx.z;
    const int tid = threadIdx.x;
    const int lane = tid & 63, wv = tid >> 6;
    const int l15 = lane & 15, g = lane >> 4;
    const int bh = b * HH + h;

    char* KT = smem;
    char* VT = smem + 8192;
    char* PB = smem + 16384 + wv * 8192;
    float* maskf = (float*)(smem + 49152);
    float* sA = (float*)(smem + 49408);
    float* sB = (float*)(smem + 50432);

    bf16x8 qf[4][2];
#pragma unroll
    for (int j = 0; j < 4; j++)
#pragma unroll
        for (int kk = 0; kk < 2; kk++)
            qf[j][kk] = *(const bf16x8*)(packed +
                (size_t)(b * SS + c * WW + wv * 64 + j * 16 + l15) * 3840 + h * 64 + kk * 32 + g * 8);
    bf16x8 gkf[2];
#pragma unroll
    for (int kk = 0; kk < 2; kk++)
        gkf[kk] = *(const bf16x8*)(packed + (size_t)(b * SS) * 3840 + DD + h * 64 + kk * 32 + g * 8);
    float v0r[4];
#pragma unroll
    for (int jd = 0; jd < 4; jd++)
        v0r[jd] = bf2f(vt[(size_t)(bh * 64 + jd * 16 + l15) * SS]);

    f32x4 o_[4][4];
#pragma unroll
    for (int i = 0; i < 4; i++)
#pragma unroll
        for (int j = 0; j < 4; j++) o_[i][j] = (f32x4){0.f, 0.f, 0.f, 0.f};
    float m_[4] = { -1e20f, -1e20f, -1e20f, -1e20f };
    float l_[4] = { 0.f, 0.f, 0.f, 0.f };

    const int rswz = (l15 & 7) << 4;
    const int kt_s = (c == 0) ? 4 : 0;
    const int kt_e = (c == CC - 1) ? 8 : 12;

    for (int kt = kt_s; kt < kt_e; kt++) {
        const int kpos0 = c * WW - WW + kt * 64;
        {
            int off = tid * 16;
#pragma unroll
            for (int ch = 0; ch < 2; ch++) {
                int o2 = off + ch * 4096;
                int row = o2 >> 7, bc = o2 & 127;
                int srcc = bc ^ ((row & 7) << 4);
                gload16((const char*)packed + (size_t)(b * SS + kpos0 + row) * 7680 + 1536 + h * 128 + srcc,
                        KT + o2);
                gload16((const char*)vt + (size_t)(bh * 64 + row) * 8192 + (size_t)(kpos0 * 2 + srcc),
                        VT + o2);
            }
            if (tid < 64) {
                int kp = kpos0 + tid;
                maskf[tid] = (mask[b * SS + kp] > 0) ? 0.f : -1e30f;
            }
        }
        __syncthreads();

        f32x4 mrd[4];
#pragma unroll
        for (int i = 0; i < 4; i++)
            mrd[i] = *(const f32x4*)&maskf[i * 16 + g * 4];

        f32x4 s_[4][4];
#pragma unroll
        for (int i = 0; i < 4; i++)
#pragma unroll
            for (int j = 0; j < 4; j++) s_[i][j] = (f32x4){0.f, 0.f, 0.f, 0.f};
#pragma unroll
        for (int kk = 0; kk < 2; kk++) {
            bf16x8 af[4];
#pragma unroll
            for (int i = 0; i < 4; i++)
                af[i] = *(const bf16x8*)(KT + (i * 16 + l15) * 128 + ((kk * 64 + g * 16) ^ rswz));
#pragma unroll
            for (int i = 0; i < 4; i++)
#pragma unroll
                for (int j = 0; j < 4; j++)
                    s_[i][j] = __builtin_amdgcn_mfma_f32_16x16x32_bf16(af[i], qf[j][kk], s_[i][j], 0, 0, 0);
        }

#pragma unroll
        for (int j = 0; j < 4; j++) {
            float tm = -1e30f;
#pragma unroll
            for (int i = 0; i < 4; i++) {
#pragma unroll
                for (int r = 0; r < 4; r++) {
                    float v = fmaf(s_[i][j][r], 0.125f, mrd[i][r]);
                    int rel = kt * 64 - WW + i * 16 + g * 4 + r - wv * 64 - j * 16 - l15;
                    v = (rel > WW || rel < -WW) ? -1e30f : v;
                    s_[i][j][r] = v;
                    tm = fmaxf(tm, v);
                }
            }
            tm = fmaxf(tm, __shfl_xor(tm, 16));
            tm = fmaxf(tm, __shfl_xor(tm, 32));
            float mn = fmaxf(m_[j], tm);
            float fac = __expf(m_[j] - mn);
            m_[j] = mn;
            float ls = 0.f;
            int q = j * 16 + l15;
#pragma unroll
            for (int i = 0; i < 4; i++) {
                float p0 = __expf(s_[i][j][0] - mn);
                float p1 = __expf(s_[i][j][1] - mn);
                float p2 = __expf(s_[i][j][2] - mn);
                float p3 = __expf(s_[i][j][3] - mn);
                ls += (p0 + p1) + (p2 + p3);
                uint2 pw;
                pw.x = (unsigned int)bfb(p0) | ((unsigned int)bfb(p1) << 16);
                pw.y = (unsigned int)bfb(p2) | ((unsigned int)bfb(p3) << 16);
                *(uint2*)(PB + q * 128 + ((i * 32 + g * 8) ^ rswz)) = pw;
            }
            ls += __shfl_xor(ls, 16);
            ls += __shfl_xor(ls, 32);
            l_[j] = l_[j] * fac + ls;
            if (g == 0) sA[wv * 64 + q] = fac;
        }

#pragma unroll
        for (int iq = 0; iq < 4; iq++) {
            f32x4 fc = *(const f32x4*)&sA[wv * 64 + iq * 16 + g * 4];
#pragma unroll
            for (int jd = 0; jd < 4; jd++)
#pragma unroll
                for (int r = 0; r < 4; r++) o_[iq][jd][r] *= fc[r];
        }
#pragma unroll
        for (int kk = 0; kk < 2; kk++) {
            bf16x8 pa[4], vb[4];
#pragma unroll
            for (int iq = 0; iq < 4; iq++)
                pa[iq] = *(const bf16x8*)(PB + (iq * 16 + l15) * 128 + ((kk * 64 + g * 16) ^ rswz));
#pragma unroll
            for (int jd = 0; jd < 4; jd++)
                vb[jd] = *(const bf16x8*)(VT + (jd * 16 + l15) * 128 + ((kk * 64 + g * 16) ^ rswz));
#pragma unroll
            for (int iq = 0; iq < 4; iq++)
#pragma unroll
                for (int jd = 0; jd < 4; jd++)
                    o_[iq][jd] = __builtin_amdgcn_mfma_f32_16x16x32_bf16(pa[iq], vb[jd], o_[iq][jd], 0, 0, 0);
        }
        __syncthreads();
    }

#pragma unroll
    for (int j = 0; j < 4; j++) {
        float pd = 0.f;
#pragma unroll
        for (int kk = 0; kk < 2; kk++)
#pragma unroll
            for (int e = 0; e < 8; e++)
                pd += bf2f((unsigned short)qf[j][kk][e]) * bf2f((unsigned short)gkf[kk][e]);
        pd += __shfl_xor(pd, 16);
        pd += __shfl_xor(pd, 32);
        float sg = pd * 0.125f;
        float mf = fmaxf(m_[j], sg);
        float fac = __expf(m_[j] - mf);
        float pg = __expf(sg - mf);
        float lf = l_[j] * fac + pg;
        float inv = 1.f / lf;
        if (g == 0) {
            sA[wv * 64 + j * 16 + l15] = fac * inv;
            sB[wv * 64 + j * 16 + l15] = pg * inv;
        }
    }
#pragma unroll
    for (int iq = 0; iq < 4; iq++) {
        f32x4 fA = *(const f32x4*)&sA[wv * 64 + iq * 16 + g * 4];
        f32x4 fB = *(const f32x4*)&sB[wv * 64 + iq * 16 + g * 4];
#pragma unroll
        for (int jd = 0; jd < 4; jd++) {
#pragma unroll
            for (int r = 0; r < 4; r++) {
                float val = o_[iq][jd][r] * fA[r] + fB[r] * v0r[jd];
                int row = b * SS + c * WW + wv * 64 + iq * 16 + g * 4 + r;
                O[(size_t)row * DD + h * 64 + jd * 16 + l15] = bfb(val);
            }
        }
    }
}

// ---------------- global-token attention, phase 1 ----------------
__global__ __launch_bounds__(256) void gattn1_k(const float* __restrict__ qg,
        const unsigned short* __restrict__ packed, const int* __restrict__ mask,
        float* __restrict__ pm, float* __restrict__ pl, float* __restrict__ po)
{
    int cc = blockIdx.x, h = blockIdx.y, b = blockIdx.z;
    int tid = threadIdx.x;
    __shared__ float qs[64], red[256], ps[256], ored[4][64];
    if (tid < 64) qs[tid] = qg[b * DD + h * 64 + tid];
    __syncthreads();
    int s = cc * 256 + tid;
    const unsigned short* kr = packed + (size_t)(b * SS + s) * 3840 + 3 * DD + h * 64;
    float a = 0.f;
#pragma unroll
    for (int d8 = 0; d8 < 8; d8++) {
        bf16x8 kv = *(const bf16x8*)(kr + d8 * 8);
#pragma unroll
        for (int e = 0; e < 8; e++)
            a = fmaf(qs[d8 * 8 + e], bf2f((unsigned short)kv[e]), a);
    }
    a *= 0.125f;
    float sv = (mask[b * SS + s] > 0) ? a : -1e9f;
    red[tid] = sv; __syncthreads();
    for (int o = 128; o > 0; o >>= 1) {
        if (tid < o) red[tid] = fmaxf(red[tid], red[tid + o]);
        __syncthreads();
    }
    float mx = red[0]; __syncthreads();
    float p = __expf(sv - mx);
    ps[tid] = p;
    red[tid] = p; __syncthreads();
    for (int o = 128; o > 0; o >>= 1) {
        if (tid < o) red[tid] += red[tid + o];
        __syncthreads();
    }
    float ls = red[0];
    int d = tid & 63, grp = tid >> 6;
    const unsigned short* vgb = packed + 4 * DD + h * 64 + d;
    float oa = 0.f;
    for (int t = 0; t < 64; t++) {
        int srow = cc * 256 + grp * 64 + t;
        oa = fmaf(ps[grp * 64 + t], bf2f(vgb[(size_t)(b * SS + srow) * 3840]), oa);
    }
    ored[grp][d] = oa; __syncthreads();
    if (tid < 64) {
        int idx = (b * HH + h) * 16 + cc;
        po[(size_t)idx * 64 + tid] = ored[0][tid] + ored[1][tid] + ored[2][tid] + ored[3][tid];
        if (tid == 0) { pm[idx] = mx; pl[idx] = ls; }
    }
}

// ---------------- global-token attention, phase 2 ----------------
__global__ __launch_bounds__(64) void gattn2_k(const float* __restrict__ pm,
        const float* __restrict__ pl, const float* __restrict__ po,
        unsigned short* __restrict__ O)
{
    int h = blockIdx.x, b = blockIdx.y;
    int tid = threadIdx.x;
    int base = (b * HH + h) * 16;
    float mx = -1e30f;
    for (int c2 = 0; c2 < 16; c2++) mx = fmaxf(mx, pm[base + c2]);
    float den = 0.f, oa = 0.f;
    for (int c2 = 0; c2 < 16; c2++) {
        float w = __expf(pm[base + c2] - mx);
        den = fmaf(pl[base + c2], w, den);
        oa = fmaf(po[(size_t)(base + c2) * 64 + tid], w, oa);
    }
    O[(size_t)(b * SS) * DD + h * 64 + tid] = bfb(oa / den);
}

// ---------------- row-GEMV: dst[b][col] = act( bias[col] + xrow[b] . W[:,col] ) ----------------
// grid (N/64, B), block 256 = 64 cols x 4 k-parts. W is [K][N] fp32 row-major.
template<int ACT_TANH>
__global__ __launch_bounds__(256) void rowgemv_k(const float* __restrict__ x,
        size_t xstride, const float* __restrict__ W, const float* __restrict__ bias,
        float* __restrict__ dst, int N)
{
    int b = blockIdx.y;
    int colL = threadIdx.x & 63, part = threadIdx.x >> 6;
    int col = blockIdx.x * 64 + colL;
    __shared__ float partial[4][64];
    const float* xr = x + (size_t)b * xstride;
    float a = 0.f;
    for (int k = part * (DD / 4); k < (part + 1) * (DD / 4); k++)
        a = fmaf(xr[k], W[(size_t)k * N + col], a);
    partial[part][colL] = a; __syncthreads();
    if (part == 0) {
        float s = partial[0][colL] + partial[1][colL] + partial[2][colL] + partial[3][colL]
                + bias[col];
        if (ACT_TANH) s = tanhf(s);
        dst[b * N + col] = s;
    }
}

// ---------------- classifier: out[b][cls] = pooled[b] . Wc[:,cls] + bc  (one block) ----------------
__global__ __launch_bounds__(256) void cls_k(const float* __restrict__ pooled,
        const float* __restrict__ Wc, const float* __restrict__ bc,
        float* __restrict__ out)
{
    int lane = threadIdx.x & 63, pair = threadIdx.x >> 6;  // 4 pairs: b*2+cls
    int b = pair >> 1, cls = pair & 1;
    float a = 0.f;
#pragma unroll
    for (int j = 0; j < 12; j++) {
        int k = lane + j * 64;
        a = fmaf(pooled[b * DD + k], Wc[k * 2 + cls], a);
    }
#pragma unroll
    for (int o = 1; o < 64; o <<= 1) a += __shfl_xor(a, o);
    if (lane == 0) out[b * 2 + cls] = a + bc[cls];
}

extern "C" void kernel_launch(void* const* d_in, const int* in_sizes, int n_in,
                              void* d_out, int out_size, void* d_ws, size_t ws_size,
                              hipStream_t stream) {
    const int*   input_ids = (const int*)d_in[0];
    const int*   amask     = (const int*)d_in[1];
    const float* word_emb  = (const float*)d_in[2];
    const float* pos_emb   = (const float*)d_in[3];
    const float* ln_e_g    = (const float*)d_in[4];
    const float* ln_e_b    = (const float*)d_in[5];
    const float* Wq  = (const float*)d_in[6];  const float* bq  = (const float*)d_in[7];
    const float* Wk  = (const float*)d_in[8];  const float* bk  = (const float*)d_in[9];
    const float* Wv  = (const float*)d_in[10]; const float* bv  = (const float*)d_in[11];
    const float* Wqg = (const float*)d_in[12]; const float* bqg = (const float*)d_in[13];
    const float* Wkg = (const float*)d_in[14]; const float* bkg = (const float*)d_in[15];
    const float* Wvg = (const float*)d_in[16]; const float* bvg = (const float*)d_in[17];
    const float* Wo  = (const float*)d_in[18]; const float* bo  = (const float*)d_in[19];
    const float* ln1_g = (const float*)d_in[20]; const float* ln1_b = (const float*)d_in[21];
    const float* W1  = (const float*)d_in[22]; const float* bf1 = (const float*)d_in[23];
    const float* W2  = (const float*)d_in[24]; const float* bf2 = (const float*)d_in[25];
    const float* ln2_g = (const float*)d_in[26]; const float* ln2_b = (const float*)d_in[27];
    const float* Wp  = (const float*)d_in[28]; const float* bp  = (const float*)d_in[29];
    const float* Wc  = (const float*)d_in[30]; const float* bc  = (const float*)d_in[31];
    float* out = (float*)d_out;

    char* wsb = (char*)d_ws;
    float*          x      = (float*)(wsb + 0);                 // 25165824
    unsigned short* xbf    = (unsigned short*)(wsb + 25165824); // 12582912
    unsigned short* packed = (unsigned short*)(wsb + 37748736); // 62914560  [8192][3840]
    unsigned short* vtb    = (unsigned short*)(wsb + 100663296);// 12582912  [24*64][4096]
    unsigned short* aout   = (unsigned short*)(wsb + 113246208);// 12582912
    float*          hf     = (float*)(wsb + 125829120);         // 25165824
    char*           wts    = wsb + 150994944;                   // 33030144
    float*          b5     = (float*)(wsb + 184025088);         // 30720
    float*          qg     = (float*)(wsb + 184055808);         // 6144
    float*          pm     = (float*)(wsb + 184061952);         // 1536
    float*          pl     = (float*)(wsb + 184063488);         // 1536
    float*          po     = (float*)(wsb + 184065024);         // 98304
    float*          pooled = (float*)(wsb + 184163328);         // 6144
    unsigned short* mid    = packed;

    const size_t SQ = (size_t)DD * DD;
    const size_t PER_L = (5 * SQ + SQ + (size_t)DD * FF + (size_t)DD * FF) * 2;
    unsigned short* Wt5[2], *Wo_t[2], *W1_t[2], *W2_t[2];
    for (int l = 0; l < 2; l++) {
        char* base = wts + (size_t)l * PER_L;
        Wt5[l]  = (unsigned short*)base;
        Wo_t[l] = (unsigned short*)(base + 5 * SQ * 2);
        W1_t[l] = (unsigned short*)(base + 6 * SQ * 2);
        W2_t[l] = (unsigned short*)(base + 6 * SQ * 2 + (size_t)DD * FF * 2);
    }

    const int M = BB * SS;
    dim3 tq(DD / 32, DD / 32);
    dim3 t1(FF / 32, DD / 32);
    dim3 t2(DD / 32, FF / 32);
    for (int l = 0; l < 2; l++) {
        transpose_bf16_k<<<tq, 256, 0, stream>>>(Wq  + (size_t)l * SQ, Wt5[l] + 0 * SQ, DD, DD);
        transpose_bf16_k<<<tq, 256, 0, stream>>>(Wk  + (size_t)l * SQ, Wt5[l] + 1 * SQ, DD, DD);
        transpose_bf16_k<<<tq, 256, 0, stream>>>(Wv  + (size_t)l * SQ, Wt5[l] + 2 * SQ, DD, DD);
        transpose_bf16_k<<<tq, 256, 0, stream>>>(Wkg + (size_t)l * SQ, Wt5[l] + 3 * SQ, DD, DD);
        transpose_bf16_k<<<tq, 256, 0, stream>>>(Wvg + (size_t)l * SQ, Wt5[l] + 4 * SQ, DD, DD);
        transpose_bf16_k<<<tq, 256, 0, stream>>>(Wo  + (size_t)l * SQ, Wo_t[l], DD, DD);
        transpose_bf16_k<<<t1, 256, 0, stream>>>(W1  + (size_t)l * DD * FF, W1_t[l], DD, FF);
        transpose_bf16_k<<<t2, 256, 0, stream>>>(W2  + (size_t)l * FF * DD, W2_t[l], FF, DD);
    }
    pack_bias5_k<<<(2 * 5 * DD + 255) / 256, 256, 0, stream>>>(bq, bk, bv, bkg, bvg, b5);

    embed_ln_k<<<M, 256, 0, stream>>>(input_ids, word_emb, pos_emb, ln_e_g, ln_e_b, x, xbf);

    dim3 gqkv(M / 128, 3840 / 128);
    dim3 g768(M / 128, DD / 128);
    dim3 g3072(M / 128, FF / 128);

    for (int l = 0; l < 2; l++) {
        const float* Wqg_l = Wqg + (size_t)l * SQ; const float* bqg_l = bqg + (size_t)l * DD;
        const float* bo_l  = bo  + (size_t)l * DD;
        const float* bf1_l = bf1 + (size_t)l * FF;
        const float* bf2_l = bf2 + (size_t)l * DD;
        const float* g1_l  = ln1_g + (size_t)l * DD; const float* b1_l = ln1_b + (size_t)l * DD;
        const float* g2_l  = ln2_g + (size_t)l * DD; const float* b2_l = ln2_b + (size_t)l * DD;

        mfma_gemm_k<1, 0><<<gqkv, 256, 0, stream>>>(xbf, Wt5[l], b5 + (size_t)l * 3840,
                                                    packed, M, 3840, DD);
        vtrans_k<<<dim3(SS / 64, HH, BB), 256, 0, stream>>>(packed, vtb);
        rowgemv_k<0><<<dim3(DD / 64, BB), 256, 0, stream>>>(x, (size_t)SS * DD, Wqg_l, bqg_l, qg, DD);

        swin_mfma_k<<<dim3(CC, HH, BB), 256, 0, stream>>>(packed, vtb, amask, aout);
        gattn1_k<<<dim3(16, HH, BB), 256, 0, stream>>>(qg, packed, amask, pm, pl, po);
        gattn2_k<<<dim3(HH, BB), 64, 0, stream>>>(pm, pl, po, aout);

        mfma_gemm_k<0, 0><<<g768, 256, 0, stream>>>(aout, Wo_t[l], bo_l, hf, M, DD, DD);
        add_ln_k<<<M, 256, 0, stream>>>(x, hf, g1_l, b1_l, x, xbf);

        mfma_gemm_k<1, 1><<<g3072, 256, 0, stream>>>(xbf, W1_t[l], bf1_l, mid, M, FF, DD);
        mfma_gemm_k<0, 0><<<g768, 256, 0, stream>>>(mid, W2_t[l], bf2_l, hf, M, DD, FF);
        add_ln_k<<<M, 256, 0, stream>>>(x, hf, g2_l, b2_l, x, xbf);
    }

    rowgemv_k<1><<<dim3(DD / 64, BB), 256, 0, stream>>>(x, (size_t)SS * DD, Wp, bp, pooled, DD);
    cls_k<<<1, 256, 0, stream>>>(pooled, Wc, bc, out);
}

// Round 7
// 820.675 us; speedup vs baseline: 7.2110x; 1.0790x over previous
//
#include <hip/hip_runtime.h>
#include <hip/hip_bf16.h>
#include <math.h>

#define BB 2
#define SS 4096
#define DD 768
#define HH 12
#define DHH 64
#define WW 256
#define CC 16
#define FF 3072

typedef __attribute__((ext_vector_type(8))) short bf16x8;
typedef __attribute__((ext_vector_type(4))) float f32x4;

struct TP12 { const float* s[12]; unsigned short* d[12]; };
struct TP4  { const float* s[4];  unsigned short* d[4];  };

__device__ __forceinline__ float gelu_f(float x) {
    float x3 = x * x * x;
    return 0.5f * x * (1.0f + tanhf(0.7978845608028654f * (x + 0.044715f * x3)));
}

__device__ __forceinline__ unsigned short bfb(float f) {
    __hip_bfloat16 h = __float2bfloat16(f);
    return *(unsigned short*)&h;
}

__device__ __forceinline__ float bf2f(unsigned short u) {
    return __uint_as_float(((unsigned int)u) << 16);
}

__device__ __forceinline__ void gload16(const void* g, void* l) {
    __builtin_amdgcn_global_load_lds(
        (const __attribute__((address_space(1))) unsigned int*)g,
        (__attribute__((address_space(3))) unsigned int*)l, 16, 0, 0);
}

// ---------------- fused weight transposes: fp32 [K][N] -> bf16 [N][K] ----------------
__global__ __launch_bounds__(256) void transpose12_k(TP12 p)
{
    __shared__ float t[32][33];
    int z = blockIdx.z;
    const float* Wsrc = p.s[z];
    unsigned short* Wt = p.d[z];
    const int K = DD, N = DD;
    int n0 = blockIdx.x * 32, k0 = blockIdx.y * 32;
    int tx = threadIdx.x & 31, ty = threadIdx.x >> 5;
#pragma unroll
    for (int i = 0; i < 32; i += 8)
        t[ty + i][tx] = Wsrc[(size_t)(k0 + ty + i) * N + n0 + tx];
    __syncthreads();
#pragma unroll
    for (int i = 0; i < 32; i += 8)
        Wt[(size_t)(n0 + ty + i) * K + k0 + tx] = bfb(t[tx][ty + i]);
}

__global__ __launch_bounds__(256) void transposeR4_k(TP4 p)
{
    __shared__ float t[32][33];
    int z = blockIdx.z;
    const float* Wsrc = p.s[z];
    unsigned short* Wt = p.d[z];
    int K, N, n0, k0;
    if (z < 2) { K = DD; N = FF; n0 = blockIdx.x * 32; k0 = blockIdx.y * 32; }
    else { K = FF; N = DD; int cell = blockIdx.y * 96 + blockIdx.x;
           n0 = (cell % 24) * 32; k0 = (cell / 24) * 32; }
    int tx = threadIdx.x & 31, ty = threadIdx.x >> 5;
#pragma unroll
    for (int i = 0; i < 32; i += 8)
        t[ty + i][tx] = Wsrc[(size_t)(k0 + ty + i) * N + n0 + tx];
    __syncthreads();
#pragma unroll
    for (int i = 0; i < 32; i += 8)
        Wt[(size_t)(n0 + ty + i) * K + k0 + tx] = bfb(t[tx][ty + i]);
}

// ---------------- pack 5 bias vectors [2][768] each -> [2][3840] ----------------
__global__ __launch_bounds__(256) void pack_bias5_k(const float* __restrict__ b0,
        const float* __restrict__ b1, const float* __restrict__ b2,
        const float* __restrict__ b3, const float* __restrict__ b4,
        float* __restrict__ dst)
{
    int gid = blockIdx.x * 256 + threadIdx.x;
    if (gid >= 2 * 5 * DD) return;
    int l = gid / (5 * DD), r = gid % (5 * DD), seg = r / DD, i = r % DD;
    const float* srcs[5] = { b0, b1, b2, b3, b4 };
    dst[gid] = srcs[seg][l * DD + i];
}

// ---------------- embedding + LayerNorm (fp32 x + bf16 x) ----------------
__global__ __launch_bounds__(256) void embed_ln_k(const int* __restrict__ ids,
        const float* __restrict__ wemb, const float* __restrict__ pemb,
        const float* __restrict__ g, const float* __restrict__ bta,
        float* __restrict__ x, unsigned short* __restrict__ xbf)
{
    int row = blockIdx.x;
    int s = row & (SS - 1);
    int tid = threadIdx.x;
    __shared__ float r1[256], r2[256];
    const float* we = wemb + (size_t)ids[row] * DD;
    const float* pe = pemb + (size_t)s * DD;
    float v[3]; float sum = 0.f, sq = 0.f;
#pragma unroll
    for (int i = 0; i < 3; i++) {
        int c = tid + i * 256;
        v[i] = we[c] + pe[c];
        sum += v[i]; sq += v[i] * v[i];
    }
    r1[tid] = sum; r2[tid] = sq; __syncthreads();
    for (int o = 128; o > 0; o >>= 1) {
        if (tid < o) { r1[tid] += r1[tid + o]; r2[tid] += r2[tid + o]; }
        __syncthreads();
    }
    float mean = r1[0] * (1.f / DD);
    float var = r2[0] * (1.f / DD) - mean * mean;
    float rstd = rsqrtf(var + 1e-5f);
#pragma unroll
    for (int i = 0; i < 3; i++) {
        int c = tid + i * 256;
        float o = (v[i] - mean) * rstd * g[c] + bta[c];
        x[(size_t)row * DD + c] = o;
        xbf[(size_t)row * DD + c] = bfb(o);
    }
}

// ---------------- residual add + LayerNorm (dual write) ----------------
__global__ __launch_bounds__(256) void add_ln_k(const float* __restrict__ xin,
        const float* __restrict__ hin, const float* __restrict__ g,
        const float* __restrict__ bta, float* __restrict__ xout,
        unsigned short* __restrict__ xbf)
{
    int row = blockIdx.x;
    int tid = threadIdx.x;
    __shared__ float r1[256], r2[256];
    const float* xr = xin + (size_t)row * DD;
    const float* hr = hin + (size_t)row * DD;
    float v[3]; float sum = 0.f, sq = 0.f;
#pragma unroll
    for (int i = 0; i < 3; i++) {
        int c = tid + i * 256;
        v[i] = xr[c] + hr[c];
        sum += v[i]; sq += v[i] * v[i];
    }
    r1[tid] = sum; r2[tid] = sq; __syncthreads();
    for (int o = 128; o > 0; o >>= 1) {
        if (tid < o) { r1[tid] += r1[tid + o]; r2[tid] += r2[tid + o]; }
        __syncthreads();
    }
    float mean = r1[0] * (1.f / DD);
    float var = r2[0] * (1.f / DD) - mean * mean;
    float rstd = rsqrtf(var + 1e-5f);
#pragma unroll
    for (int i = 0; i < 3; i++) {
        int c = tid + i * 256;
        float o = (v[i] - mean) * rstd * g[c] + bta[c];
        xout[(size_t)row * DD + c] = o;
        xbf[(size_t)row * DD + c] = bfb(o);
    }
}

// ---------------- bf16 MFMA GEMM: C = A[M,K] @ Bt[N,K]^T + bias (XCD-swizzled) ----------------
template<int OUT_BF16, int ACT_GELU>
__global__ __launch_bounds__(256) void mfma_gemm_k(
        const unsigned short* __restrict__ A,
        const unsigned short* __restrict__ Bt,
        const float* __restrict__ bias,
        void* __restrict__ Cv, int M, int N, int K)
{
    __shared__ short As[128 * 32];
    __shared__ short Bs[128 * 32];
    const int tid = threadIdx.x;
    const int lane = tid & 63, wv = tid >> 6;
    // XCD-aware bijective swizzle (all grids have nwg % 8 == 0)
    int nbx = gridDim.x;
    int nwg = nbx * gridDim.y;
    int lid = blockIdx.y * nbx + blockIdx.x;
    int nid = ((nwg & 7) == 0) ? ((lid & 7) * (nwg >> 3) + (lid >> 3)) : lid;
    const int bm = (nid % nbx) * 128, bn = (nid / nbx) * 128;
    const int wm = wv >> 1, wn = wv & 1;

    const int off0 = wv * 1024 + lane * 16;
    const int off1 = off0 + 4096;
    const int r0 = off0 >> 6, c0 = (off0 & 63) >> 1;
    const int r1 = off1 >> 6, c1 = (off1 & 63) >> 1;
    const unsigned short* Abase = A + (size_t)bm * K;
    const unsigned short* Bbase = Bt + (size_t)bn * K;

    f32x4 acc[4][4];
#pragma unroll
    for (int i = 0; i < 4; i++)
#pragma unroll
        for (int j = 0; j < 4; j++) acc[i][j] = (f32x4){0.f, 0.f, 0.f, 0.f};

    const int lr = lane & 15;
    const int lk = (lane >> 4) * 8;

    for (int k0 = 0; k0 < K; k0 += 32) {
        __syncthreads();
        gload16(Abase + (size_t)r0 * K + k0 + c0, (char*)As + off0);
        gload16(Abase + (size_t)r1 * K + k0 + c1, (char*)As + off1);
        gload16(Bbase + (size_t)r0 * K + k0 + c0, (char*)Bs + off0);
        gload16(Bbase + (size_t)r1 * K + k0 + c1, (char*)Bs + off1);
        __syncthreads();
        bf16x8 af[4], bfr[4];
#pragma unroll
        for (int i = 0; i < 4; i++)
            af[i] = *(const bf16x8*)&As[(wm * 64 + i * 16 + lr) * 32 + lk];
#pragma unroll
        for (int j = 0; j < 4; j++)
            bfr[j] = *(const bf16x8*)&Bs[(wn * 64 + j * 16 + lr) * 32 + lk];
#pragma unroll
        for (int i = 0; i < 4; i++)
#pragma unroll
            for (int j = 0; j < 4; j++)
                acc[i][j] = __builtin_amdgcn_mfma_f32_16x16x32_bf16(af[i], bfr[j], acc[i][j], 0, 0, 0);
    }

    const int rq = lane >> 4;
#pragma unroll
    for (int j = 0; j < 4; j++) {
        int col = bn + wn * 64 + j * 16 + lr;
        float bv = bias[col];
#pragma unroll
        for (int i = 0; i < 4; i++) {
            int rowb = bm + wm * 64 + i * 16 + rq * 4;
#pragma unroll
            for (int r = 0; r < 4; r++) {
                float o = acc[i][j][r] + bv;
                if (ACT_GELU) o = gelu_f(o);
                if (OUT_BF16)
                    ((unsigned short*)Cv)[(size_t)(rowb + r) * N + col] = bfb(o);
                else
                    ((float*)Cv)[(size_t)(rowb + r) * N + col] = o;
            }
        }
    }
}

// ---------------- V head-transpose ----------------
__global__ __launch_bounds__(256) void vtrans_k(const unsigned short* __restrict__ packed,
        unsigned short* __restrict__ vt)
{
    int s0 = blockIdx.x * 64, h = blockIdx.y, b = blockIdx.z;
    int tid = threadIdx.x;
    __shared__ unsigned short t[64][72];
    int r = tid >> 3, dc = (tid & 7) * 8;
#pragma unroll
    for (int half = 0; half < 2; half++) {
        int rr = r + half * 32;
        const unsigned short* src = packed + (size_t)(b * SS + s0 + rr) * 3840 + 2 * DD + h * 64 + dc;
        *(uint4*)&t[rr][dc] = *(const uint4*)src;
    }
    __syncthreads();
    int d = tid >> 3, sc = (tid & 7) * 8;
#pragma unroll
    for (int half = 0; half < 2; half++) {
        int dd2 = d + half * 32;
        unsigned short v[8];
#pragma unroll
        for (int e = 0; e < 8; e++) v[e] = t[sc + e][dd2];
        unsigned short* dst = vt + (size_t)((b * HH + h) * 64 + dd2) * SS + s0 + sc;
        *(uint4*)dst = *(uint4*)v;
    }
}

// ---------------- MFMA sliding-window flash attention (128-q blocks, dbuf pipeline) ----------------
__global__ __launch_bounds__(256) void swin_mfma_k(
        const unsigned short* __restrict__ packed,
        const unsigned short* __restrict__ vt,
        const int* __restrict__ mask,
        unsigned short* __restrict__ O)
{
    __shared__ __align__(16) char smem[52736];
    const int c2 = blockIdx.x, h = blockIdx.y, b = blockIdx.z;
    const int tid = threadIdx.x;
    const int lane = tid & 63, wv = tid >> 6;
    const int l15 = lane & 15, g = lane >> 4;
    const int bh = b * HH + h;
    const int q0 = c2 * 128;

    // LDS layout: K dbuf [0,16384), V dbuf [16384,32768), P [32768,49152),
    // mask [49152,51712), sA [51712,52224), sB [52224,52736)
    char* PB = smem + 32768 + wv * 4096;
    float* maskAll = (float*)(smem + 49152);
    float* sA = (float*)(smem + 51712);
    float* sB = (float*)(smem + 52224);

    const char* pk_bytes = (const char*)packed;
    const char* vt_bytes = (const char*)vt;

    bf16x8 qf[2][2];
#pragma unroll
    for (int j = 0; j < 2; j++)
#pragma unroll
        for (int kk = 0; kk < 2; kk++)
            qf[j][kk] = *(const bf16x8*)(packed +
                (size_t)(b * SS + q0 + wv * 32 + j * 16 + l15) * 3840 + h * 64 + kk * 32 + g * 8);
    bf16x8 gkf[2];
#pragma unroll
    for (int kk = 0; kk < 2; kk++)
        gkf[kk] = *(const bf16x8*)(packed + (size_t)(b * SS) * 3840 + DD + h * 64 + kk * 32 + g * 8);
    float v0r[4];
#pragma unroll
    for (int jd = 0; jd < 4; jd++)
        v0r[jd] = bf2f(vt[(size_t)(bh * 64 + jd * 16 + l15) * SS]);

    f32x4 o_[2][4];
#pragma unroll
    for (int i = 0; i < 2; i++)
#pragma unroll
        for (int j = 0; j < 4; j++) o_[i][j] = (f32x4){0.f, 0.f, 0.f, 0.f};
    float m_[2] = { -1e20f, -1e20f };
    float l_[2] = { 0.f, 0.f };

    const int rswz = (l15 & 7) << 4;
    const int kt_s = max(0, 4 - 2 * c2);
    const int kt_e = min(10, 68 - 2 * c2);
    const int lo = wv >> 1;                       // wave tile window [lo, lo+8]

    auto stage = [&](int ib, int kt) {
        const int kpos0 = q0 - 256 + kt * 64;
        char* KTd = smem + ib * 8192;
        char* VTd = smem + 16384 + ib * 8192;
        int off = tid * 16;
#pragma unroll
        for (int ch = 0; ch < 2; ch++) {
            int o2 = off + ch * 4096;
            int row = o2 >> 7, bc = o2 & 127;
            int srcc = bc ^ ((row & 7) << 4);
            gload16(pk_bytes + (size_t)(b * SS + kpos0 + row) * 7680 + 1536 + h * 128 + srcc,
                    KTd + o2);
            gload16(vt_bytes + (size_t)(bh * 64 + row) * 8192 + (size_t)(kpos0 * 2 + srcc),
                    VTd + o2);
        }
    };

    // prologue: stage first tile + hoist mask
    stage(0, kt_s);
    {
        int span = (kt_e - kt_s) * 64;
        int base_k = q0 - 256 + kt_s * 64;
        for (int idx = tid; idx < span; idx += 256) {
            int kp = base_k + idx;
            maskAll[kt_s * 64 + idx] = (mask[b * SS + kp] > 0) ? 0.f : -1e30f;
        }
    }
    __syncthreads();

    int cur = 0;
    for (int kt = kt_s; kt < kt_e; kt++) {
        if (kt + 1 < kt_e) stage(cur ^ 1, kt + 1);

        const int dl = kt - lo;
        if (dl >= 0 && dl <= 8) {
            const char* KT = smem + cur * 8192;
            const char* VT = smem + 16384 + cur * 8192;
            const bool edge = (dl == 0) || (dl == 8);

            f32x4 mrd[4];
#pragma unroll
            for (int i = 0; i < 4; i++)
                mrd[i] = *(const f32x4*)&maskAll[kt * 64 + i * 16 + g * 4];

            // ---- S^T = K . Q^T ----
            f32x4 s_[4][2];
#pragma unroll
            for (int i = 0; i < 4; i++)
#pragma unroll
                for (int j = 0; j < 2; j++) s_[i][j] = (f32x4){0.f, 0.f, 0.f, 0.f};
#pragma unroll
            for (int kk = 0; kk < 2; kk++) {
                bf16x8 af[4];
#pragma unroll
                for (int i = 0; i < 4; i++)
                    af[i] = *(const bf16x8*)(KT + (i * 16 + l15) * 128 + ((kk * 64 + g * 16) ^ rswz));
#pragma unroll
                for (int i = 0; i < 4; i++)
#pragma unroll
                    for (int j = 0; j < 2; j++)
                        s_[i][j] = __builtin_amdgcn_mfma_f32_16x16x32_bf16(af[i], qf[j][kk], s_[i][j], 0, 0, 0);
            }

            // ---- online softmax per q (q32 = j*16 + l15) ----
#pragma unroll
            for (int j = 0; j < 2; j++) {
                float tm = -1e30f;
                if (edge) {
#pragma unroll
                    for (int i = 0; i < 4; i++) {
#pragma unroll
                        for (int r = 0; r < 4; r++) {
                            float v = fmaf(s_[i][j][r], 0.125f, mrd[i][r]);
                            int rel = kt * 64 - 256 + i * 16 + g * 4 + r - wv * 32 - j * 16 - l15;
                            v = (rel > 256 || rel < -256) ? -1e30f : v;
                            s_[i][j][r] = v;
                            tm = fmaxf(tm, v);
                        }
                    }
                } else {
#pragma unroll
                    for (int i = 0; i < 4; i++) {
#pragma unroll
                        for (int r = 0; r < 4; r++) {
                            float v = fmaf(s_[i][j][r], 0.125f, mrd[i][r]);
                            s_[i][j][r] = v;
                            tm = fmaxf(tm, v);
                        }
                    }
                }
                tm = fmaxf(tm, __shfl_xor(tm, 16));
                tm = fmaxf(tm, __shfl_xor(tm, 32));
                float mn = fmaxf(m_[j], tm);
                float fac = __expf(m_[j] - mn);
                m_[j] = mn;
                float ls = 0.f;
                int q32 = j * 16 + l15;
#pragma unroll
                for (int i = 0; i < 4; i++) {
                    float p0 = __expf(s_[i][j][0] - mn);
                    float p1 = __expf(s_[i][j][1] - mn);
                    float p2 = __expf(s_[i][j][2] - mn);
                    float p3 = __expf(s_[i][j][3] - mn);
                    ls += (p0 + p1) + (p2 + p3);
                    uint2 pw;
                    pw.x = (unsigned int)bfb(p0) | ((unsigned int)bfb(p1) << 16);
                    pw.y = (unsigned int)bfb(p2) | ((unsigned int)bfb(p3) << 16);
                    *(uint2*)(PB + q32 * 128 + ((i * 32 + g * 8) ^ rswz)) = pw;
                }
                ls += __shfl_xor(ls, 16);
                ls += __shfl_xor(ls, 32);
                l_[j] = l_[j] * fac + ls;
                if (g == 0) sA[wv * 32 + q32] = fac;
            }

            // ---- PV: rescale O, then O += P . V ----
#pragma unroll
            for (int iq = 0; iq < 2; iq++) {
                f32x4 fc = *(const f32x4*)&sA[wv * 32 + iq * 16 + g * 4];
#pragma unroll
                for (int jd = 0; jd < 4; jd++)
#pragma unroll
                    for (int r = 0; r < 4; r++) o_[iq][jd][r] *= fc[r];
            }
#pragma unroll
            for (int kk = 0; kk < 2; kk++) {
                bf16x8 pa[2], vb[4];
#pragma unroll
                for (int iq = 0; iq < 2; iq++)
                    pa[iq] = *(const bf16x8*)(PB + (iq * 16 + l15) * 128 + ((kk * 64 + g * 16) ^ rswz));
#pragma unroll
                for (int jd = 0; jd < 4; jd++)
                    vb[jd] = *(const bf16x8*)(VT + (jd * 16 + l15) * 128 + ((kk * 64 + g * 16) ^ rswz));
#pragma unroll
                for (int iq = 0; iq < 2; iq++)
#pragma unroll
                    for (int jd = 0; jd < 4; jd++)
                        o_[iq][jd] = __builtin_amdgcn_mfma_f32_16x16x32_bf16(pa[iq], vb[jd], o_[iq][jd], 0, 0, 0);
            }
        }

        asm volatile("s_waitcnt vmcnt(0)" ::: "memory");
        __builtin_amdgcn_sched_barrier(0);
        __builtin_amdgcn_s_barrier();
        __builtin_amdgcn_sched_barrier(0);
        cur ^= 1;
    }

    // ---- global key column (unmasked) + finalize ----
#pragma unroll
    for (int j = 0; j < 2; j++) {
        float pd = 0.f;
#pragma unroll
        for (int kk = 0; kk < 2; kk++)
#pragma unroll
            for (int e = 0; e < 8; e++)
                pd += bf2f((unsigned short)qf[j][kk][e]) * bf2f((unsigned short)gkf[kk][e]);
        pd += __shfl_xor(pd, 16);
        pd += __shfl_xor(pd, 32);
        float sg = pd * 0.125f;
        float mf = fmaxf(m_[j], sg);
        float fac = __expf(m_[j] - mf);
        float pg = __expf(sg - mf);
        float lf = l_[j] * fac + pg;
        float inv = 1.f / lf;
        if (g == 0) {
            sA[wv * 32 + j * 16 + l15] = fac * inv;
            sB[wv * 32 + j * 16 + l15] = pg * inv;
        }
    }
#pragma unroll
    for (int iq = 0; iq < 2; iq++) {
        f32x4 fA = *(const f32x4*)&sA[wv * 32 + iq * 16 + g * 4];
        f32x4 fB = *(const f32x4*)&sB[wv * 32 + iq * 16 + g * 4];
#pragma unroll
        for (int jd = 0; jd < 4; jd++) {
#pragma unroll
            for (int r = 0; r < 4; r++) {
                float val = o_[iq][jd][r] * fA[r] + fB[r] * v0r[jd];
                int row = b * SS + q0 + wv * 32 + iq * 16 + g * 4 + r;
                O[(size_t)row * DD + h * 64 + jd * 16 + l15] = bfb(val);
            }
        }
    }
}

// ---------------- global-token attention, phase 1 ----------------
__global__ __launch_bounds__(256) void gattn1_k(const float* __restrict__ qg,
        const unsigned short* __restrict__ packed, const int* __restrict__ mask,
        float* __restrict__ pm, float* __restrict__ pl, float* __restrict__ po)
{
    int cc = blockIdx.x, h = blockIdx.y, b = blockIdx.z;
    int tid = threadIdx.x;
    __shared__ float qs[64], red[256], ps[256], ored[4][64];
    if (tid < 64) qs[tid] = qg[b * DD + h * 64 + tid];
    __syncthreads();
    int s = cc * 256 + tid;
    const unsigned short* kr = packed + (size_t)(b * SS + s) * 3840 + 3 * DD + h * 64;
    float a = 0.f;
#pragma unroll
    for (int d8 = 0; d8 < 8; d8++) {
        bf16x8 kv = *(const bf16x8*)(kr + d8 * 8);
#pragma unroll
        for (int e = 0; e < 8; e++)
            a = fmaf(qs[d8 * 8 + e], bf2f((unsigned short)kv[e]), a);
    }
    a *= 0.125f;
    float sv = (mask[b * SS + s] > 0) ? a : -1e9f;
    red[tid] = sv; __syncthreads();
    for (int o = 128; o > 0; o >>= 1) {
        if (tid < o) red[tid] = fmaxf(red[tid], red[tid + o]);
        __syncthreads();
    }
    float mx = red[0]; __syncthreads();
    float p = __expf(sv - mx);
    ps[tid] = p;
    red[tid] = p; __syncthreads();
    for (int o = 128; o > 0; o >>= 1) {
        if (tid < o) red[tid] += red[tid + o];
        __syncthreads();
    }
    float ls = red[0];
    int d = tid & 63, grp = tid >> 6;
    const unsigned short* vgb = packed + 4 * DD + h * 64 + d;
    float oa = 0.f;
    for (int t = 0; t < 64; t++) {
        int srow = cc * 256 + grp * 64 + t;
        oa = fmaf(ps[grp * 64 + t], bf2f(vgb[(size_t)(b * SS + srow) * 3840]), oa);
    }
    ored[grp][d] = oa; __syncthreads();
    if (tid < 64) {
        int idx = (b * HH + h) * 16 + cc;
        po[(size_t)idx * 64 + tid] = ored[0][tid] + ored[1][tid] + ored[2][tid] + ored[3][tid];
        if (tid == 0) { pm[idx] = mx; pl[idx] = ls; }
    }
}

// ---------------- global-token attention, phase 2 ----------------
__global__ __launch_bounds__(64) void gattn2_k(const float* __restrict__ pm,
        const float* __restrict__ pl, const float* __restrict__ po,
        unsigned short* __restrict__ O)
{
    int h = blockIdx.x, b = blockIdx.y;
    int tid = threadIdx.x;
    int base = (b * HH + h) * 16;
    float mx = -1e30f;
    for (int c2 = 0; c2 < 16; c2++) mx = fmaxf(mx, pm[base + c2]);
    float den = 0.f, oa = 0.f;
    for (int c2 = 0; c2 < 16; c2++) {
        float w = __expf(pm[base + c2] - mx);
        den = fmaf(pl[base + c2], w, den);
        oa = fmaf(po[(size_t)(base + c2) * 64 + tid], w, oa);
    }
    O[(size_t)(b * SS) * DD + h * 64 + tid] = bfb(oa / den);
}

// ---------------- row-GEMV ----------------
template<int ACT_TANH>
__global__ __launch_bounds__(256) void rowgemv_k(const float* __restrict__ x,
        size_t xstride, const float* __restrict__ W, const float* __restrict__ bias,
        float* __restrict__ dst, int N)
{
    int b = blockIdx.y;
    int colL = threadIdx.x & 63, part = threadIdx.x >> 6;
    int col = blockIdx.x * 64 + colL;
    __shared__ float partial[4][64];
    const float* xr = x + (size_t)b * xstride;
    float a = 0.f;
    for (int k = part * (DD / 4); k < (part + 1) * (DD / 4); k++)
        a = fmaf(xr[k], W[(size_t)k * N + col], a);
    partial[part][colL] = a; __syncthreads();
    if (part == 0) {
        float s = partial[0][colL] + partial[1][colL] + partial[2][colL] + partial[3][colL]
                + bias[col];
        if (ACT_TANH) s = tanhf(s);
        dst[b * N + col] = s;
    }
}

// ---------------- classifier ----------------
__global__ __launch_bounds__(256) void cls_k(const float* __restrict__ pooled,
        const float* __restrict__ Wc, const float* __restrict__ bc,
        float* __restrict__ out)
{
    int lane = threadIdx.x & 63, pair = threadIdx.x >> 6;
    int b = pair >> 1, cls = pair & 1;
    float a = 0.f;
#pragma unroll
    for (int j = 0; j < 12; j++) {
        int k = lane + j * 64;
        a = fmaf(pooled[b * DD + k], Wc[k * 2 + cls], a);
    }
#pragma unroll
    for (int o = 1; o < 64; o <<= 1) a += __shfl_xor(a, o);
    if (lane == 0) out[b * 2 + cls] = a + bc[cls];
}

extern "C" void kernel_launch(void* const* d_in, const int* in_sizes, int n_in,
                              void* d_out, int out_size, void* d_ws, size_t ws_size,
                              hipStream_t stream) {
    const int*   input_ids = (const int*)d_in[0];
    const int*   amask     = (const int*)d_in[1];
    const float* word_emb  = (const float*)d_in[2];
    const float* pos_emb   = (const float*)d_in[3];
    const float* ln_e_g    = (const float*)d_in[4];
    const float* ln_e_b    = (const float*)d_in[5];
    const float* Wq  = (const float*)d_in[6];  const float* bq  = (const float*)d_in[7];
    const float* Wk  = (const float*)d_in[8];  const float* bk  = (const float*)d_in[9];
    const float* Wv  = (const float*)d_in[10]; const float* bv  = (const float*)d_in[11];
    const float* Wqg = (const float*)d_in[12]; const float* bqg = (const float*)d_in[13];
    const float* Wkg = (const float*)d_in[14]; const float* bkg = (const float*)d_in[15];
    const float* Wvg = (const float*)d_in[16]; const float* bvg = (const float*)d_in[17];
    const float* Wo  = (const float*)d_in[18]; const float* bo  = (const float*)d_in[19];
    const float* ln1_g = (const float*)d_in[20]; const float* ln1_b = (const float*)d_in[21];
    const float* W1  = (const float*)d_in[22]; const float* bf1 = (const float*)d_in[23];
    const float* W2  = (const float*)d_in[24]; const float* bf2 = (const float*)d_in[25];
    const float* ln2_g = (const float*)d_in[26]; const float* ln2_b = (const float*)d_in[27];
    const float* Wp  = (const float*)d_in[28]; const float* bp  = (const float*)d_in[29];
    const float* Wc  = (const float*)d_in[30]; const float* bc  = (const float*)d_in[31];
    float* out = (float*)d_out;

    char* wsb = (char*)d_ws;
    float*          x      = (float*)(wsb + 0);
    unsigned short* xbf    = (unsigned short*)(wsb + 25165824);
    unsigned short* packed = (unsigned short*)(wsb + 37748736);
    unsigned short* vtb    = (unsigned short*)(wsb + 100663296);
    unsigned short* aout   = (unsigned short*)(wsb + 113246208);
    float*          hf     = (float*)(wsb + 125829120);
    char*           wts    = wsb + 150994944;
    float*          b5     = (float*)(wsb + 184025088);
    float*          qg     = (float*)(wsb + 184055808);
    float*          pm     = (float*)(wsb + 184061952);
    float*          pl     = (float*)(wsb + 184063488);
    float*          po     = (float*)(wsb + 184065024);
    float*          pooled = (float*)(wsb + 184163328);
    unsigned short* mid    = packed;

    const size_t SQ = (size_t)DD * DD;
    const size_t PER_L = (6 * SQ + 2 * (size_t)DD * FF) * 2;
    unsigned short* Wt5[2], *Wo_t[2], *W1_t[2], *W2_t[2];
    for (int l = 0; l < 2; l++) {
        char* base = wts + (size_t)l * PER_L;
        Wt5[l]  = (unsigned short*)base;
        Wo_t[l] = (unsigned short*)(base + 5 * SQ * 2);
        W1_t[l] = (unsigned short*)(base + 6 * SQ * 2);
        W2_t[l] = (unsigned short*)(base + 6 * SQ * 2 + (size_t)DD * FF * 2);
    }

    const int M = BB * SS;

    TP12 t12;
    for (int l = 0; l < 2; l++) {
        t12.s[l * 6 + 0] = Wq  + (size_t)l * SQ;  t12.d[l * 6 + 0] = Wt5[l] + 0 * SQ;
        t12.s[l * 6 + 1] = Wk  + (size_t)l * SQ;  t12.d[l * 6 + 1] = Wt5[l] + 1 * SQ;
        t12.s[l * 6 + 2] = Wv  + (size_t)l * SQ;  t12.d[l * 6 + 2] = Wt5[l] + 2 * SQ;
        t12.s[l * 6 + 3] = Wkg + (size_t)l * SQ;  t12.d[l * 6 + 3] = Wt5[l] + 3 * SQ;
        t12.s[l * 6 + 4] = Wvg + (size_t)l * SQ;  t12.d[l * 6 + 4] = Wt5[l] + 4 * SQ;
        t12.s[l * 6 + 5] = Wo  + (size_t)l * SQ;  t12.d[l * 6 + 5] = Wo_t[l];
    }
    TP4 t4;
    t4.s[0] = W1;                      t4.d[0] = W1_t[0];
    t4.s[1] = W1 + (size_t)DD * FF;    t4.d[1] = W1_t[1];
    t4.s[2] = W2;                      t4.d[2] = W2_t[0];
    t4.s[3] = W2 + (size_t)FF * DD;    t4.d[3] = W2_t[1];

    transpose12_k<<<dim3(24, 24, 12), 256, 0, stream>>>(t12);
    transposeR4_k<<<dim3(96, 24, 4), 256, 0, stream>>>(t4);
    pack_bias5_k<<<(2 * 5 * DD + 255) / 256, 256, 0, stream>>>(bq, bk, bv, bkg, bvg, b5);

    embed_ln_k<<<M, 256, 0, stream>>>(input_ids, word_emb, pos_emb, ln_e_g, ln_e_b, x, xbf);

    dim3 gqkv(M / 128, 3840 / 128);
    dim3 g768(M / 128, DD / 128);
    dim3 g3072(M / 128, FF / 128);

    for (int l = 0; l < 2; l++) {
        const float* Wqg_l = Wqg + (size_t)l * SQ; const float* bqg_l = bqg + (size_t)l * DD;
        const float* bo_l  = bo  + (size_t)l * DD;
        const float* bf1_l = bf1 + (size_t)l * FF;
        const float* bf2_l = bf2 + (size_t)l * DD;
        const float* g1_l  = ln1_g + (size_t)l * DD; const float* b1_l = ln1_b + (size_t)l * DD;
        const float* g2_l  = ln2_g + (size_t)l * DD; const float* b2_l = ln2_b + (size_t)l * DD;

        mfma_gemm_k<1, 0><<<gqkv, 256, 0, stream>>>(xbf, Wt5[l], b5 + (size_t)l * 3840,
                                                    packed, M, 3840, DD);
        vtrans_k<<<dim3(SS / 64, HH, BB), 256, 0, stream>>>(packed, vtb);
        rowgemv_k<0><<<dim3(DD / 64, BB), 256, 0, stream>>>(x, (size_t)SS * DD, Wqg_l, bqg_l, qg, DD);

        swin_mfma_k<<<dim3(SS / 128, HH, BB), 256, 0, stream>>>(packed, vtb, amask, aout);
        gattn1_k<<<dim3(16, HH, BB), 256, 0, stream>>>(qg, packed, amask, pm, pl, po);
        gattn2_k<<<dim3(HH, BB), 64, 0, stream>>>(pm, pl, po, aout);

        mfma_gemm_k<0, 0><<<g768, 256, 0, stream>>>(aout, Wo_t[l], bo_l, hf, M, DD, DD);
        add_ln_k<<<M, 256, 0, stream>>>(x, hf, g1_l, b1_l, x, xbf);

        mfma_gemm_k<1, 1><<<g3072, 256, 0, stream>>>(xbf, W1_t[l], bf1_l, mid, M, FF, DD);
        mfma_gemm_k<0, 0><<<g768, 256, 0, stream>>>(mid, W2_t[l], bf2_l, hf, M, DD, FF);
        add_ln_k<<<M, 256, 0, stream>>>(x, hf, g2_l, b2_l, x, xbf);
    }

    rowgemv_k<1><<<dim3(DD / 64, BB), 256, 0, stream>>>(x, (size_t)SS * DD, Wp, bp, pooled, DD);
    cls_k<<<1, 256, 0, stream>>>(pooled, Wc, bc, out);
}

// Round 8
// 809.316 us; speedup vs baseline: 7.3122x; 1.0140x over previous
//
#include <hip/hip_runtime.h>
#include <hip/hip_bf16.h>
#include <math.h>

#define BB 2
#define SS 4096
#define DD 768
#define HH 12
#define DHH 64
#define WW 256
#define CC 16
#define FF 3072

typedef __attribute__((ext_vector_type(8))) short bf16x8;
typedef __attribute__((ext_vector_type(4))) float f32x4;

struct TP12 { const float* s[12]; unsigned short* d[12]; };
struct TP4  { const float* s[4];  unsigned short* d[4];  };

// gelu(x) = 0.5x(1+tanh(u)) = x * sigmoid(2u), u = 0.79788456(x + 0.044715 x^3)
__device__ __forceinline__ float gelu_f(float x) {
    float u = 0.7978845608028654f * fmaf(0.044715f * x * x, x, x);
    return x / (1.f + __expf(-2.f * u));
}

__device__ __forceinline__ unsigned short bfb(float f) {
    __hip_bfloat16 h = __float2bfloat16(f);
    return *(unsigned short*)&h;
}

__device__ __forceinline__ float bf2f(unsigned short u) {
    return __uint_as_float(((unsigned int)u) << 16);
}

__device__ __forceinline__ void gload16(const void* g, void* l) {
    __builtin_amdgcn_global_load_lds(
        (const __attribute__((address_space(1))) unsigned int*)g,
        (__attribute__((address_space(3))) unsigned int*)l, 16, 0, 0);
}

// ---------------- fused weight transposes: fp32 [K][N] -> bf16 [N][K] ----------------
__global__ __launch_bounds__(256) void transpose12_k(TP12 p)
{
    __shared__ float t[32][33];
    int z = blockIdx.z;
    const float* Wsrc = p.s[z];
    unsigned short* Wt = p.d[z];
    const int K = DD, N = DD;
    int n0 = blockIdx.x * 32, k0 = blockIdx.y * 32;
    int tx = threadIdx.x & 31, ty = threadIdx.x >> 5;
#pragma unroll
    for (int i = 0; i < 32; i += 8)
        t[ty + i][tx] = Wsrc[(size_t)(k0 + ty + i) * N + n0 + tx];
    __syncthreads();
#pragma unroll
    for (int i = 0; i < 32; i += 8)
        Wt[(size_t)(n0 + ty + i) * K + k0 + tx] = bfb(t[tx][ty + i]);
}

__global__ __launch_bounds__(256) void transposeR4_k(TP4 p)
{
    __shared__ float t[32][33];
    int z = blockIdx.z;
    const float* Wsrc = p.s[z];
    unsigned short* Wt = p.d[z];
    int K, N, n0, k0;
    if (z < 2) { K = DD; N = FF; n0 = blockIdx.x * 32; k0 = blockIdx.y * 32; }
    else { K = FF; N = DD; int cell = blockIdx.y * 96 + blockIdx.x;
           n0 = (cell % 24) * 32; k0 = (cell / 24) * 32; }
    int tx = threadIdx.x & 31, ty = threadIdx.x >> 5;
#pragma unroll
    for (int i = 0; i < 32; i += 8)
        t[ty + i][tx] = Wsrc[(size_t)(k0 + ty + i) * N + n0 + tx];
    __syncthreads();
#pragma unroll
    for (int i = 0; i < 32; i += 8)
        Wt[(size_t)(n0 + ty + i) * K + k0 + tx] = bfb(t[tx][ty + i]);
}

// ---------------- pack 5 bias vectors [2][768] each -> [2][3840] ----------------
__global__ __launch_bounds__(256) void pack_bias5_k(const float* __restrict__ b0,
        const float* __restrict__ b1, const float* __restrict__ b2,
        const float* __restrict__ b3, const float* __restrict__ b4,
        float* __restrict__ dst)
{
    int gid = blockIdx.x * 256 + threadIdx.x;
    if (gid >= 2 * 5 * DD) return;
    int l = gid / (5 * DD), r = gid % (5 * DD), seg = r / DD, i = r % DD;
    const float* srcs[5] = { b0, b1, b2, b3, b4 };
    dst[gid] = srcs[seg][l * DD + i];
}

// ---------------- embedding + LayerNorm (float4 + shfl reduce, 1 barrier) ----------------
__global__ __launch_bounds__(256) void embed_ln_k(const int* __restrict__ ids,
        const float* __restrict__ wemb, const float* __restrict__ pemb,
        const float* __restrict__ g, const float* __restrict__ bta,
        float* __restrict__ x, unsigned short* __restrict__ xbf)
{
    int row = blockIdx.x;
    int s = row & (SS - 1);
    int tid = threadIdx.x;
    int lane = tid & 63, wvi = tid >> 6;
    __shared__ float red[8];
    float4 v = { 0.f, 0.f, 0.f, 0.f };
    if (tid < 192) {
        const float4* we = (const float4*)(wemb + (size_t)ids[row] * DD);
        const float4* pe = (const float4*)(pemb + (size_t)s * DD);
        float4 a = we[tid], b = pe[tid];
        v.x = a.x + b.x; v.y = a.y + b.y; v.z = a.z + b.z; v.w = a.w + b.w;
    }
    float sum = (v.x + v.y) + (v.z + v.w);
    float sq = fmaf(v.x, v.x, fmaf(v.y, v.y, fmaf(v.z, v.z, v.w * v.w)));
#pragma unroll
    for (int o = 1; o < 64; o <<= 1) {
        sum += __shfl_xor(sum, o);
        sq  += __shfl_xor(sq, o);
    }
    if (lane == 0) { red[wvi] = sum; red[4 + wvi] = sq; }
    __syncthreads();
    float S = (red[0] + red[1]) + (red[2] + red[3]);
    float Q = (red[4] + red[5]) + (red[6] + red[7]);
    float mean = S * (1.f / DD);
    float var = Q * (1.f / DD) - mean * mean;
    float rstd = rsqrtf(var + 1e-5f);
    if (tid < 192) {
        float4 gg = ((const float4*)g)[tid];
        float4 bb = ((const float4*)bta)[tid];
        float4 o;
        o.x = (v.x - mean) * rstd * gg.x + bb.x;
        o.y = (v.y - mean) * rstd * gg.y + bb.y;
        o.z = (v.z - mean) * rstd * gg.z + bb.z;
        o.w = (v.w - mean) * rstd * gg.w + bb.w;
        ((float4*)(x + (size_t)row * DD))[tid] = o;
        ushort4 ob = { bfb(o.x), bfb(o.y), bfb(o.z), bfb(o.w) };
        ((ushort4*)(xbf + (size_t)row * DD))[tid] = ob;
    }
}

// ---------------- residual add + LayerNorm (float4 + shfl reduce) ----------------
__global__ __launch_bounds__(256) void add_ln_k(const float* __restrict__ xin,
        const float* __restrict__ hin, const float* __restrict__ g,
        const float* __restrict__ bta, float* __restrict__ xout,
        unsigned short* __restrict__ xbf)
{
    int row = blockIdx.x;
    int tid = threadIdx.x;
    int lane = tid & 63, wvi = tid >> 6;
    __shared__ float red[8];
    float4 v = { 0.f, 0.f, 0.f, 0.f };
    if (tid < 192) {
        float4 a = ((const float4*)(xin + (size_t)row * DD))[tid];
        float4 b = ((const float4*)(hin + (size_t)row * DD))[tid];
        v.x = a.x + b.x; v.y = a.y + b.y; v.z = a.z + b.z; v.w = a.w + b.w;
    }
    float sum = (v.x + v.y) + (v.z + v.w);
    float sq = fmaf(v.x, v.x, fmaf(v.y, v.y, fmaf(v.z, v.z, v.w * v.w)));
#pragma unroll
    for (int o = 1; o < 64; o <<= 1) {
        sum += __shfl_xor(sum, o);
        sq  += __shfl_xor(sq, o);
    }
    if (lane == 0) { red[wvi] = sum; red[4 + wvi] = sq; }
    __syncthreads();
    float S = (red[0] + red[1]) + (red[2] + red[3]);
    float Q = (red[4] + red[5]) + (red[6] + red[7]);
    float mean = S * (1.f / DD);
    float var = Q * (1.f / DD) - mean * mean;
    float rstd = rsqrtf(var + 1e-5f);
    if (tid < 192) {
        float4 gg = ((const float4*)g)[tid];
        float4 bb = ((const float4*)bta)[tid];
        float4 o;
        o.x = (v.x - mean) * rstd * gg.x + bb.x;
        o.y = (v.y - mean) * rstd * gg.y + bb.y;
        o.z = (v.z - mean) * rstd * gg.z + bb.z;
        o.w = (v.w - mean) * rstd * gg.w + bb.w;
        ((float4*)(xout + (size_t)row * DD))[tid] = o;
        ushort4 ob = { bfb(o.x), bfb(o.y), bfb(o.z), bfb(o.w) };
        ((ushort4*)(xbf + (size_t)row * DD))[tid] = ob;
    }
}

// ---------------- bf16 MFMA GEMM, BK=64: C = A[M,K] @ Bt[N,K]^T + bias ----------------
template<int OUT_BF16, int ACT_GELU>
__global__ __launch_bounds__(256) void mfma_gemm_k(
        const unsigned short* __restrict__ A,
        const unsigned short* __restrict__ Bt,
        const float* __restrict__ bias,
        void* __restrict__ Cv, int M, int N, int K)
{
    __shared__ short As[128 * 64];   // 16 KB
    __shared__ short Bs[128 * 64];   // 16 KB
    const int tid = threadIdx.x;
    const int lane = tid & 63, wv = tid >> 6;
    // XCD-aware bijective swizzle (all grids have nwg % 8 == 0)
    int nbx = gridDim.x;
    int nwg = nbx * gridDim.y;
    int lid = blockIdx.y * nbx + blockIdx.x;
    int nid = ((nwg & 7) == 0) ? ((lid & 7) * (nwg >> 3) + (lid >> 3)) : lid;
    const int bm = (nid % nbx) * 128, bn = (nid / nbx) * 128;
    const int wm = wv >> 1, wn = wv & 1;

    // staging: tile image row-major [128 rows][64 elems] (128B rows), 4 passes x 16B/thread
    const int srow = tid >> 3;            // 0..31
    const int scol = (tid & 7) * 8;       // element col
    const int ldst = tid * 16;            // pass p dest: p*4096 + ldst
    const unsigned short* Abase = A + (size_t)bm * K;
    const unsigned short* Bbase = Bt + (size_t)bn * K;

    f32x4 acc[4][4];
#pragma unroll
    for (int i = 0; i < 4; i++)
#pragma unroll
        for (int j = 0; j < 4; j++) acc[i][j] = (f32x4){0.f, 0.f, 0.f, 0.f};

    const int lr = lane & 15;
    const int g = lane >> 4;

    for (int k0 = 0; k0 < K; k0 += 64) {
        __syncthreads();
#pragma unroll
        for (int p = 0; p < 4; p++) {
            int row = srow + p * 32;
            gload16(Abase + (size_t)row * K + k0 + scol, (char*)As + p * 4096 + ldst);
            gload16(Bbase + (size_t)row * K + k0 + scol, (char*)Bs + p * 4096 + ldst);
        }
        __syncthreads();
#pragma unroll
        for (int kk = 0; kk < 2; kk++) {
            int ko = kk * 32 + g * 8;
            bf16x8 af[4], bfr[4];
#pragma unroll
            for (int i = 0; i < 4; i++)
                af[i] = *(const bf16x8*)&As[(wm * 64 + i * 16 + lr) * 64 + ko];
#pragma unroll
            for (int j = 0; j < 4; j++)
                bfr[j] = *(const bf16x8*)&Bs[(wn * 64 + j * 16 + lr) * 64 + ko];
#pragma unroll
            for (int i = 0; i < 4; i++)
#pragma unroll
                for (int j = 0; j < 4; j++)
                    acc[i][j] = __builtin_amdgcn_mfma_f32_16x16x32_bf16(af[i], bfr[j], acc[i][j], 0, 0, 0);
        }
    }

    const int rq = lane >> 4;
#pragma unroll
    for (int j = 0; j < 4; j++) {
        int col = bn + wn * 64 + j * 16 + lr;
        float bv = bias[col];
#pragma unroll
        for (int i = 0; i < 4; i++) {
            int rowb = bm + wm * 64 + i * 16 + rq * 4;
#pragma unroll
            for (int r = 0; r < 4; r++) {
                float o = acc[i][j][r] + bv;
                if (ACT_GELU) o = gelu_f(o);
                if (OUT_BF16)
                    ((unsigned short*)Cv)[(size_t)(rowb + r) * N + col] = bfb(o);
                else
                    ((float*)Cv)[(size_t)(rowb + r) * N + col] = o;
            }
        }
    }
}

// ---------------- V head-transpose ----------------
__global__ __launch_bounds__(256) void vtrans_k(const unsigned short* __restrict__ packed,
        unsigned short* __restrict__ vt)
{
    int s0 = blockIdx.x * 64, h = blockIdx.y, b = blockIdx.z;
    int tid = threadIdx.x;
    __shared__ unsigned short t[64][72];
    int r = tid >> 3, dc = (tid & 7) * 8;
#pragma unroll
    for (int half = 0; half < 2; half++) {
        int rr = r + half * 32;
        const unsigned short* src = packed + (size_t)(b * SS + s0 + rr) * 3840 + 2 * DD + h * 64 + dc;
        *(uint4*)&t[rr][dc] = *(const uint4*)src;
    }
    __syncthreads();
    int d = tid >> 3, sc = (tid & 7) * 8;
#pragma unroll
    for (int half = 0; half < 2; half++) {
        int dd2 = d + half * 32;
        unsigned short v[8];
#pragma unroll
        for (int e = 0; e < 8; e++) v[e] = t[sc + e][dd2];
        unsigned short* dst = vt + (size_t)((b * HH + h) * 64 + dd2) * SS + s0 + sc;
        *(uint4*)dst = *(uint4*)v;
    }
}

// ---------------- MFMA sliding-window flash attention (128-q blocks, dbuf pipeline) ----------------
__global__ __launch_bounds__(256) void swin_mfma_k(
        const unsigned short* __restrict__ packed,
        const unsigned short* __restrict__ vt,
        const int* __restrict__ mask,
        unsigned short* __restrict__ O)
{
    __shared__ __align__(16) char smem[52736];
    const int c2 = blockIdx.x, h = blockIdx.y, b = blockIdx.z;
    const int tid = threadIdx.x;
    const int lane = tid & 63, wv = tid >> 6;
    const int l15 = lane & 15, g = lane >> 4;
    const int bh = b * HH + h;
    const int q0 = c2 * 128;

    char* PB = smem + 32768 + wv * 4096;
    float* maskAll = (float*)(smem + 49152);
    float* sA = (float*)(smem + 51712);
    float* sB = (float*)(smem + 52224);

    const char* pk_bytes = (const char*)packed;
    const char* vt_bytes = (const char*)vt;

    bf16x8 qf[2][2];
#pragma unroll
    for (int j = 0; j < 2; j++)
#pragma unroll
        for (int kk = 0; kk < 2; kk++)
            qf[j][kk] = *(const bf16x8*)(packed +
                (size_t)(b * SS + q0 + wv * 32 + j * 16 + l15) * 3840 + h * 64 + kk * 32 + g * 8);
    bf16x8 gkf[2];
#pragma unroll
    for (int kk = 0; kk < 2; kk++)
        gkf[kk] = *(const bf16x8*)(packed + (size_t)(b * SS) * 3840 + DD + h * 64 + kk * 32 + g * 8);
    float v0r[4];
#pragma unroll
    for (int jd = 0; jd < 4; jd++)
        v0r[jd] = bf2f(vt[(size_t)(bh * 64 + jd * 16 + l15) * SS]);

    f32x4 o_[2][4];
#pragma unroll
    for (int i = 0; i < 2; i++)
#pragma unroll
        for (int j = 0; j < 4; j++) o_[i][j] = (f32x4){0.f, 0.f, 0.f, 0.f};
    float m_[2] = { -1e20f, -1e20f };
    float l_[2] = { 0.f, 0.f };

    const int rswz = (l15 & 7) << 4;
    const int kt_s = max(0, 4 - 2 * c2);
    const int kt_e = min(10, 68 - 2 * c2);
    const int lo = wv >> 1;

    auto stage = [&](int ib, int kt) {
        const int kpos0 = q0 - 256 + kt * 64;
        char* KTd = smem + ib * 8192;
        char* VTd = smem + 16384 + ib * 8192;
        int off = tid * 16;
#pragma unroll
        for (int ch = 0; ch < 2; ch++) {
            int o2 = off + ch * 4096;
            int row = o2 >> 7, bc = o2 & 127;
            int srcc = bc ^ ((row & 7) << 4);
            gload16(pk_bytes + (size_t)(b * SS + kpos0 + row) * 7680 + 1536 + h * 128 + srcc,
                    KTd + o2);
            gload16(vt_bytes + (size_t)(bh * 64 + row) * 8192 + (size_t)(kpos0 * 2 + srcc),
                    VTd + o2);
        }
    };

    stage(0, kt_s);
    {
        int span = (kt_e - kt_s) * 64;
        int base_k = q0 - 256 + kt_s * 64;
        for (int idx = tid; idx < span; idx += 256) {
            int kp = base_k + idx;
            maskAll[kt_s * 64 + idx] = (mask[b * SS + kp] > 0) ? 0.f : -1e30f;
        }
    }
    __syncthreads();

    int cur = 0;
    for (int kt = kt_s; kt < kt_e; kt++) {
        if (kt + 1 < kt_e) stage(cur ^ 1, kt + 1);

        const int dl = kt - lo;
        if (dl >= 0 && dl <= 8) {
            const char* KT = smem + cur * 8192;
            const char* VT = smem + 16384 + cur * 8192;
            const bool edge = (dl == 0) || (dl == 8);

            f32x4 mrd[4];
#pragma unroll
            for (int i = 0; i < 4; i++)
                mrd[i] = *(const f32x4*)&maskAll[kt * 64 + i * 16 + g * 4];

            f32x4 s_[4][2];
#pragma unroll
            for (int i = 0; i < 4; i++)
#pragma unroll
                for (int j = 0; j < 2; j++) s_[i][j] = (f32x4){0.f, 0.f, 0.f, 0.f};
            __builtin_amdgcn_s_setprio(1);
#pragma unroll
            for (int kk = 0; kk < 2; kk++) {
                bf16x8 af[4];
#pragma unroll
                for (int i = 0; i < 4; i++)
                    af[i] = *(const bf16x8*)(KT + (i * 16 + l15) * 128 + ((kk * 64 + g * 16) ^ rswz));
#pragma unroll
                for (int i = 0; i < 4; i++)
#pragma unroll
                    for (int j = 0; j < 2; j++)
                        s_[i][j] = __builtin_amdgcn_mfma_f32_16x16x32_bf16(af[i], qf[j][kk], s_[i][j], 0, 0, 0);
            }
            __builtin_amdgcn_s_setprio(0);

#pragma unroll
            for (int j = 0; j < 2; j++) {
                float tm = -1e30f;
                if (edge) {
#pragma unroll
                    for (int i = 0; i < 4; i++) {
#pragma unroll
                        for (int r = 0; r < 4; r++) {
                            float v = fmaf(s_[i][j][r], 0.125f, mrd[i][r]);
                            int rel = kt * 64 - 256 + i * 16 + g * 4 + r - wv * 32 - j * 16 - l15;
                            v = (rel > 256 || rel < -256) ? -1e30f : v;
                            s_[i][j][r] = v;
                            tm = fmaxf(tm, v);
                        }
                    }
                } else {
#pragma unroll
                    for (int i = 0; i < 4; i++) {
#pragma unroll
                        for (int r = 0; r < 4; r++) {
                            float v = fmaf(s_[i][j][r], 0.125f, mrd[i][r]);
                            s_[i][j][r] = v;
                            tm = fmaxf(tm, v);
                        }
                    }
                }
                tm = fmaxf(tm, __shfl_xor(tm, 16));
                tm = fmaxf(tm, __shfl_xor(tm, 32));
                float mn = fmaxf(m_[j], tm);
                float fac = __expf(m_[j] - mn);
                m_[j] = mn;
                float ls = 0.f;
                int q32 = j * 16 + l15;
#pragma unroll
                for (int i = 0; i < 4; i++) {
                    float p0 = __expf(s_[i][j][0] - mn);
                    float p1 = __expf(s_[i][j][1] - mn);
                    float p2 = __expf(s_[i][j][2] - mn);
                    float p3 = __expf(s_[i][j][3] - mn);
                    ls += (p0 + p1) + (p2 + p3);
                    uint2 pw;
                    pw.x = (unsigned int)bfb(p0) | ((unsigned int)bfb(p1) << 16);
                    pw.y = (unsigned int)bfb(p2) | ((unsigned int)bfb(p3) << 16);
                    *(uint2*)(PB + q32 * 128 + ((i * 32 + g * 8) ^ rswz)) = pw;
                }
                ls += __shfl_xor(ls, 16);
                ls += __shfl_xor(ls, 32);
                l_[j] = l_[j] * fac + ls;
                if (g == 0) sA[wv * 32 + q32] = fac;
            }

#pragma unroll
            for (int iq = 0; iq < 2; iq++) {
                f32x4 fc = *(const f32x4*)&sA[wv * 32 + iq * 16 + g * 4];
#pragma unroll
                for (int jd = 0; jd < 4; jd++)
#pragma unroll
                    for (int r = 0; r < 4; r++) o_[iq][jd][r] *= fc[r];
            }
            __builtin_amdgcn_s_setprio(1);
#pragma unroll
            for (int kk = 0; kk < 2; kk++) {
                bf16x8 pa[2], vb[4];
#pragma unroll
                for (int iq = 0; iq < 2; iq++)
                    pa[iq] = *(const bf16x8*)(PB + (iq * 16 + l15) * 128 + ((kk * 64 + g * 16) ^ rswz));
#pragma unroll
                for (int jd = 0; jd < 4; jd++)
                    vb[jd] = *(const bf16x8*)(VT + (jd * 16 + l15) * 128 + ((kk * 64 + g * 16) ^ rswz));
#pragma unroll
                for (int iq = 0; iq < 2; iq++)
#pragma unroll
                    for (int jd = 0; jd < 4; jd++)
                        o_[iq][jd] = __builtin_amdgcn_mfma_f32_16x16x32_bf16(pa[iq], vb[jd], o_[iq][jd], 0, 0, 0);
            }
            __builtin_amdgcn_s_setprio(0);
        }

        asm volatile("s_waitcnt vmcnt(0)" ::: "memory");
        __builtin_amdgcn_sched_barrier(0);
        __builtin_amdgcn_s_barrier();
        __builtin_amdgcn_sched_barrier(0);
        cur ^= 1;
    }

#pragma unroll
    for (int j = 0; j < 2; j++) {
        float pd = 0.f;
#pragma unroll
        for (int kk = 0; kk < 2; kk++)
#pragma unroll
            for (int e = 0; e < 8; e++)
                pd += bf2f((unsigned short)qf[j][kk][e]) * bf2f((unsigned short)gkf[kk][e]);
        pd += __shfl_xor(pd, 16);
        pd += __shfl_xor(pd, 32);
        float sg = pd * 0.125f;
        float mf = fmaxf(m_[j], sg);
        float fac = __expf(m_[j] - mf);
        float pg = __expf(sg - mf);
        float lf = l_[j] * fac + pg;
        float inv = 1.f / lf;
        if (g == 0) {
            sA[wv * 32 + j * 16 + l15] = fac * inv;
            sB[wv * 32 + j * 16 + l15] = pg * inv;
        }
    }
#pragma unroll
    for (int iq = 0; iq < 2; iq++) {
        f32x4 fA = *(const f32x4*)&sA[wv * 32 + iq * 16 + g * 4];
        f32x4 fB = *(const f32x4*)&sB[wv * 32 + iq * 16 + g * 4];
#pragma unroll
        for (int jd = 0; jd < 4; jd++) {
#pragma unroll
            for (int r = 0; r < 4; r++) {
                float val = o_[iq][jd][r] * fA[r] + fB[r] * v0r[jd];
                int row = b * SS + q0 + wv * 32 + iq * 16 + g * 4 + r;
                O[(size_t)row * DD + h * 64 + jd * 16 + l15] = bfb(val);
            }
        }
    }
}

// ---------------- global-token attention, phase 1 ----------------
__global__ __launch_bounds__(256) void gattn1_k(const float* __restrict__ qg,
        const unsigned short* __restrict__ packed, const int* __restrict__ mask,
        float* __restrict__ pm, float* __restrict__ pl, float* __restrict__ po)
{
    int cc = blockIdx.x, h = blockIdx.y, b = blockIdx.z;
    int tid = threadIdx.x;
    __shared__ float qs[64], red[256], ps[256], ored[4][64];
    if (tid < 64) qs[tid] = qg[b * DD + h * 64 + tid];
    __syncthreads();
    int s = cc * 256 + tid;
    const unsigned short* kr = packed + (size_t)(b * SS + s) * 3840 + 3 * DD + h * 64;
    float a = 0.f;
#pragma unroll
    for (int d8 = 0; d8 < 8; d8++) {
        bf16x8 kv = *(const bf16x8*)(kr + d8 * 8);
#pragma unroll
        for (int e = 0; e < 8; e++)
            a = fmaf(qs[d8 * 8 + e], bf2f((unsigned short)kv[e]), a);
    }
    a *= 0.125f;
    float sv = (mask[b * SS + s] > 0) ? a : -1e9f;
    red[tid] = sv; __syncthreads();
    for (int o = 128; o > 0; o >>= 1) {
        if (tid < o) red[tid] = fmaxf(red[tid], red[tid + o]);
        __syncthreads();
    }
    float mx = red[0]; __syncthreads();
    float p = __expf(sv - mx);
    ps[tid] = p;
    red[tid] = p; __syncthreads();
    for (int o = 128; o > 0; o >>= 1) {
        if (tid < o) red[tid] += red[tid + o];
        __syncthreads();
    }
    float ls = red[0];
    int d = tid & 63, grp = tid >> 6;
    const unsigned short* vgb = packed + 4 * DD + h * 64 + d;
    float oa = 0.f;
    for (int t = 0; t < 64; t++) {
        int srow = cc * 256 + grp * 64 + t;
        oa = fmaf(ps[grp * 64 + t], bf2f(vgb[(size_t)(b * SS + srow) * 3840]), oa);
    }
    ored[grp][d] = oa; __syncthreads();
    if (tid < 64) {
        int idx = (b * HH + h) * 16 + cc;
        po[(size_t)idx * 64 + tid] = ored[0][tid] + ored[1][tid] + ored[2][tid] + ored[3][tid];
        if (tid == 0) { pm[idx] = mx; pl[idx] = ls; }
    }
}

// ---------------- global-token attention, phase 2 ----------------
__global__ __launch_bounds__(64) void gattn2_k(const float* __restrict__ pm,
        const float* __restrict__ pl, const float* __restrict__ po,
        unsigned short* __restrict__ O)
{
    int h = blockIdx.x, b = blockIdx.y;
    int tid = threadIdx.x;
    int base = (b * HH + h) * 16;
    float mx = -1e30f;
    for (int c2 = 0; c2 < 16; c2++) mx = fmaxf(mx, pm[base + c2]);
    float den = 0.f, oa = 0.f;
    for (int c2 = 0; c2 < 16; c2++) {
        float w = __expf(pm[base + c2] - mx);
        den = fmaf(pl[base + c2], w, den);
        oa = fmaf(po[(size_t)(base + c2) * 64 + tid], w, oa);
    }
    O[(size_t)(b * SS) * DD + h * 64 + tid] = bfb(oa / den);
}

// ---------------- row-GEMV ----------------
template<int ACT_TANH>
__global__ __launch_bounds__(256) void rowgemv_k(const float* __restrict__ x,
        size_t xstride, const float* __restrict__ W, const float* __restrict__ bias,
        float* __restrict__ dst, int N)
{
    int b = blockIdx.y;
    int colL = threadIdx.x & 63, part = threadIdx.x >> 6;
    int col = blockIdx.x * 64 + colL;
    __shared__ float partial[4][64];
    const float* xr = x + (size_t)b * xstride;
    float a = 0.f;
    for (int k = part * (DD / 4); k < (part + 1) * (DD / 4); k++)
        a = fmaf(xr[k], W[(size_t)k * N + col], a);
    partial[part][colL] = a; __syncthreads();
    if (part == 0) {
        float s = partial[0][colL] + partial[1][colL] + partial[2][colL] + partial[3][colL]
                + bias[col];
        if (ACT_TANH) s = tanhf(s);
        dst[b * N + col] = s;
    }
}

// ---------------- classifier ----------------
__global__ __launch_bounds__(256) void cls_k(const float* __restrict__ pooled,
        const float* __restrict__ Wc, const float* __restrict__ bc,
        float* __restrict__ out)
{
    int lane = threadIdx.x & 63, pair = threadIdx.x >> 6;
    int b = pair >> 1, cls = pair & 1;
    float a = 0.f;
#pragma unroll
    for (int j = 0; j < 12; j++) {
        int k = lane + j * 64;
        a = fmaf(pooled[b * DD + k], Wc[k * 2 + cls], a);
    }
#pragma unroll
    for (int o = 1; o < 64; o <<= 1) a += __shfl_xor(a, o);
    if (lane == 0) out[b * 2 + cls] = a + bc[cls];
}

extern "C" void kernel_launch(void* const* d_in, const int* in_sizes, int n_in,
                              void* d_out, int out_size, void* d_ws, size_t ws_size,
                              hipStream_t stream) {
    const int*   input_ids = (const int*)d_in[0];
    const int*   amask     = (const int*)d_in[1];
    const float* word_emb  = (const float*)d_in[2];
    const float* pos_emb   = (const float*)d_in[3];
    const float* ln_e_g    = (const float*)d_in[4];
    const float* ln_e_b    = (const float*)d_in[5];
    const float* Wq  = (const float*)d_in[6];  const float* bq  = (const float*)d_in[7];
    const float* Wk  = (const float*)d_in[8];  const float* bk  = (const float*)d_in[9];
    const float* Wv  = (const float*)d_in[10]; const float* bv  = (const float*)d_in[11];
    const float* Wqg = (const float*)d_in[12]; const float* bqg = (const float*)d_in[13];
    const float* Wkg = (const float*)d_in[14]; const float* bkg = (const float*)d_in[15];
    const float* Wvg = (const float*)d_in[16]; const float* bvg = (const float*)d_in[17];
    const float* Wo  = (const float*)d_in[18]; const float* bo  = (const float*)d_in[19];
    const float* ln1_g = (const float*)d_in[20]; const float* ln1_b = (const float*)d_in[21];
    const float* W1  = (const float*)d_in[22]; const float* bf1 = (const float*)d_in[23];
    const float* W2  = (const float*)d_in[24]; const float* bf2 = (const float*)d_in[25];
    const float* ln2_g = (const float*)d_in[26]; const float* ln2_b = (const float*)d_in[27];
    const float* Wp  = (const float*)d_in[28]; const float* bp  = (const float*)d_in[29];
    const float* Wc  = (const float*)d_in[30]; const float* bc  = (const float*)d_in[31];
    float* out = (float*)d_out;

    char* wsb = (char*)d_ws;
    float*          x      = (float*)(wsb + 0);
    unsigned short* xbf    = (unsigned short*)(wsb + 25165824);
    unsigned short* packed = (unsigned short*)(wsb + 37748736);
    unsigned short* vtb    = (unsigned short*)(wsb + 100663296);
    unsigned short* aout   = (unsigned short*)(wsb + 113246208);
    float*          hf     = (float*)(wsb + 125829120);
    char*           wts    = wsb + 150994944;
    float*          b5     = (float*)(wsb + 184025088);
    float*          qg     = (float*)(wsb + 184055808);
    float*          pm     = (float*)(wsb + 184061952);
    float*          pl     = (float*)(wsb + 184063488);
    float*          po     = (float*)(wsb + 184065024);
    float*          pooled = (float*)(wsb + 184163328);
    unsigned short* mid    = packed;

    const size_t SQ = (size_t)DD * DD;
    const size_t PER_L = (6 * SQ + 2 * (size_t)DD * FF) * 2;
    unsigned short* Wt5[2], *Wo_t[2], *W1_t[2], *W2_t[2];
    for (int l = 0; l < 2; l++) {
        char* base = wts + (size_t)l * PER_L;
        Wt5[l]  = (unsigned short*)base;
        Wo_t[l] = (unsigned short*)(base + 5 * SQ * 2);
        W1_t[l] = (unsigned short*)(base + 6 * SQ * 2);
        W2_t[l] = (unsigned short*)(base + 6 * SQ * 2 + (size_t)DD * FF * 2);
    }

    const int M = BB * SS;

    TP12 t12;
    for (int l = 0; l < 2; l++) {
        t12.s[l * 6 + 0] = Wq  + (size_t)l * SQ;  t12.d[l * 6 + 0] = Wt5[l] + 0 * SQ;
        t12.s[l * 6 + 1] = Wk  + (size_t)l * SQ;  t12.d[l * 6 + 1] = Wt5[l] + 1 * SQ;
        t12.s[l * 6 + 2] = Wv  + (size_t)l * SQ;  t12.d[l * 6 + 2] = Wt5[l] + 2 * SQ;
        t12.s[l * 6 + 3] = Wkg + (size_t)l * SQ;  t12.d[l * 6 + 3] = Wt5[l] + 3 * SQ;
        t12.s[l * 6 + 4] = Wvg + (size_t)l * SQ;  t12.d[l * 6 + 4] = Wt5[l] + 4 * SQ;
        t12.s[l * 6 + 5] = Wo  + (size_t)l * SQ;  t12.d[l * 6 + 5] = Wo_t[l];
    }
    TP4 t4;
    t4.s[0] = W1;                      t4.d[0] = W1_t[0];
    t4.s[1] = W1 + (size_t)DD * FF;    t4.d[1] = W1_t[1];
    t4.s[2] = W2;                      t4.d[2] = W2_t[0];
    t4.s[3] = W2 + (size_t)FF * DD;    t4.d[3] = W2_t[1];

    transpose12_k<<<dim3(24, 24, 12), 256, 0, stream>>>(t12);
    transposeR4_k<<<dim3(96, 24, 4), 256, 0, stream>>>(t4);
    pack_bias5_k<<<(2 * 5 * DD + 255) / 256, 256, 0, stream>>>(bq, bk, bv, bkg, bvg, b5);

    embed_ln_k<<<M, 256, 0, stream>>>(input_ids, word_emb, pos_emb, ln_e_g, ln_e_b, x, xbf);

    dim3 gqkv(M / 128, 3840 / 128);
    dim3 g768(M / 128, DD / 128);
    dim3 g3072(M / 128, FF / 128);

    for (int l = 0; l < 2; l++) {
        const float* Wqg_l = Wqg + (size_t)l * SQ; const float* bqg_l = bqg + (size_t)l * DD;
        const float* bo_l  = bo  + (size_t)l * DD;
        const float* bf1_l = bf1 + (size_t)l * FF;
        const float* bf2_l = bf2 + (size_t)l * DD;
        const float* g1_l  = ln1_g + (size_t)l * DD; const float* b1_l = ln1_b + (size_t)l * DD;
        const float* g2_l  = ln2_g + (size_t)l * DD; const float* b2_l = ln2_b + (size_t)l * DD;

        mfma_gemm_k<1, 0><<<gqkv, 256, 0, stream>>>(xbf, Wt5[l], b5 + (size_t)l * 3840,
                                                    packed, M, 3840, DD);
        vtrans_k<<<dim3(SS / 64, HH, BB), 256, 0, stream>>>(packed, vtb);
        rowgemv_k<0><<<dim3(DD / 64, BB), 256, 0, stream>>>(x, (size_t)SS * DD, Wqg_l, bqg_l, qg, DD);

        swin_mfma_k<<<dim3(SS / 128, HH, BB), 256, 0, stream>>>(packed, vtb, amask, aout);
        gattn1_k<<<dim3(16, HH, BB), 256, 0, stream>>>(qg, packed, amask, pm, pl, po);
        gattn2_k<<<dim3(HH, BB), 64, 0, stream>>>(pm, pl, po, aout);

        mfma_gemm_k<0, 0><<<g768, 256, 0, stream>>>(aout, Wo_t[l], bo_l, hf, M, DD, DD);
        add_ln_k<<<M, 256, 0, stream>>>(x, hf, g1_l, b1_l, x, xbf);

        mfma_gemm_k<1, 1><<<g3072, 256, 0, stream>>>(xbf, W1_t[l], bf1_l, mid, M, FF, DD);
        mfma_gemm_k<0, 0><<<g768, 256, 0, stream>>>(mid, W2_t[l], bf2_l, hf, M, DD, FF);
        add_ln_k<<<M, 256, 0, stream>>>(x, hf, g2_l, b2_l, x, xbf);
    }

    rowgemv_k<1><<<dim3(DD / 64, BB), 256, 0, stream>>>(x, (size_t)SS * DD, Wp, bp, pooled, DD);
    cls_k<<<1, 256, 0, stream>>>(pooled, Wc, bc, out);
}

// Round 9
// 759.574 us; speedup vs baseline: 7.7910x; 1.0655x over previous
//
#include <hip/hip_runtime.h>
#include <hip/hip_bf16.h>
#include <math.h>

#define BB 2
#define SS 4096
#define DD 768
#define HH 12
#define DHH 64
#define WW 256
#define CC 16
#define FF 3072

typedef __attribute__((ext_vector_type(8))) short bf16x8;
typedef __attribute__((ext_vector_type(4))) float f32x4;

struct TP12 { const float* s[12]; unsigned short* d[12]; };
struct TP4  { const float* s[4];  unsigned short* d[4];  };

// gelu(x) = 0.5x(1+tanh(u)) = x * sigmoid(2u), u = 0.79788456(x + 0.044715 x^3)
__device__ __forceinline__ float gelu_f(float x) {
    float u = 0.7978845608028654f * fmaf(0.044715f * x * x, x, x);
    return x / (1.f + __expf(-2.f * u));
}

__device__ __forceinline__ unsigned short bfb(float f) {
    __hip_bfloat16 h = __float2bfloat16(f);
    return *(unsigned short*)&h;
}

__device__ __forceinline__ float bf2f(unsigned short u) {
    return __uint_as_float(((unsigned int)u) << 16);
}

__device__ __forceinline__ void gload16(const void* g, void* l) {
    __builtin_amdgcn_global_load_lds(
        (const __attribute__((address_space(1))) unsigned int*)g,
        (__attribute__((address_space(3))) unsigned int*)l, 16, 0, 0);
}

// ---------------- fused weight transposes: fp32 [K][N] -> bf16 [N][K] ----------------
__global__ __launch_bounds__(256) void transpose12_k(TP12 p)
{
    __shared__ float t[32][33];
    int z = blockIdx.z;
    const float* Wsrc = p.s[z];
    unsigned short* Wt = p.d[z];
    const int K = DD, N = DD;
    int n0 = blockIdx.x * 32, k0 = blockIdx.y * 32;
    int tx = threadIdx.x & 31, ty = threadIdx.x >> 5;
#pragma unroll
    for (int i = 0; i < 32; i += 8)
        t[ty + i][tx] = Wsrc[(size_t)(k0 + ty + i) * N + n0 + tx];
    __syncthreads();
#pragma unroll
    for (int i = 0; i < 32; i += 8)
        Wt[(size_t)(n0 + ty + i) * K + k0 + tx] = bfb(t[tx][ty + i]);
}

__global__ __launch_bounds__(256) void transposeR4_k(TP4 p)
{
    __shared__ float t[32][33];
    int z = blockIdx.z;
    const float* Wsrc = p.s[z];
    unsigned short* Wt = p.d[z];
    int K, N, n0, k0;
    if (z < 2) { K = DD; N = FF; n0 = blockIdx.x * 32; k0 = blockIdx.y * 32; }
    else { K = FF; N = DD; int cell = blockIdx.y * 96 + blockIdx.x;
           n0 = (cell % 24) * 32; k0 = (cell / 24) * 32; }
    int tx = threadIdx.x & 31, ty = threadIdx.x >> 5;
#pragma unroll
    for (int i = 0; i < 32; i += 8)
        t[ty + i][tx] = Wsrc[(size_t)(k0 + ty + i) * N + n0 + tx];
    __syncthreads();
#pragma unroll
    for (int i = 0; i < 32; i += 8)
        Wt[(size_t)(n0 + ty + i) * K + k0 + tx] = bfb(t[tx][ty + i]);
}

// ---------------- pack 5 bias vectors [2][768] each -> [2][3840] ----------------
__global__ __launch_bounds__(256) void pack_bias5_k(const float* __restrict__ b0,
        const float* __restrict__ b1, const float* __restrict__ b2,
        const float* __restrict__ b3, const float* __restrict__ b4,
        float* __restrict__ dst)
{
    int gid = blockIdx.x * 256 + threadIdx.x;
    if (gid >= 2 * 5 * DD) return;
    int l = gid / (5 * DD), r = gid % (5 * DD), seg = r / DD, i = r % DD;
    const float* srcs[5] = { b0, b1, b2, b3, b4 };
    dst[gid] = srcs[seg][l * DD + i];
}

// ---------------- embedding + LayerNorm (float4 + shfl reduce, 1 barrier) ----------------
__global__ __launch_bounds__(256) void embed_ln_k(const int* __restrict__ ids,
        const float* __restrict__ wemb, const float* __restrict__ pemb,
        const float* __restrict__ g, const float* __restrict__ bta,
        float* __restrict__ x, unsigned short* __restrict__ xbf)
{
    int row = blockIdx.x;
    int s = row & (SS - 1);
    int tid = threadIdx.x;
    int lane = tid & 63, wvi = tid >> 6;
    __shared__ float red[8];
    float4 v = { 0.f, 0.f, 0.f, 0.f };
    if (tid < 192) {
        const float4* we = (const float4*)(wemb + (size_t)ids[row] * DD);
        const float4* pe = (const float4*)(pemb + (size_t)s * DD);
        float4 a = we[tid], b = pe[tid];
        v.x = a.x + b.x; v.y = a.y + b.y; v.z = a.z + b.z; v.w = a.w + b.w;
    }
    float sum = (v.x + v.y) + (v.z + v.w);
    float sq = fmaf(v.x, v.x, fmaf(v.y, v.y, fmaf(v.z, v.z, v.w * v.w)));
#pragma unroll
    for (int o = 1; o < 64; o <<= 1) {
        sum += __shfl_xor(sum, o);
        sq  += __shfl_xor(sq, o);
    }
    if (lane == 0) { red[wvi] = sum; red[4 + wvi] = sq; }
    __syncthreads();
    float S = (red[0] + red[1]) + (red[2] + red[3]);
    float Q = (red[4] + red[5]) + (red[6] + red[7]);
    float mean = S * (1.f / DD);
    float var = Q * (1.f / DD) - mean * mean;
    float rstd = rsqrtf(var + 1e-5f);
    if (tid < 192) {
        float4 gg = ((const float4*)g)[tid];
        float4 bb = ((const float4*)bta)[tid];
        float4 o;
        o.x = (v.x - mean) * rstd * gg.x + bb.x;
        o.y = (v.y - mean) * rstd * gg.y + bb.y;
        o.z = (v.z - mean) * rstd * gg.z + bb.z;
        o.w = (v.w - mean) * rstd * gg.w + bb.w;
        ((float4*)(x + (size_t)row * DD))[tid] = o;
        ushort4 ob = { bfb(o.x), bfb(o.y), bfb(o.z), bfb(o.w) };
        ((ushort4*)(xbf + (size_t)row * DD))[tid] = ob;
    }
}

// ---------------- residual add + LayerNorm (float4 + shfl reduce) ----------------
__global__ __launch_bounds__(256) void add_ln_k(const float* __restrict__ xin,
        const float* __restrict__ hin, const float* __restrict__ g,
        const float* __restrict__ bta, float* __restrict__ xout,
        unsigned short* __restrict__ xbf)
{
    int row = blockIdx.x;
    int tid = threadIdx.x;
    int lane = tid & 63, wvi = tid >> 6;
    __shared__ float red[8];
    float4 v = { 0.f, 0.f, 0.f, 0.f };
    if (tid < 192) {
        float4 a = ((const float4*)(xin + (size_t)row * DD))[tid];
        float4 b = ((const float4*)(hin + (size_t)row * DD))[tid];
        v.x = a.x + b.x; v.y = a.y + b.y; v.z = a.z + b.z; v.w = a.w + b.w;
    }
    float sum = (v.x + v.y) + (v.z + v.w);
    float sq = fmaf(v.x, v.x, fmaf(v.y, v.y, fmaf(v.z, v.z, v.w * v.w)));
#pragma unroll
    for (int o = 1; o < 64; o <<= 1) {
        sum += __shfl_xor(sum, o);
        sq  += __shfl_xor(sq, o);
    }
    if (lane == 0) { red[wvi] = sum; red[4 + wvi] = sq; }
    __syncthreads();
    float S = (red[0] + red[1]) + (red[2] + red[3]);
    float Q = (red[4] + red[5]) + (red[6] + red[7]);
    float mean = S * (1.f / DD);
    float var = Q * (1.f / DD) - mean * mean;
    float rstd = rsqrtf(var + 1e-5f);
    if (tid < 192) {
        float4 gg = ((const float4*)g)[tid];
        float4 bb = ((const float4*)bta)[tid];
        float4 o;
        o.x = (v.x - mean) * rstd * gg.x + bb.x;
        o.y = (v.y - mean) * rstd * gg.y + bb.y;
        o.z = (v.z - mean) * rstd * gg.z + bb.z;
        o.w = (v.w - mean) * rstd * gg.w + bb.w;
        ((float4*)(xout + (size_t)row * DD))[tid] = o;
        ushort4 ob = { bfb(o.x), bfb(o.y), bfb(o.z), bfb(o.w) };
        ((ushort4*)(xbf + (size_t)row * DD))[tid] = ob;
    }
}

// ---------------- bf16 MFMA GEMM, BK=64, XOR-swizzled LDS ----------------
// Swizzle (G21 both-sides): linear LDS dest + pre-swizzled global SOURCE column,
// fragment reads apply the same involution byte^=((row&7)<<4).
template<int OUT_BF16, int ACT_GELU>
__global__ __launch_bounds__(256) void mfma_gemm_k(
        const unsigned short* __restrict__ A,
        const unsigned short* __restrict__ Bt,
        const float* __restrict__ bias,
        void* __restrict__ Cv, int M, int N, int K)
{
    __shared__ short As[128 * 64];   // 16 KB
    __shared__ short Bs[128 * 64];   // 16 KB
    const int tid = threadIdx.x;
    const int lane = tid & 63, wv = tid >> 6;
    // XCD-aware bijective swizzle (all grids have nwg % 8 == 0)
    int nbx = gridDim.x;
    int nwg = nbx * gridDim.y;
    int lid = blockIdx.y * nbx + blockIdx.x;
    int nid = ((nwg & 7) == 0) ? ((lid & 7) * (nwg >> 3) + (lid >> 3)) : lid;
    const int bm = (nid % nbx) * 128, bn = (nid / nbx) * 128;
    const int wm = wv >> 1, wn = wv & 1;

    // staging: dest linear d = p*4096 + tid*16; row = d>>7 (= srow0 + 32p), bc = d&127
    // source byte col = bc ^ ((row&7)<<4); row&7 invariant across p.
    const int srow0 = (tid * 16) >> 7;          // 0..31
    const int sbc   = (tid * 16) & 127;
    const int srcc  = sbc ^ ((srow0 & 7) << 4); // source byte col, 16B aligned
    const int ldst  = tid * 16;
    const char* Ab = (const char*)(A + (size_t)bm * K);
    const char* Bb = (const char*)(Bt + (size_t)bn * K);

    f32x4 acc[4][4];
#pragma unroll
    for (int i = 0; i < 4; i++)
#pragma unroll
        for (int j = 0; j < 4; j++) acc[i][j] = (f32x4){0.f, 0.f, 0.f, 0.f};

    const int lr = lane & 15;
    const int g = lane >> 4;
    const int rswz = (lr & 7) << 4;

    for (int k0 = 0; k0 < K; k0 += 64) {
        __syncthreads();
#pragma unroll
        for (int p = 0; p < 4; p++) {
            size_t roff = (size_t)(srow0 + p * 32) * (K * 2) + (size_t)k0 * 2 + srcc;
            gload16(Ab + roff, (char*)As + p * 4096 + ldst);
            gload16(Bb + roff, (char*)Bs + p * 4096 + ldst);
        }
        __syncthreads();
#pragma unroll
        for (int kk = 0; kk < 2; kk++) {
            int colb = (kk * 64 + g * 16) ^ rswz;
            bf16x8 af[4], bfr[4];
#pragma unroll
            for (int i = 0; i < 4; i++)
                af[i] = *(const bf16x8*)((const char*)As + (wm * 64 + i * 16 + lr) * 128 + colb);
#pragma unroll
            for (int j = 0; j < 4; j++)
                bfr[j] = *(const bf16x8*)((const char*)Bs + (wn * 64 + j * 16 + lr) * 128 + colb);
#pragma unroll
            for (int i = 0; i < 4; i++)
#pragma unroll
                for (int j = 0; j < 4; j++)
                    acc[i][j] = __builtin_amdgcn_mfma_f32_16x16x32_bf16(af[i], bfr[j], acc[i][j], 0, 0, 0);
        }
    }

    const int rq = lane >> 4;
#pragma unroll
    for (int j = 0; j < 4; j++) {
        int col = bn + wn * 64 + j * 16 + lr;
        float bv = bias[col];
#pragma unroll
        for (int i = 0; i < 4; i++) {
            int rowb = bm + wm * 64 + i * 16 + rq * 4;
#pragma unroll
            for (int r = 0; r < 4; r++) {
                float o = acc[i][j][r] + bv;
                if (ACT_GELU) o = gelu_f(o);
                if (OUT_BF16)
                    ((unsigned short*)Cv)[(size_t)(rowb + r) * N + col] = bfb(o);
                else
                    ((float*)Cv)[(size_t)(rowb + r) * N + col] = o;
            }
        }
    }
}

// ---------------- V head-transpose ----------------
__global__ __launch_bounds__(256) void vtrans_k(const unsigned short* __restrict__ packed,
        unsigned short* __restrict__ vt)
{
    int s0 = blockIdx.x * 64, h = blockIdx.y, b = blockIdx.z;
    int tid = threadIdx.x;
    __shared__ unsigned short t[64][72];
    int r = tid >> 3, dc = (tid & 7) * 8;
#pragma unroll
    for (int half = 0; half < 2; half++) {
        int rr = r + half * 32;
        const unsigned short* src = packed + (size_t)(b * SS + s0 + rr) * 3840 + 2 * DD + h * 64 + dc;
        *(uint4*)&t[rr][dc] = *(const uint4*)src;
    }
    __syncthreads();
    int d = tid >> 3, sc = (tid & 7) * 8;
#pragma unroll
    for (int half = 0; half < 2; half++) {
        int dd2 = d + half * 32;
        unsigned short v[8];
#pragma unroll
        for (int e = 0; e < 8; e++) v[e] = t[sc + e][dd2];
        unsigned short* dst = vt + (size_t)((b * HH + h) * 64 + dd2) * SS + s0 + sc;
        *(uint4*)dst = *(uint4*)v;
    }
}

// ---------------- MFMA sliding-window flash attention (128-q blocks, dbuf pipeline) ----------------
__global__ __launch_bounds__(256) void swin_mfma_k(
        const unsigned short* __restrict__ packed,
        const unsigned short* __restrict__ vt,
        const int* __restrict__ mask,
        unsigned short* __restrict__ O)
{
    __shared__ __align__(16) char smem[52736];
    const int c2 = blockIdx.x, h = blockIdx.y, b = blockIdx.z;
    const int tid = threadIdx.x;
    const int lane = tid & 63, wv = tid >> 6;
    const int l15 = lane & 15, g = lane >> 4;
    const int bh = b * HH + h;
    const int q0 = c2 * 128;

    char* PB = smem + 32768 + wv * 4096;
    float* maskAll = (float*)(smem + 49152);
    float* sA = (float*)(smem + 51712);
    float* sB = (float*)(smem + 52224);

    const char* pk_bytes = (const char*)packed;
    const char* vt_bytes = (const char*)vt;

    bf16x8 qf[2][2];
#pragma unroll
    for (int j = 0; j < 2; j++)
#pragma unroll
        for (int kk = 0; kk < 2; kk++)
            qf[j][kk] = *(const bf16x8*)(packed +
                (size_t)(b * SS + q0 + wv * 32 + j * 16 + l15) * 3840 + h * 64 + kk * 32 + g * 8);
    bf16x8 gkf[2];
#pragma unroll
    for (int kk = 0; kk < 2; kk++)
        gkf[kk] = *(const bf16x8*)(packed + (size_t)(b * SS) * 3840 + DD + h * 64 + kk * 32 + g * 8);
    float v0r[4];
#pragma unroll
    for (int jd = 0; jd < 4; jd++)
        v0r[jd] = bf2f(vt[(size_t)(bh * 64 + jd * 16 + l15) * SS]);

    f32x4 o_[2][4];
#pragma unroll
    for (int i = 0; i < 2; i++)
#pragma unroll
        for (int j = 0; j < 4; j++) o_[i][j] = (f32x4){0.f, 0.f, 0.f, 0.f};
    float m_[2] = { -1e20f, -1e20f };
    float l_[2] = { 0.f, 0.f };

    const int rswz = (l15 & 7) << 4;
    const int kt_s = max(0, 4 - 2 * c2);
    const int kt_e = min(10, 68 - 2 * c2);
    const int lo = wv >> 1;

    auto stage = [&](int ib, int kt) {
        const int kpos0 = q0 - 256 + kt * 64;
        char* KTd = smem + ib * 8192;
        char* VTd = smem + 16384 + ib * 8192;
        int off = tid * 16;
#pragma unroll
        for (int ch = 0; ch < 2; ch++) {
            int o2 = off + ch * 4096;
            int row = o2 >> 7, bc = o2 & 127;
            int srcc = bc ^ ((row & 7) << 4);
            gload16(pk_bytes + (size_t)(b * SS + kpos0 + row) * 7680 + 1536 + h * 128 + srcc,
                    KTd + o2);
            gload16(vt_bytes + (size_t)(bh * 64 + row) * 8192 + (size_t)(kpos0 * 2 + srcc),
                    VTd + o2);
        }
    };

    stage(0, kt_s);
    {
        int span = (kt_e - kt_s) * 64;
        int base_k = q0 - 256 + kt_s * 64;
        for (int idx = tid; idx < span; idx += 256) {
            int kp = base_k + idx;
            maskAll[kt_s * 64 + idx] = (mask[b * SS + kp] > 0) ? 0.f : -1e30f;
        }
    }
    __syncthreads();

    int cur = 0;
    for (int kt = kt_s; kt < kt_e; kt++) {
        if (kt + 1 < kt_e) stage(cur ^ 1, kt + 1);

        const int dl = kt - lo;
        if (dl >= 0 && dl <= 8) {
            const char* KT = smem + cur * 8192;
            const char* VT = smem + 16384 + cur * 8192;
            const bool edge = (dl == 0) || (dl == 8);

            f32x4 mrd[4];
#pragma unroll
            for (int i = 0; i < 4; i++)
                mrd[i] = *(const f32x4*)&maskAll[kt * 64 + i * 16 + g * 4];

            f32x4 s_[4][2];
#pragma unroll
            for (int i = 0; i < 4; i++)
#pragma unroll
                for (int j = 0; j < 2; j++) s_[i][j] = (f32x4){0.f, 0.f, 0.f, 0.f};
            __builtin_amdgcn_s_setprio(1);
#pragma unroll
            for (int kk = 0; kk < 2; kk++) {
                bf16x8 af[4];
#pragma unroll
                for (int i = 0; i < 4; i++)
                    af[i] = *(const bf16x8*)(KT + (i * 16 + l15) * 128 + ((kk * 64 + g * 16) ^ rswz));
#pragma unroll
                for (int i = 0; i < 4; i++)
#pragma unroll
                    for (int j = 0; j < 2; j++)
                        s_[i][j] = __builtin_amdgcn_mfma_f32_16x16x32_bf16(af[i], qf[j][kk], s_[i][j], 0, 0, 0);
            }
            __builtin_amdgcn_s_setprio(0);

#pragma unroll
            for (int j = 0; j < 2; j++) {
                float tm = -1e30f;
                if (edge) {
#pragma unroll
                    for (int i = 0; i < 4; i++) {
#pragma unroll
                        for (int r = 0; r < 4; r++) {
                            float v = fmaf(s_[i][j][r], 0.125f, mrd[i][r]);
                            int rel = kt * 64 - 256 + i * 16 + g * 4 + r - wv * 32 - j * 16 - l15;
                            v = (rel > 256 || rel < -256) ? -1e30f : v;
                            s_[i][j][r] = v;
                            tm = fmaxf(tm, v);
                        }
                    }
                } else {
#pragma unroll
                    for (int i = 0; i < 4; i++) {
#pragma unroll
                        for (int r = 0; r < 4; r++) {
                            float v = fmaf(s_[i][j][r], 0.125f, mrd[i][r]);
                            s_[i][j][r] = v;
                            tm = fmaxf(tm, v);
                        }
                    }
                }
                tm = fmaxf(tm, __shfl_xor(tm, 16));
                tm = fmaxf(tm, __shfl_xor(tm, 32));
                float mn = fmaxf(m_[j], tm);
                float fac = __expf(m_[j] - mn);
                m_[j] = mn;
                float ls = 0.f;
                int q32 = j * 16 + l15;
#pragma unroll
                for (int i = 0; i < 4; i++) {
                    float p0 = __expf(s_[i][j][0] - mn);
                    float p1 = __expf(s_[i][j][1] - mn);
                    float p2 = __expf(s_[i][j][2] - mn);
                    float p3 = __expf(s_[i][j][3] - mn);
                    ls += (p0 + p1) + (p2 + p3);
                    uint2 pw;
                    pw.x = (unsigned int)bfb(p0) | ((unsigned int)bfb(p1) << 16);
                    pw.y = (unsigned int)bfb(p2) | ((unsigned int)bfb(p3) << 16);
                    *(uint2*)(PB + q32 * 128 + ((i * 32 + g * 8) ^ rswz)) = pw;
                }
                ls += __shfl_xor(ls, 16);
                ls += __shfl_xor(ls, 32);
                l_[j] = l_[j] * fac + ls;
                if (g == 0) sA[wv * 32 + q32] = fac;
            }

#pragma unroll
            for (int iq = 0; iq < 2; iq++) {
                f32x4 fc = *(const f32x4*)&sA[wv * 32 + iq * 16 + g * 4];
#pragma unroll
                for (int jd = 0; jd < 4; jd++)
#pragma unroll
                    for (int r = 0; r < 4; r++) o_[iq][jd][r] *= fc[r];
            }
            __builtin_amdgcn_s_setprio(1);
#pragma unroll
            for (int kk = 0; kk < 2; kk++) {
                bf16x8 pa[2], vb[4];
#pragma unroll
                for (int iq = 0; iq < 2; iq++)
                    pa[iq] = *(const bf16x8*)(PB + (iq * 16 + l15) * 128 + ((kk * 64 + g * 16) ^ rswz));
#pragma unroll
                for (int jd = 0; jd < 4; jd++)
                    vb[jd] = *(const bf16x8*)(VT + (jd * 16 + l15) * 128 + ((kk * 64 + g * 16) ^ rswz));
#pragma unroll
                for (int iq = 0; iq < 2; iq++)
#pragma unroll
                    for (int jd = 0; jd < 4; jd++)
                        o_[iq][jd] = __builtin_amdgcn_mfma_f32_16x16x32_bf16(pa[iq], vb[jd], o_[iq][jd], 0, 0, 0);
            }
            __builtin_amdgcn_s_setprio(0);
        }

        asm volatile("s_waitcnt vmcnt(0)" ::: "memory");
        __builtin_amdgcn_sched_barrier(0);
        __builtin_amdgcn_s_barrier();
        __builtin_amdgcn_sched_barrier(0);
        cur ^= 1;
    }

#pragma unroll
    for (int j = 0; j < 2; j++) {
        float pd = 0.f;
#pragma unroll
        for (int kk = 0; kk < 2; kk++)
#pragma unroll
            for (int e = 0; e < 8; e++)
                pd += bf2f((unsigned short)qf[j][kk][e]) * bf2f((unsigned short)gkf[kk][e]);
        pd += __shfl_xor(pd, 16);
        pd += __shfl_xor(pd, 32);
        float sg = pd * 0.125f;
        float mf = fmaxf(m_[j], sg);
        float fac = __expf(m_[j] - mf);
        float pg = __expf(sg - mf);
        float lf = l_[j] * fac + pg;
        float inv = 1.f / lf;
        if (g == 0) {
            sA[wv * 32 + j * 16 + l15] = fac * inv;
            sB[wv * 32 + j * 16 + l15] = pg * inv;
        }
    }
#pragma unroll
    for (int iq = 0; iq < 2; iq++) {
        f32x4 fA = *(const f32x4*)&sA[wv * 32 + iq * 16 + g * 4];
        f32x4 fB = *(const f32x4*)&sB[wv * 32 + iq * 16 + g * 4];
#pragma unroll
        for (int jd = 0; jd < 4; jd++) {
#pragma unroll
            for (int r = 0; r < 4; r++) {
                float val = o_[iq][jd][r] * fA[r] + fB[r] * v0r[jd];
                int row = b * SS + q0 + wv * 32 + iq * 16 + g * 4 + r;
                O[(size_t)row * DD + h * 64 + jd * 16 + l15] = bfb(val);
            }
        }
    }
}

// ---------------- global-token attention, phase 1 ----------------
__global__ __launch_bounds__(256) void gattn1_k(const float* __restrict__ qg,
        const unsigned short* __restrict__ packed, const int* __restrict__ mask,
        float* __restrict__ pm, float* __restrict__ pl, float* __restrict__ po)
{
    int cc = blockIdx.x, h = blockIdx.y, b = blockIdx.z;
    int tid = threadIdx.x;
    __shared__ float qs[64], red[256], ps[256], ored[4][64];
    if (tid < 64) qs[tid] = qg[b * DD + h * 64 + tid];
    __syncthreads();
    int s = cc * 256 + tid;
    const unsigned short* kr = packed + (size_t)(b * SS + s) * 3840 + 3 * DD + h * 64;
    float a = 0.f;
#pragma unroll
    for (int d8 = 0; d8 < 8; d8++) {
        bf16x8 kv = *(const bf16x8*)(kr + d8 * 8);
#pragma unroll
        for (int e = 0; e < 8; e++)
            a = fmaf(qs[d8 * 8 + e], bf2f((unsigned short)kv[e]), a);
    }
    a *= 0.125f;
    float sv = (mask[b * SS + s] > 0) ? a : -1e9f;
    red[tid] = sv; __syncthreads();
    for (int o = 128; o > 0; o >>= 1) {
        if (tid < o) red[tid] = fmaxf(red[tid], red[tid + o]);
        __syncthreads();
    }
    float mx = red[0]; __syncthreads();
    float p = __expf(sv - mx);
    ps[tid] = p;
    red[tid] = p; __syncthreads();
    for (int o = 128; o > 0; o >>= 1) {
        if (tid < o) red[tid] += red[tid + o];
        __syncthreads();
    }
    float ls = red[0];
    int d = tid & 63, grp = tid >> 6;
    const unsigned short* vgb = packed + 4 * DD + h * 64 + d;
    float oa = 0.f;
    for (int t = 0; t < 64; t++) {
        int srow = cc * 256 + grp * 64 + t;
        oa = fmaf(ps[grp * 64 + t], bf2f(vgb[(size_t)(b * SS + srow) * 3840]), oa);
    }
    ored[grp][d] = oa; __syncthreads();
    if (tid < 64) {
        int idx = (b * HH + h) * 16 + cc;
        po[(size_t)idx * 64 + tid] = ored[0][tid] + ored[1][tid] + ored[2][tid] + ored[3][tid];
        if (tid == 0) { pm[idx] = mx; pl[idx] = ls; }
    }
}

// ---------------- global-token attention, phase 2 ----------------
__global__ __launch_bounds__(64) void gattn2_k(const float* __restrict__ pm,
        const float* __restrict__ pl, const float* __restrict__ po,
        unsigned short* __restrict__ O)
{
    int h = blockIdx.x, b = blockIdx.y;
    int tid = threadIdx.x;
    int base = (b * HH + h) * 16;
    float mx = -1e30f;
    for (int c2 = 0; c2 < 16; c2++) mx = fmaxf(mx, pm[base + c2]);
    float den = 0.f, oa = 0.f;
    for (int c2 = 0; c2 < 16; c2++) {
        float w = __expf(pm[base + c2] - mx);
        den = fmaf(pl[base + c2], w, den);
        oa = fmaf(po[(size_t)(base + c2) * 64 + tid], w, oa);
    }
    O[(size_t)(b * SS) * DD + h * 64 + tid] = bfb(oa / den);
}

// ---------------- row-GEMV ----------------
template<int ACT_TANH>
__global__ __launch_bounds__(256) void rowgemv_k(const float* __restrict__ x,
        size_t xstride, const float* __restrict__ W, const float* __restrict__ bias,
        float* __restrict__ dst, int N)
{
    int b = blockIdx.y;
    int colL = threadIdx.x & 63, part = threadIdx.x >> 6;
    int col = blockIdx.x * 64 + colL;
    __shared__ float partial[4][64];
    const float* xr = x + (size_t)b * xstride;
    float a = 0.f;
    for (int k = part * (DD / 4); k < (part + 1) * (DD / 4); k++)
        a = fmaf(xr[k], W[(size_t)k * N + col], a);
    partial[part][colL] = a; __syncthreads();
    if (part == 0) {
        float s = partial[0][colL] + partial[1][colL] + partial[2][colL] + partial[3][colL]
                + bias[col];
        if (ACT_TANH) s = tanhf(s);
        dst[b * N + col] = s;
    }
}

// ---------------- classifier ----------------
__global__ __launch_bounds__(256) void cls_k(const float* __restrict__ pooled,
        const float* __restrict__ Wc, const float* __restrict__ bc,
        float* __restrict__ out)
{
    int lane = threadIdx.x & 63, pair = threadIdx.x >> 6;
    int b = pair >> 1, cls = pair & 1;
    float a = 0.f;
#pragma unroll
    for (int j = 0; j < 12; j++) {
        int k = lane + j * 64;
        a = fmaf(pooled[b * DD + k], Wc[k * 2 + cls], a);
    }
#pragma unroll
    for (int o = 1; o < 64; o <<= 1) a += __shfl_xor(a, o);
    if (lane == 0) out[b * 2 + cls] = a + bc[cls];
}

extern "C" void kernel_launch(void* const* d_in, const int* in_sizes, int n_in,
                              void* d_out, int out_size, void* d_ws, size_t ws_size,
                              hipStream_t stream) {
    const int*   input_ids = (const int*)d_in[0];
    const int*   amask     = (const int*)d_in[1];
    const float* word_emb  = (const float*)d_in[2];
    const float* pos_emb   = (const float*)d_in[3];
    const float* ln_e_g    = (const float*)d_in[4];
    const float* ln_e_b    = (const float*)d_in[5];
    const float* Wq  = (const float*)d_in[6];  const float* bq  = (const float*)d_in[7];
    const float* Wk  = (const float*)d_in[8];  const float* bk  = (const float*)d_in[9];
    const float* Wv  = (const float*)d_in[10]; const float* bv  = (const float*)d_in[11];
    const float* Wqg = (const float*)d_in[12]; const float* bqg = (const float*)d_in[13];
    const float* Wkg = (const float*)d_in[14]; const float* bkg = (const float*)d_in[15];
    const float* Wvg = (const float*)d_in[16]; const float* bvg = (const float*)d_in[17];
    const float* Wo  = (const float*)d_in[18]; const float* bo  = (const float*)d_in[19];
    const float* ln1_g = (const float*)d_in[20]; const float* ln1_b = (const float*)d_in[21];
    const float* W1  = (const float*)d_in[22]; const float* bf1 = (const float*)d_in[23];
    const float* W2  = (const float*)d_in[24]; const float* bf2 = (const float*)d_in[25];
    const float* ln2_g = (const float*)d_in[26]; const float* ln2_b = (const float*)d_in[27];
    const float* Wp  = (const float*)d_in[28]; const float* bp  = (const float*)d_in[29];
    const float* Wc  = (const float*)d_in[30]; const float* bc  = (const float*)d_in[31];
    float* out = (float*)d_out;

    char* wsb = (char*)d_ws;
    float*          x      = (float*)(wsb + 0);
    unsigned short* xbf    = (unsigned short*)(wsb + 25165824);
    unsigned short* packed = (unsigned short*)(wsb + 37748736);
    unsigned short* vtb    = (unsigned short*)(wsb + 100663296);
    unsigned short* aout   = (unsigned short*)(wsb + 113246208);
    float*          hf     = (float*)(wsb + 125829120);
    char*           wts    = wsb + 150994944;
    float*          b5     = (float*)(wsb + 184025088);
    float*          qg     = (float*)(wsb + 184055808);
    float*          pm     = (float*)(wsb + 184061952);
    float*          pl     = (float*)(wsb + 184063488);
    float*          po     = (float*)(wsb + 184065024);
    float*          pooled = (float*)(wsb + 184163328);
    unsigned short* mid    = packed;

    const size_t SQ = (size_t)DD * DD;
    const size_t PER_L = (6 * SQ + 2 * (size_t)DD * FF) * 2;
    unsigned short* Wt5[2], *Wo_t[2], *W1_t[2], *W2_t[2];
    for (int l = 0; l < 2; l++) {
        char* base = wts + (size_t)l * PER_L;
        Wt5[l]  = (unsigned short*)base;
        Wo_t[l] = (unsigned short*)(base + 5 * SQ * 2);
        W1_t[l] = (unsigned short*)(base + 6 * SQ * 2);
        W2_t[l] = (unsigned short*)(base + 6 * SQ * 2 + (size_t)DD * FF * 2);
    }

    const int M = BB * SS;

    TP12 t12;
    for (int l = 0; l < 2; l++) {
        t12.s[l * 6 + 0] = Wq  + (size_t)l * SQ;  t12.d[l * 6 + 0] = Wt5[l] + 0 * SQ;
        t12.s[l * 6 + 1] = Wk  + (size_t)l * SQ;  t12.d[l * 6 + 1] = Wt5[l] + 1 * SQ;
        t12.s[l * 6 + 2] = Wv  + (size_t)l * SQ;  t12.d[l * 6 + 2] = Wt5[l] + 2 * SQ;
        t12.s[l * 6 + 3] = Wkg + (size_t)l * SQ;  t12.d[l * 6 + 3] = Wt5[l] + 3 * SQ;
        t12.s[l * 6 + 4] = Wvg + (size_t)l * SQ;  t12.d[l * 6 + 4] = Wt5[l] + 4 * SQ;
        t12.s[l * 6 + 5] = Wo  + (size_t)l * SQ;  t12.d[l * 6 + 5] = Wo_t[l];
    }
    TP4 t4;
    t4.s[0] = W1;                      t4.d[0] = W1_t[0];
    t4.s[1] = W1 + (size_t)DD * FF;    t4.d[1] = W1_t[1];
    t4.s[2] = W2;                      t4.d[2] = W2_t[0];
    t4.s[3] = W2 + (size_t)FF * DD;    t4.d[3] = W2_t[1];

    transpose12_k<<<dim3(24, 24, 12), 256, 0, stream>>>(t12);
    transposeR4_k<<<dim3(96, 24, 4), 256, 0, stream>>>(t4);
    pack_bias5_k<<<(2 * 5 * DD + 255) / 256, 256, 0, stream>>>(bq, bk, bv, bkg, bvg, b5);

    embed_ln_k<<<M, 256, 0, stream>>>(input_ids, word_emb, pos_emb, ln_e_g, ln_e_b, x, xbf);

    dim3 gqkv(M / 128, 3840 / 128);
    dim3 g768(M / 128, DD / 128);
    dim3 g3072(M / 128, FF / 128);

    for (int l = 0; l < 2; l++) {
        const float* Wqg_l = Wqg + (size_t)l * SQ; const float* bqg_l = bqg + (size_t)l * DD;
        const float* bo_l  = bo  + (size_t)l * DD;
        const float* bf1_l = bf1 + (size_t)l * FF;
        const float* bf2_l = bf2 + (size_t)l * DD;
        const float* g1_l  = ln1_g + (size_t)l * DD; const float* b1_l = ln1_b + (size_t)l * DD;
        const float* g2_l  = ln2_g + (size_t)l * DD; const float* b2_l = ln2_b + (size_t)l * DD;

        mfma_gemm_k<1, 0><<<gqkv, 256, 0, stream>>>(xbf, Wt5[l], b5 + (size_t)l * 3840,
                                                    packed, M, 3840, DD);
        vtrans_k<<<dim3(SS / 64, HH, BB), 256, 0, stream>>>(packed, vtb);
        rowgemv_k<0><<<dim3(DD / 64, BB), 256, 0, stream>>>(x, (size_t)SS * DD, Wqg_l, bqg_l, qg, DD);

        swin_mfma_k<<<dim3(SS / 128, HH, BB), 256, 0, stream>>>(packed, vtb, amask, aout);
        gattn1_k<<<dim3(16, HH, BB), 256, 0, stream>>>(qg, packed, amask, pm, pl, po);
        gattn2_k<<<dim3(HH, BB), 64, 0, stream>>>(pm, pl, po, aout);

        mfma_gemm_k<0, 0><<<g768, 256, 0, stream>>>(aout, Wo_t[l], bo_l, hf, M, DD, DD);
        add_ln_k<<<M, 256, 0, stream>>>(x, hf, g1_l, b1_l, x, xbf);

        mfma_gemm_k<1, 1><<<g3072, 256, 0, stream>>>(xbf, W1_t[l], bf1_l, mid, M, FF, DD);
        mfma_gemm_k<0, 0><<<g768, 256, 0, stream>>>(mid, W2_t[l], bf2_l, hf, M, DD, FF);
        add_ln_k<<<M, 256, 0, stream>>>(x, hf, g2_l, b2_l, x, xbf);
    }

    rowgemv_k<1><<<dim3(DD / 64, BB), 256, 0, stream>>>(x, (size_t)SS * DD, Wp, bp, pooled, DD);
    cls_k<<<1, 256, 0, stream>>>(pooled, Wc, bc, out);
}

// Round 10
// 711.517 us; speedup vs baseline: 8.3173x; 1.0675x over previous
//
#include <hip/hip_runtime.h>
#include <hip/hip_bf16.h>
#include <math.h>

#define BB 2
#define SS 4096
#define DD 768
#define HH 12
#define DHH 64
#define WW 256
#define CC 16
#define FF 3072

typedef __attribute__((ext_vector_type(8))) short bf16x8;
typedef __attribute__((ext_vector_type(4))) float f32x4;

struct TP12 { const float* s[12]; unsigned short* d[12]; };
struct TP4  { const float* s[4];  unsigned short* d[4];  };

// gelu(x) = 0.5x(1+tanh(u)) = x * sigmoid(2u), u = 0.79788456(x + 0.044715 x^3)
__device__ __forceinline__ float gelu_f(float x) {
    float u = 0.7978845608028654f * fmaf(0.044715f * x * x, x, x);
    return x / (1.f + __expf(-2.f * u));
}

__device__ __forceinline__ unsigned short bfb(float f) {
    __hip_bfloat16 h = __float2bfloat16(f);
    return *(unsigned short*)&h;
}

__device__ __forceinline__ float bf2f(unsigned short u) {
    return __uint_as_float(((unsigned int)u) << 16);
}

__device__ __forceinline__ void gload16(const void* g, void* l) {
    __builtin_amdgcn_global_load_lds(
        (const __attribute__((address_space(1))) unsigned int*)g,
        (__attribute__((address_space(3))) unsigned int*)l, 16, 0, 0);
}

// ---------------- fused weight transposes: fp32 [K][N] -> bf16 [N][K] ----------------
__global__ __launch_bounds__(256) void transpose12_k(TP12 p)
{
    __shared__ float t[32][33];
    int z = blockIdx.z;
    const float* Wsrc = p.s[z];
    unsigned short* Wt = p.d[z];
    const int K = DD, N = DD;
    int n0 = blockIdx.x * 32, k0 = blockIdx.y * 32;
    int tx = threadIdx.x & 31, ty = threadIdx.x >> 5;
#pragma unroll
    for (int i = 0; i < 32; i += 8)
        t[ty + i][tx] = Wsrc[(size_t)(k0 + ty + i) * N + n0 + tx];
    __syncthreads();
#pragma unroll
    for (int i = 0; i < 32; i += 8)
        Wt[(size_t)(n0 + ty + i) * K + k0 + tx] = bfb(t[tx][ty + i]);
}

__global__ __launch_bounds__(256) void transposeR4_k(TP4 p)
{
    __shared__ float t[32][33];
    int z = blockIdx.z;
    const float* Wsrc = p.s[z];
    unsigned short* Wt = p.d[z];
    int K, N, n0, k0;
    if (z < 2) { K = DD; N = FF; n0 = blockIdx.x * 32; k0 = blockIdx.y * 32; }
    else { K = FF; N = DD; int cell = blockIdx.y * 96 + blockIdx.x;
           n0 = (cell % 24) * 32; k0 = (cell / 24) * 32; }
    int tx = threadIdx.x & 31, ty = threadIdx.x >> 5;
#pragma unroll
    for (int i = 0; i < 32; i += 8)
        t[ty + i][tx] = Wsrc[(size_t)(k0 + ty + i) * N + n0 + tx];
    __syncthreads();
#pragma unroll
    for (int i = 0; i < 32; i += 8)
        Wt[(size_t)(n0 + ty + i) * K + k0 + tx] = bfb(t[tx][ty + i]);
}

// ---------------- pack 5 bias vectors [2][768] each -> [2][3840] ----------------
__global__ __launch_bounds__(256) void pack_bias5_k(const float* __restrict__ b0,
        const float* __restrict__ b1, const float* __restrict__ b2,
        const float* __restrict__ b3, const float* __restrict__ b4,
        float* __restrict__ dst)
{
    int gid = blockIdx.x * 256 + threadIdx.x;
    if (gid >= 2 * 5 * DD) return;
    int l = gid / (5 * DD), r = gid % (5 * DD), seg = r / DD, i = r % DD;
    const float* srcs[5] = { b0, b1, b2, b3, b4 };
    dst[gid] = srcs[seg][l * DD + i];
}

// ---------------- embedding + LayerNorm (float4 + shfl reduce, 1 barrier) ----------------
__global__ __launch_bounds__(256) void embed_ln_k(const int* __restrict__ ids,
        const float* __restrict__ wemb, const float* __restrict__ pemb,
        const float* __restrict__ g, const float* __restrict__ bta,
        float* __restrict__ x, unsigned short* __restrict__ xbf)
{
    int row = blockIdx.x;
    int s = row & (SS - 1);
    int tid = threadIdx.x;
    int lane = tid & 63, wvi = tid >> 6;
    __shared__ float red[8];
    float4 v = { 0.f, 0.f, 0.f, 0.f };
    if (tid < 192) {
        const float4* we = (const float4*)(wemb + (size_t)ids[row] * DD);
        const float4* pe = (const float4*)(pemb + (size_t)s * DD);
        float4 a = we[tid], b = pe[tid];
        v.x = a.x + b.x; v.y = a.y + b.y; v.z = a.z + b.z; v.w = a.w + b.w;
    }
    float sum = (v.x + v.y) + (v.z + v.w);
    float sq = fmaf(v.x, v.x, fmaf(v.y, v.y, fmaf(v.z, v.z, v.w * v.w)));
#pragma unroll
    for (int o = 1; o < 64; o <<= 1) {
        sum += __shfl_xor(sum, o);
        sq  += __shfl_xor(sq, o);
    }
    if (lane == 0) { red[wvi] = sum; red[4 + wvi] = sq; }
    __syncthreads();
    float S = (red[0] + red[1]) + (red[2] + red[3]);
    float Q = (red[4] + red[5]) + (red[6] + red[7]);
    float mean = S * (1.f / DD);
    float var = Q * (1.f / DD) - mean * mean;
    float rstd = rsqrtf(var + 1e-5f);
    if (tid < 192) {
        float4 gg = ((const float4*)g)[tid];
        float4 bb = ((const float4*)bta)[tid];
        float4 o;
        o.x = (v.x - mean) * rstd * gg.x + bb.x;
        o.y = (v.y - mean) * rstd * gg.y + bb.y;
        o.z = (v.z - mean) * rstd * gg.z + bb.z;
        o.w = (v.w - mean) * rstd * gg.w + bb.w;
        ((float4*)(x + (size_t)row * DD))[tid] = o;
        ushort4 ob = { bfb(o.x), bfb(o.y), bfb(o.z), bfb(o.w) };
        ((ushort4*)(xbf + (size_t)row * DD))[tid] = ob;
    }
}

// ---------------- residual add + LayerNorm (float4 + shfl reduce) ----------------
__global__ __launch_bounds__(256) void add_ln_k(const float* __restrict__ xin,
        const float* __restrict__ hin, const float* __restrict__ g,
        const float* __restrict__ bta, float* __restrict__ xout,
        unsigned short* __restrict__ xbf)
{
    int row = blockIdx.x;
    int tid = threadIdx.x;
    int lane = tid & 63, wvi = tid >> 6;
    __shared__ float red[8];
    float4 v = { 0.f, 0.f, 0.f, 0.f };
    if (tid < 192) {
        float4 a = ((const float4*)(xin + (size_t)row * DD))[tid];
        float4 b = ((const float4*)(hin + (size_t)row * DD))[tid];
        v.x = a.x + b.x; v.y = a.y + b.y; v.z = a.z + b.z; v.w = a.w + b.w;
    }
    float sum = (v.x + v.y) + (v.z + v.w);
    float sq = fmaf(v.x, v.x, fmaf(v.y, v.y, fmaf(v.z, v.z, v.w * v.w)));
#pragma unroll
    for (int o = 1; o < 64; o <<= 1) {
        sum += __shfl_xor(sum, o);
        sq  += __shfl_xor(sq, o);
    }
    if (lane == 0) { red[wvi] = sum; red[4 + wvi] = sq; }
    __syncthreads();
    float S = (red[0] + red[1]) + (red[2] + red[3]);
    float Q = (red[4] + red[5]) + (red[6] + red[7]);
    float mean = S * (1.f / DD);
    float var = Q * (1.f / DD) - mean * mean;
    float rstd = rsqrtf(var + 1e-5f);
    if (tid < 192) {
        float4 gg = ((const float4*)g)[tid];
        float4 bb = ((const float4*)bta)[tid];
        float4 o;
        o.x = (v.x - mean) * rstd * gg.x + bb.x;
        o.y = (v.y - mean) * rstd * gg.y + bb.y;
        o.z = (v.z - mean) * rstd * gg.z + bb.z;
        o.w = (v.w - mean) * rstd * gg.w + bb.w;
        ((float4*)(xout + (size_t)row * DD))[tid] = o;
        ushort4 ob = { bfb(o.x), bfb(o.y), bfb(o.z), bfb(o.w) };
        ((ushort4*)(xbf + (size_t)row * DD))[tid] = ob;
    }
}

// ---------------- bf16 MFMA GEMM, BK=64, XOR-swizzled LDS, bn-fast L2 tiling ----------------
// XCD chunk = contiguous nid range; bn varies fastest so each XCD holds a small
// L2-resident A row-panel chunk and sweeps B (L3-served).
template<int OUT_BF16, int ACT_GELU>
__global__ __launch_bounds__(256) void mfma_gemm_k(
        const unsigned short* __restrict__ A,
        const unsigned short* __restrict__ Bt,
        const float* __restrict__ bias,
        void* __restrict__ Cv, int M, int N, int K)
{
    __shared__ short As[128 * 64];   // 16 KB
    __shared__ short Bs[128 * 64];   // 16 KB
    const int tid = threadIdx.x;
    const int lane = tid & 63, wv = tid >> 6;
    // XCD-aware bijective swizzle (all grids have nwg % 8 == 0)
    int nbx = gridDim.x;
    int nby = gridDim.y;
    int nwg = nbx * nby;
    int lid = blockIdx.y * nbx + blockIdx.x;
    int nid = ((nwg & 7) == 0) ? ((lid & 7) * (nwg >> 3) + (lid >> 3)) : lid;
    const int bm = (nid / nby) * 128, bn = (nid % nby) * 128;   // bn fastest
    const int wm = wv >> 1, wn = wv & 1;

    const int srow0 = (tid * 16) >> 7;          // 0..31
    const int sbc   = (tid * 16) & 127;
    const int srcc  = sbc ^ ((srow0 & 7) << 4); // pre-swizzled source byte col
    const int ldst  = tid * 16;
    const char* Ab = (const char*)(A + (size_t)bm * K);
    const char* Bb = (const char*)(Bt + (size_t)bn * K);

    f32x4 acc[4][4];
#pragma unroll
    for (int i = 0; i < 4; i++)
#pragma unroll
        for (int j = 0; j < 4; j++) acc[i][j] = (f32x4){0.f, 0.f, 0.f, 0.f};

    const int lr = lane & 15;
    const int g = lane >> 4;
    const int rswz = (lr & 7) << 4;

    for (int k0 = 0; k0 < K; k0 += 64) {
        __syncthreads();
#pragma unroll
        for (int p = 0; p < 4; p++) {
            size_t roff = (size_t)(srow0 + p * 32) * (K * 2) + (size_t)k0 * 2 + srcc;
            gload16(Ab + roff, (char*)As + p * 4096 + ldst);
            gload16(Bb + roff, (char*)Bs + p * 4096 + ldst);
        }
        __syncthreads();
#pragma unroll
        for (int kk = 0; kk < 2; kk++) {
            int colb = (kk * 64 + g * 16) ^ rswz;
            bf16x8 af[4], bfr[4];
#pragma unroll
            for (int i = 0; i < 4; i++)
                af[i] = *(const bf16x8*)((const char*)As + (wm * 64 + i * 16 + lr) * 128 + colb);
#pragma unroll
            for (int j = 0; j < 4; j++)
                bfr[j] = *(const bf16x8*)((const char*)Bs + (wn * 64 + j * 16 + lr) * 128 + colb);
#pragma unroll
            for (int i = 0; i < 4; i++)
#pragma unroll
                for (int j = 0; j < 4; j++)
                    acc[i][j] = __builtin_amdgcn_mfma_f32_16x16x32_bf16(af[i], bfr[j], acc[i][j], 0, 0, 0);
        }
    }

    const int rq = lane >> 4;
#pragma unroll
    for (int j = 0; j < 4; j++) {
        int col = bn + wn * 64 + j * 16 + lr;
        float bv = bias[col];
#pragma unroll
        for (int i = 0; i < 4; i++) {
            int rowb = bm + wm * 64 + i * 16 + rq * 4;
#pragma unroll
            for (int r = 0; r < 4; r++) {
                float o = acc[i][j][r] + bv;
                if (ACT_GELU) o = gelu_f(o);
                if (OUT_BF16)
                    ((unsigned short*)Cv)[(size_t)(rowb + r) * N + col] = bfb(o);
                else
                    ((float*)Cv)[(size_t)(rowb + r) * N + col] = o;
            }
        }
    }
}

// ---------------- V head-transpose ----------------
__global__ __launch_bounds__(256) void vtrans_k(const unsigned short* __restrict__ packed,
        unsigned short* __restrict__ vt)
{
    int s0 = blockIdx.x * 64, h = blockIdx.y, b = blockIdx.z;
    int tid = threadIdx.x;
    __shared__ unsigned short t[64][72];
    int r = tid >> 3, dc = (tid & 7) * 8;
#pragma unroll
    for (int half = 0; half < 2; half++) {
        int rr = r + half * 32;
        const unsigned short* src = packed + (size_t)(b * SS + s0 + rr) * 3840 + 2 * DD + h * 64 + dc;
        *(uint4*)&t[rr][dc] = *(const uint4*)src;
    }
    __syncthreads();
    int d = tid >> 3, sc = (tid & 7) * 8;
#pragma unroll
    for (int half = 0; half < 2; half++) {
        int dd2 = d + half * 32;
        unsigned short v[8];
#pragma unroll
        for (int e = 0; e < 8; e++) v[e] = t[sc + e][dd2];
        unsigned short* dst = vt + (size_t)((b * HH + h) * 64 + dd2) * SS + s0 + sc;
        *(uint4*)dst = *(uint4*)v;
    }
}

// ---------------- MFMA sliding-window flash attention (128-q blocks, dbuf pipeline) ----------------
__global__ __launch_bounds__(256) void swin_mfma_k(
        const unsigned short* __restrict__ packed,
        const unsigned short* __restrict__ vt,
        const int* __restrict__ mask,
        unsigned short* __restrict__ O)
{
    __shared__ __align__(16) char smem[52736];
    const int c2 = blockIdx.x, h = blockIdx.y, b = blockIdx.z;
    const int tid = threadIdx.x;
    const int lane = tid & 63, wv = tid >> 6;
    const int l15 = lane & 15, g = lane >> 4;
    const int bh = b * HH + h;
    const int q0 = c2 * 128;

    char* PB = smem + 32768 + wv * 4096;
    float* maskAll = (float*)(smem + 49152);
    float* sA = (float*)(smem + 51712);
    float* sB = (float*)(smem + 52224);

    const char* pk_bytes = (const char*)packed;
    const char* vt_bytes = (const char*)vt;

    bf16x8 qf[2][2];
#pragma unroll
    for (int j = 0; j < 2; j++)
#pragma unroll
        for (int kk = 0; kk < 2; kk++)
            qf[j][kk] = *(const bf16x8*)(packed +
                (size_t)(b * SS + q0 + wv * 32 + j * 16 + l15) * 3840 + h * 64 + kk * 32 + g * 8);
    bf16x8 gkf[2];
#pragma unroll
    for (int kk = 0; kk < 2; kk++)
        gkf[kk] = *(const bf16x8*)(packed + (size_t)(b * SS) * 3840 + DD + h * 64 + kk * 32 + g * 8);
    float v0r[4];
#pragma unroll
    for (int jd = 0; jd < 4; jd++)
        v0r[jd] = bf2f(vt[(size_t)(bh * 64 + jd * 16 + l15) * SS]);

    f32x4 o_[2][4];
#pragma unroll
    for (int i = 0; i < 2; i++)
#pragma unroll
        for (int j = 0; j < 4; j++) o_[i][j] = (f32x4){0.f, 0.f, 0.f, 0.f};
    float m_[2] = { -1e20f, -1e20f };
    float l_[2] = { 0.f, 0.f };

    const int rswz = (l15 & 7) << 4;
    const int kt_s = max(0, 4 - 2 * c2);
    const int kt_e = min(10, 68 - 2 * c2);
    const int lo = wv >> 1;

    auto stage = [&](int ib, int kt) {
        const int kpos0 = q0 - 256 + kt * 64;
        char* KTd = smem + ib * 8192;
        char* VTd = smem + 16384 + ib * 8192;
        int off = tid * 16;
#pragma unroll
        for (int ch = 0; ch < 2; ch++) {
            int o2 = off + ch * 4096;
            int row = o2 >> 7, bc = o2 & 127;
            int srcc = bc ^ ((row & 7) << 4);
            gload16(pk_bytes + (size_t)(b * SS + kpos0 + row) * 7680 + 1536 + h * 128 + srcc,
                    KTd + o2);
            gload16(vt_bytes + (size_t)(bh * 64 + row) * 8192 + (size_t)(kpos0 * 2 + srcc),
                    VTd + o2);
        }
    };

    stage(0, kt_s);
    {
        int span = (kt_e - kt_s) * 64;
        int base_k = q0 - 256 + kt_s * 64;
        for (int idx = tid; idx < span; idx += 256) {
            int kp = base_k + idx;
            maskAll[kt_s * 64 + idx] = (mask[b * SS + kp] > 0) ? 0.f : -1e30f;
        }
    }
    __syncthreads();

    int cur = 0;
    for (int kt = kt_s; kt < kt_e; kt++) {
        if (kt + 1 < kt_e) stage(cur ^ 1, kt + 1);

        const int dl = kt - lo;
        if (dl >= 0 && dl <= 8) {
            const char* KT = smem + cur * 8192;
            const char* VT = smem + 16384 + cur * 8192;
            const bool edge = (dl == 0) || (dl == 8);

            f32x4 mrd[4];
#pragma unroll
            for (int i = 0; i < 4; i++)
                mrd[i] = *(const f32x4*)&maskAll[kt * 64 + i * 16 + g * 4];

            f32x4 s_[4][2];
#pragma unroll
            for (int i = 0; i < 4; i++)
#pragma unroll
                for (int j = 0; j < 2; j++) s_[i][j] = (f32x4){0.f, 0.f, 0.f, 0.f};
            __builtin_amdgcn_s_setprio(1);
#pragma unroll
            for (int kk = 0; kk < 2; kk++) {
                bf16x8 af[4];
#pragma unroll
                for (int i = 0; i < 4; i++)
                    af[i] = *(const bf16x8*)(KT + (i * 16 + l15) * 128 + ((kk * 64 + g * 16) ^ rswz));
#pragma unroll
                for (int i = 0; i < 4; i++)
#pragma unroll
                    for (int j = 0; j < 2; j++)
                        s_[i][j] = __builtin_amdgcn_mfma_f32_16x16x32_bf16(af[i], qf[j][kk], s_[i][j], 0, 0, 0);
            }
            __builtin_amdgcn_s_setprio(0);

#pragma unroll
            for (int j = 0; j < 2; j++) {
                float tm = -1e30f;
                if (edge) {
#pragma unroll
                    for (int i = 0; i < 4; i++) {
#pragma unroll
                        for (int r = 0; r < 4; r++) {
                            float v = fmaf(s_[i][j][r], 0.125f, mrd[i][r]);
                            int rel = kt * 64 - 256 + i * 16 + g * 4 + r - wv * 32 - j * 16 - l15;
                            v = (rel > 256 || rel < -256) ? -1e30f : v;
                            s_[i][j][r] = v;
                            tm = fmaxf(tm, v);
                        }
                    }
                } else {
#pragma unroll
                    for (int i = 0; i < 4; i++) {
#pragma unroll
                        for (int r = 0; r < 4; r++) {
                            float v = fmaf(s_[i][j][r], 0.125f, mrd[i][r]);
                            s_[i][j][r] = v;
                            tm = fmaxf(tm, v);
                        }
                    }
                }
                tm = fmaxf(tm, __shfl_xor(tm, 16));
                tm = fmaxf(tm, __shfl_xor(tm, 32));
                float mn = fmaxf(m_[j], tm);
                float fac = __expf(m_[j] - mn);
                m_[j] = mn;
                float ls = 0.f;
                int q32 = j * 16 + l15;
#pragma unroll
                for (int i = 0; i < 4; i++) {
                    float p0 = __expf(s_[i][j][0] - mn);
                    float p1 = __expf(s_[i][j][1] - mn);
                    float p2 = __expf(s_[i][j][2] - mn);
                    float p3 = __expf(s_[i][j][3] - mn);
                    ls += (p0 + p1) + (p2 + p3);
                    uint2 pw;
                    pw.x = (unsigned int)bfb(p0) | ((unsigned int)bfb(p1) << 16);
                    pw.y = (unsigned int)bfb(p2) | ((unsigned int)bfb(p3) << 16);
                    *(uint2*)(PB + q32 * 128 + ((i * 32 + g * 8) ^ rswz)) = pw;
                }
                ls += __shfl_xor(ls, 16);
                ls += __shfl_xor(ls, 32);
                l_[j] = l_[j] * fac + ls;
                if (g == 0) sA[wv * 32 + q32] = fac;
            }

#pragma unroll
            for (int iq = 0; iq < 2; iq++) {
                f32x4 fc = *(const f32x4*)&sA[wv * 32 + iq * 16 + g * 4];
#pragma unroll
                for (int jd = 0; jd < 4; jd++)
#pragma unroll
                    for (int r = 0; r < 4; r++) o_[iq][jd][r] *= fc[r];
            }
            __builtin_amdgcn_s_setprio(1);
#pragma unroll
            for (int kk = 0; kk < 2; kk++) {
                bf16x8 pa[2], vb[4];
#pragma unroll
                for (int iq = 0; iq < 2; iq++)
                    pa[iq] = *(const bf16x8*)(PB + (iq * 16 + l15) * 128 + ((kk * 64 + g * 16) ^ rswz));
#pragma unroll
                for (int jd = 0; jd < 4; jd++)
                    vb[jd] = *(const bf16x8*)(VT + (jd * 16 + l15) * 128 + ((kk * 64 + g * 16) ^ rswz));
#pragma unroll
                for (int iq = 0; iq < 2; iq++)
#pragma unroll
                    for (int jd = 0; jd < 4; jd++)
                        o_[iq][jd] = __builtin_amdgcn_mfma_f32_16x16x32_bf16(pa[iq], vb[jd], o_[iq][jd], 0, 0, 0);
            }
            __builtin_amdgcn_s_setprio(0);
        }

        asm volatile("s_waitcnt vmcnt(0)" ::: "memory");
        __builtin_amdgcn_sched_barrier(0);
        __builtin_amdgcn_s_barrier();
        __builtin_amdgcn_sched_barrier(0);
        cur ^= 1;
    }

#pragma unroll
    for (int j = 0; j < 2; j++) {
        float pd = 0.f;
#pragma unroll
        for (int kk = 0; kk < 2; kk++)
#pragma unroll
            for (int e = 0; e < 8; e++)
                pd += bf2f((unsigned short)qf[j][kk][e]) * bf2f((unsigned short)gkf[kk][e]);
        pd += __shfl_xor(pd, 16);
        pd += __shfl_xor(pd, 32);
        float sg = pd * 0.125f;
        float mf = fmaxf(m_[j], sg);
        float fac = __expf(m_[j] - mf);
        float pg = __expf(sg - mf);
        float lf = l_[j] * fac + pg;
        float inv = 1.f / lf;
        if (g == 0) {
            sA[wv * 32 + j * 16 + l15] = fac * inv;
            sB[wv * 32 + j * 16 + l15] = pg * inv;
        }
    }
#pragma unroll
    for (int iq = 0; iq < 2; iq++) {
        f32x4 fA = *(const f32x4*)&sA[wv * 32 + iq * 16 + g * 4];
        f32x4 fB = *(const f32x4*)&sB[wv * 32 + iq * 16 + g * 4];
#pragma unroll
        for (int jd = 0; jd < 4; jd++) {
#pragma unroll
            for (int r = 0; r < 4; r++) {
                float val = o_[iq][jd][r] * fA[r] + fB[r] * v0r[jd];
                int row = b * SS + q0 + wv * 32 + iq * 16 + g * 4 + r;
                O[(size_t)row * DD + h * 64 + jd * 16 + l15] = bfb(val);
            }
        }
    }
}

// ---------------- global-token attention, phase 1 ----------------
__global__ __launch_bounds__(256) void gattn1_k(const float* __restrict__ qg,
        const unsigned short* __restrict__ packed, const int* __restrict__ mask,
        float* __restrict__ pm, float* __restrict__ pl, float* __restrict__ po)
{
    int cc = blockIdx.x, h = blockIdx.y, b = blockIdx.z;
    int tid = threadIdx.x;
    __shared__ float qs[64], red[256], ps[256], ored[4][64];
    if (tid < 64) qs[tid] = qg[b * DD + h * 64 + tid];
    __syncthreads();
    int s = cc * 256 + tid;
    const unsigned short* kr = packed + (size_t)(b * SS + s) * 3840 + 3 * DD + h * 64;
    float a = 0.f;
#pragma unroll
    for (int d8 = 0; d8 < 8; d8++) {
        bf16x8 kv = *(const bf16x8*)(kr + d8 * 8);
#pragma unroll
        for (int e = 0; e < 8; e++)
            a = fmaf(qs[d8 * 8 + e], bf2f((unsigned short)kv[e]), a);
    }
    a *= 0.125f;
    float sv = (mask[b * SS + s] > 0) ? a : -1e9f;
    red[tid] = sv; __syncthreads();
    for (int o = 128; o > 0; o >>= 1) {
        if (tid < o) red[tid] = fmaxf(red[tid], red[tid + o]);
        __syncthreads();
    }
    float mx = red[0]; __syncthreads();
    float p = __expf(sv - mx);
    ps[tid] = p;
    red[tid] = p; __syncthreads();
    for (int o = 128; o > 0; o >>= 1) {
        if (tid < o) red[tid] += red[tid + o];
        __syncthreads();
    }
    float ls = red[0];
    int d = tid & 63, grp = tid >> 6;
    const unsigned short* vgb = packed + 4 * DD + h * 64 + d;
    float oa = 0.f;
    for (int t = 0; t < 64; t++) {
        int srow = cc * 256 + grp * 64 + t;
        oa = fmaf(ps[grp * 64 + t], bf2f(vgb[(size_t)(b * SS + srow) * 3840]), oa);
    }
    ored[grp][d] = oa; __syncthreads();
    if (tid < 64) {
        int idx = (b * HH + h) * 16 + cc;
        po[(size_t)idx * 64 + tid] = ored[0][tid] + ored[1][tid] + ored[2][tid] + ored[3][tid];
        if (tid == 0) { pm[idx] = mx; pl[idx] = ls; }
    }
}

// ---------------- global-token attention, phase 2 ----------------
__global__ __launch_bounds__(64) void gattn2_k(const float* __restrict__ pm,
        const float* __restrict__ pl, const float* __restrict__ po,
        unsigned short* __restrict__ O)
{
    int h = blockIdx.x, b = blockIdx.y;
    int tid = threadIdx.x;
    int base = (b * HH + h) * 16;
    float mx = -1e30f;
    for (int c2 = 0; c2 < 16; c2++) mx = fmaxf(mx, pm[base + c2]);
    float den = 0.f, oa = 0.f;
    for (int c2 = 0; c2 < 16; c2++) {
        float w = __expf(pm[base + c2] - mx);
        den = fmaf(pl[base + c2], w, den);
        oa = fmaf(po[(size_t)(base + c2) * 64 + tid], w, oa);
    }
    O[(size_t)(b * SS) * DD + h * 64 + tid] = bfb(oa / den);
}

// ---------------- row-GEMV ----------------
template<int ACT_TANH>
__global__ __launch_bounds__(256) void rowgemv_k(const float* __restrict__ x,
        size_t xstride, const float* __restrict__ W, const float* __restrict__ bias,
        float* __restrict__ dst, int N)
{
    int b = blockIdx.y;
    int colL = threadIdx.x & 63, part = threadIdx.x >> 6;
    int col = blockIdx.x * 64 + colL;
    __shared__ float partial[4][64];
    const float* xr = x + (size_t)b * xstride;
    float a = 0.f;
    for (int k = part * (DD / 4); k < (part + 1) * (DD / 4); k++)
        a = fmaf(xr[k], W[(size_t)k * N + col], a);
    partial[part][colL] = a; __syncthreads();
    if (part == 0) {
        float s = partial[0][colL] + partial[1][colL] + partial[2][colL] + partial[3][colL]
                + bias[col];
        if (ACT_TANH) s = tanhf(s);
        dst[b * N + col] = s;
    }
}

// ---------------- classifier ----------------
__global__ __launch_bounds__(256) void cls_k(const float* __restrict__ pooled,
        const float* __restrict__ Wc, const float* __restrict__ bc,
        float* __restrict__ out)
{
    int lane = threadIdx.x & 63, pair = threadIdx.x >> 6;
    int b = pair >> 1, cls = pair & 1;
    float a = 0.f;
#pragma unroll
    for (int j = 0; j < 12; j++) {
        int k = lane + j * 64;
        a = fmaf(pooled[b * DD + k], Wc[k * 2 + cls], a);
    }
#pragma unroll
    for (int o = 1; o < 64; o <<= 1) a += __shfl_xor(a, o);
    if (lane == 0) out[b * 2 + cls] = a + bc[cls];
}

extern "C" void kernel_launch(void* const* d_in, const int* in_sizes, int n_in,
                              void* d_out, int out_size, void* d_ws, size_t ws_size,
                              hipStream_t stream) {
    const int*   input_ids = (const int*)d_in[0];
    const int*   amask     = (const int*)d_in[1];
    const float* word_emb  = (const float*)d_in[2];
    const float* pos_emb   = (const float*)d_in[3];
    const float* ln_e_g    = (const float*)d_in[4];
    const float* ln_e_b    = (const float*)d_in[5];
    const float* Wq  = (const float*)d_in[6];  const float* bq  = (const float*)d_in[7];
    const float* Wk  = (const float*)d_in[8];  const float* bk  = (const float*)d_in[9];
    const float* Wv  = (const float*)d_in[10]; const float* bv  = (const float*)d_in[11];
    const float* Wqg = (const float*)d_in[12]; const float* bqg = (const float*)d_in[13];
    const float* Wkg = (const float*)d_in[14]; const float* bkg = (const float*)d_in[15];
    const float* Wvg = (const float*)d_in[16]; const float* bvg = (const float*)d_in[17];
    const float* Wo  = (const float*)d_in[18]; const float* bo  = (const float*)d_in[19];
    const float* ln1_g = (const float*)d_in[20]; const float* ln1_b = (const float*)d_in[21];
    const float* W1  = (const float*)d_in[22]; const float* bf1 = (const float*)d_in[23];
    const float* W2  = (const float*)d_in[24]; const float* bf2 = (const float*)d_in[25];
    const float* ln2_g = (const float*)d_in[26]; const float* ln2_b = (const float*)d_in[27];
    const float* Wp  = (const float*)d_in[28]; const float* bp  = (const float*)d_in[29];
    const float* Wc  = (const float*)d_in[30]; const float* bc  = (const float*)d_in[31];
    float* out = (float*)d_out;

    char* wsb = (char*)d_ws;
    float*          x      = (float*)(wsb + 0);
    unsigned short* xbf    = (unsigned short*)(wsb + 25165824);
    unsigned short* packed = (unsigned short*)(wsb + 37748736);
    unsigned short* vtb    = (unsigned short*)(wsb + 100663296);
    unsigned short* aout   = (unsigned short*)(wsb + 113246208);
    float*          hf     = (float*)(wsb + 125829120);
    char*           wts    = wsb + 150994944;
    float*          b5     = (float*)(wsb + 184025088);
    float*          qg     = (float*)(wsb + 184055808);
    float*          pm     = (float*)(wsb + 184061952);
    float*          pl     = (float*)(wsb + 184063488);
    float*          po     = (float*)(wsb + 184065024);
    float*          pooled = (float*)(wsb + 184163328);
    unsigned short* mid    = packed;

    const size_t SQ = (size_t)DD * DD;
    const size_t PER_L = (6 * SQ + 2 * (size_t)DD * FF) * 2;
    unsigned short* Wt5[2], *Wo_t[2], *W1_t[2], *W2_t[2];
    for (int l = 0; l < 2; l++) {
        char* base = wts + (size_t)l * PER_L;
        Wt5[l]  = (unsigned short*)base;
        Wo_t[l] = (unsigned short*)(base + 5 * SQ * 2);
        W1_t[l] = (unsigned short*)(base + 6 * SQ * 2);
        W2_t[l] = (unsigned short*)(base + 6 * SQ * 2 + (size_t)DD * FF * 2);
    }

    const int M = BB * SS;

    TP12 t12;
    for (int l = 0; l < 2; l++) {
        t12.s[l * 6 + 0] = Wq  + (size_t)l * SQ;  t12.d[l * 6 + 0] = Wt5[l] + 0 * SQ;
        t12.s[l * 6 + 1] = Wk  + (size_t)l * SQ;  t12.d[l * 6 + 1] = Wt5[l] + 1 * SQ;
        t12.s[l * 6 + 2] = Wv  + (size_t)l * SQ;  t12.d[l * 6 + 2] = Wt5[l] + 2 * SQ;
        t12.s[l * 6 + 3] = Wkg + (size_t)l * SQ;  t12.d[l * 6 + 3] = Wt5[l] + 3 * SQ;
        t12.s[l * 6 + 4] = Wvg + (size_t)l * SQ;  t12.d[l * 6 + 4] = Wt5[l] + 4 * SQ;
        t12.s[l * 6 + 5] = Wo  + (size_t)l * SQ;  t12.d[l * 6 + 5] = Wo_t[l];
    }
    TP4 t4;
    t4.s[0] = W1;                      t4.d[0] = W1_t[0];
    t4.s[1] = W1 + (size_t)DD * FF;    t4.d[1] = W1_t[1];
    t4.s[2] = W2;                      t4.d[2] = W2_t[0];
    t4.s[3] = W2 + (size_t)FF * DD;    t4.d[3] = W2_t[1];

    transpose12_k<<<dim3(24, 24, 12), 256, 0, stream>>>(t12);
    transposeR4_k<<<dim3(96, 24, 4), 256, 0, stream>>>(t4);
    pack_bias5_k<<<(2 * 5 * DD + 255) / 256, 256, 0, stream>>>(bq, bk, bv, bkg, bvg, b5);

    embed_ln_k<<<M, 256, 0, stream>>>(input_ids, word_emb, pos_emb, ln_e_g, ln_e_b, x, xbf);

    dim3 gqkv(M / 128, 3840 / 128);
    dim3 g768(M / 128, DD / 128);
    dim3 g3072(M / 128, FF / 128);

    for (int l = 0; l < 2; l++) {
        const float* Wqg_l = Wqg + (size_t)l * SQ; const float* bqg_l = bqg + (size_t)l * DD;
        const float* bo_l  = bo  + (size_t)l * DD;
        const float* bf1_l = bf1 + (size_t)l * FF;
        const float* bf2_l = bf2 + (size_t)l * DD;
        const float* g1_l  = ln1_g + (size_t)l * DD; const float* b1_l = ln1_b + (size_t)l * DD;
        const float* g2_l  = ln2_g + (size_t)l * DD; const float* b2_l = ln2_b + (size_t)l * DD;

        mfma_gemm_k<1, 0><<<gqkv, 256, 0, stream>>>(xbf, Wt5[l], b5 + (size_t)l * 3840,
                                                    packed, M, 3840, DD);
        vtrans_k<<<dim3(SS / 64, HH, BB), 256, 0, stream>>>(packed, vtb);
        rowgemv_k<0><<<dim3(DD / 64, BB), 256, 0, stream>>>(x, (size_t)SS * DD, Wqg_l, bqg_l, qg, DD);

        swin_mfma_k<<<dim3(SS / 128, HH, BB), 256, 0, stream>>>(packed, vtb, amask, aout);
        gattn1_k<<<dim3(16, HH, BB), 256, 0, stream>>>(qg, packed, amask, pm, pl, po);
        gattn2_k<<<dim3(HH, BB), 64, 0, stream>>>(pm, pl, po, aout);

        mfma_gemm_k<0, 0><<<g768, 256, 0, stream>>>(aout, Wo_t[l], bo_l, hf, M, DD, DD);
        add_ln_k<<<M, 256, 0, stream>>>(x, hf, g1_l, b1_l, x, xbf);

        mfma_gemm_k<1, 1><<<g3072, 256, 0, stream>>>(xbf, W1_t[l], bf1_l, mid, M, FF, DD);
        mfma_gemm_k<0, 0><<<g768, 256, 0, stream>>>(mid, W2_t[l], bf2_l, hf, M, DD, FF);
        add_ln_k<<<M, 256, 0, stream>>>(x, hf, g2_l, b2_l, x, xbf);
    }

    rowgemv_k<1><<<dim3(DD / 64, BB), 256, 0, stream>>>(x, (size_t)SS * DD, Wp, bp, pooled, DD);
    cls_k<<<1, 256, 0, stream>>>(pooled, Wc, bc, out);
}

// Round 11
// 686.285 us; speedup vs baseline: 8.6230x; 1.0368x over previous
//
#include <hip/hip_runtime.h>
#include <hip/hip_bf16.h>
#include <math.h>

#define BB 2
#define SS 4096
#define DD 768
#define HH 12
#define DHH 64
#define WW 256
#define CC 16
#define FF 3072

typedef __attribute__((ext_vector_type(8))) short bf16x8;
typedef __attribute__((ext_vector_type(4))) float f32x4;

struct TP12 { const float* s[12]; unsigned short* d[12]; };
struct TP4  { const float* s[4];  unsigned short* d[4];  };

// gelu(x) = 0.5x(1+tanh(u)) = x * sigmoid(2u), u = 0.79788456(x + 0.044715 x^3)
__device__ __forceinline__ float gelu_f(float x) {
    float u = 0.7978845608028654f * fmaf(0.044715f * x * x, x, x);
    return x / (1.f + __expf(-2.f * u));
}

__device__ __forceinline__ unsigned short bfb(float f) {
    __hip_bfloat16 h = __float2bfloat16(f);
    return *(unsigned short*)&h;
}

__device__ __forceinline__ float bf2f(unsigned short u) {
    return __uint_as_float(((unsigned int)u) << 16);
}

__device__ __forceinline__ void gload16(const void* g, void* l) {
    __builtin_amdgcn_global_load_lds(
        (const __attribute__((address_space(1))) unsigned int*)g,
        (__attribute__((address_space(3))) unsigned int*)l, 16, 0, 0);
}

// ---------------- fused weight transposes: fp32 [K][N] -> bf16 [N][K] ----------------
__global__ __launch_bounds__(256) void transpose12_k(TP12 p)
{
    __shared__ float t[32][33];
    int z = blockIdx.z;
    const float* Wsrc = p.s[z];
    unsigned short* Wt = p.d[z];
    const int K = DD, N = DD;
    int n0 = blockIdx.x * 32, k0 = blockIdx.y * 32;
    int tx = threadIdx.x & 31, ty = threadIdx.x >> 5;
#pragma unroll
    for (int i = 0; i < 32; i += 8)
        t[ty + i][tx] = Wsrc[(size_t)(k0 + ty + i) * N + n0 + tx];
    __syncthreads();
#pragma unroll
    for (int i = 0; i < 32; i += 8)
        Wt[(size_t)(n0 + ty + i) * K + k0 + tx] = bfb(t[tx][ty + i]);
}

__global__ __launch_bounds__(256) void transposeR4_k(TP4 p)
{
    __shared__ float t[32][33];
    int z = blockIdx.z;
    const float* Wsrc = p.s[z];
    unsigned short* Wt = p.d[z];
    int K, N, n0, k0;
    if (z < 2) { K = DD; N = FF; n0 = blockIdx.x * 32; k0 = blockIdx.y * 32; }
    else { K = FF; N = DD; int cell = blockIdx.y * 96 + blockIdx.x;
           n0 = (cell % 24) * 32; k0 = (cell / 24) * 32; }
    int tx = threadIdx.x & 31, ty = threadIdx.x >> 5;
#pragma unroll
    for (int i = 0; i < 32; i += 8)
        t[ty + i][tx] = Wsrc[(size_t)(k0 + ty + i) * N + n0 + tx];
    __syncthreads();
#pragma unroll
    for (int i = 0; i < 32; i += 8)
        Wt[(size_t)(n0 + ty + i) * K + k0 + tx] = bfb(t[tx][ty + i]);
}

// ---------------- pack 5 bias vectors [2][768] each -> [2][3840] ----------------
__global__ __launch_bounds__(256) void pack_bias5_k(const float* __restrict__ b0,
        const float* __restrict__ b1, const float* __restrict__ b2,
        const float* __restrict__ b3, const float* __restrict__ b4,
        float* __restrict__ dst)
{
    int gid = blockIdx.x * 256 + threadIdx.x;
    if (gid >= 2 * 5 * DD) return;
    int l = gid / (5 * DD), r = gid % (5 * DD), seg = r / DD, i = r % DD;
    const float* srcs[5] = { b0, b1, b2, b3, b4 };
    dst[gid] = srcs[seg][l * DD + i];
}

// ---------------- embedding + LayerNorm (float4 + shfl reduce, 1 barrier) ----------------
__global__ __launch_bounds__(256) void embed_ln_k(const int* __restrict__ ids,
        const float* __restrict__ wemb, const float* __restrict__ pemb,
        const float* __restrict__ g, const float* __restrict__ bta,
        float* __restrict__ x, unsigned short* __restrict__ xbf)
{
    int row = blockIdx.x;
    int s = row & (SS - 1);
    int tid = threadIdx.x;
    int lane = tid & 63, wvi = tid >> 6;
    __shared__ float red[8];
    float4 v = { 0.f, 0.f, 0.f, 0.f };
    if (tid < 192) {
        const float4* we = (const float4*)(wemb + (size_t)ids[row] * DD);
        const float4* pe = (const float4*)(pemb + (size_t)s * DD);
        float4 a = we[tid], b = pe[tid];
        v.x = a.x + b.x; v.y = a.y + b.y; v.z = a.z + b.z; v.w = a.w + b.w;
    }
    float sum = (v.x + v.y) + (v.z + v.w);
    float sq = fmaf(v.x, v.x, fmaf(v.y, v.y, fmaf(v.z, v.z, v.w * v.w)));
#pragma unroll
    for (int o = 1; o < 64; o <<= 1) {
        sum += __shfl_xor(sum, o);
        sq  += __shfl_xor(sq, o);
    }
    if (lane == 0) { red[wvi] = sum; red[4 + wvi] = sq; }
    __syncthreads();
    float S = (red[0] + red[1]) + (red[2] + red[3]);
    float Q = (red[4] + red[5]) + (red[6] + red[7]);
    float mean = S * (1.f / DD);
    float var = Q * (1.f / DD) - mean * mean;
    float rstd = rsqrtf(var + 1e-5f);
    if (tid < 192) {
        float4 gg = ((const float4*)g)[tid];
        float4 bb = ((const float4*)bta)[tid];
        float4 o;
        o.x = (v.x - mean) * rstd * gg.x + bb.x;
        o.y = (v.y - mean) * rstd * gg.y + bb.y;
        o.z = (v.z - mean) * rstd * gg.z + bb.z;
        o.w = (v.w - mean) * rstd * gg.w + bb.w;
        ((float4*)(x + (size_t)row * DD))[tid] = o;
        ushort4 ob = { bfb(o.x), bfb(o.y), bfb(o.z), bfb(o.w) };
        ((ushort4*)(xbf + (size_t)row * DD))[tid] = ob;
    }
}

// ---------------- residual add + LayerNorm (float4 + shfl reduce) ----------------
__global__ __launch_bounds__(256) void add_ln_k(const float* __restrict__ xin,
        const float* __restrict__ hin, const float* __restrict__ g,
        const float* __restrict__ bta, float* __restrict__ xout,
        unsigned short* __restrict__ xbf)
{
    int row = blockIdx.x;
    int tid = threadIdx.x;
    int lane = tid & 63, wvi = tid >> 6;
    __shared__ float red[8];
    float4 v = { 0.f, 0.f, 0.f, 0.f };
    if (tid < 192) {
        float4 a = ((const float4*)(xin + (size_t)row * DD))[tid];
        float4 b = ((const float4*)(hin + (size_t)row * DD))[tid];
        v.x = a.x + b.x; v.y = a.y + b.y; v.z = a.z + b.z; v.w = a.w + b.w;
    }
    float sum = (v.x + v.y) + (v.z + v.w);
    float sq = fmaf(v.x, v.x, fmaf(v.y, v.y, fmaf(v.z, v.z, v.w * v.w)));
#pragma unroll
    for (int o = 1; o < 64; o <<= 1) {
        sum += __shfl_xor(sum, o);
        sq  += __shfl_xor(sq, o);
    }
    if (lane == 0) { red[wvi] = sum; red[4 + wvi] = sq; }
    __syncthreads();
    float S = (red[0] + red[1]) + (red[2] + red[3]);
    float Q = (red[4] + red[5]) + (red[6] + red[7]);
    float mean = S * (1.f / DD);
    float var = Q * (1.f / DD) - mean * mean;
    float rstd = rsqrtf(var + 1e-5f);
    if (tid < 192) {
        float4 gg = ((const float4*)g)[tid];
        float4 bb = ((const float4*)bta)[tid];
        float4 o;
        o.x = (v.x - mean) * rstd * gg.x + bb.x;
        o.y = (v.y - mean) * rstd * gg.y + bb.y;
        o.z = (v.z - mean) * rstd * gg.z + bb.z;
        o.w = (v.w - mean) * rstd * gg.w + bb.w;
        ((float4*)(xout + (size_t)row * DD))[tid] = o;
        ushort4 ob = { bfb(o.x), bfb(o.y), bfb(o.z), bfb(o.w) };
        ((ushort4*)(xbf + (size_t)row * DD))[tid] = ob;
    }
}

// ---------------- bf16 MFMA GEMM, BK=64, XOR-swizzled LDS, bn-fast L2 tiling,
// double-buffered pipeline: stage(t+1) issued before compute(t), 1 barrier/iter ----------------
template<int OUT_BF16, int ACT_GELU>
__global__ __launch_bounds__(256) void mfma_gemm_k(
        const unsigned short* __restrict__ A,
        const unsigned short* __restrict__ Bt,
        const float* __restrict__ bias,
        void* __restrict__ Cv, int M, int N, int K)
{
    __shared__ short As[2 * 128 * 64];   // 32 KB dbuf
    __shared__ short Bs[2 * 128 * 64];   // 32 KB dbuf
    const int tid = threadIdx.x;
    const int lane = tid & 63, wv = tid >> 6;
    // XCD-aware bijective swizzle (all grids have nwg % 8 == 0)
    int nbx = gridDim.x;
    int nby = gridDim.y;
    int nwg = nbx * nby;
    int lid = blockIdx.y * nbx + blockIdx.x;
    int nid = ((nwg & 7) == 0) ? ((lid & 7) * (nwg >> 3) + (lid >> 3)) : lid;
    const int bm = (nid / nby) * 128, bn = (nid % nby) * 128;   // bn fastest
    const int wm = wv >> 1, wn = wv & 1;

    const int srow0 = (tid * 16) >> 7;          // 0..31
    const int sbc   = (tid * 16) & 127;
    const int srcc  = sbc ^ ((srow0 & 7) << 4); // pre-swizzled source byte col
    const int ldst  = tid * 16;
    const char* Ab = (const char*)(A + (size_t)bm * K);
    const char* Bb = (const char*)(Bt + (size_t)bn * K);

    f32x4 acc[4][4];
#pragma unroll
    for (int i = 0; i < 4; i++)
#pragma unroll
        for (int j = 0; j < 4; j++) acc[i][j] = (f32x4){0.f, 0.f, 0.f, 0.f};

    const int lr = lane & 15;
    const int g = lane >> 4;
    const int rswz = (lr & 7) << 4;
    const int NK = K >> 6;

    auto stage = [&](int ib, int t) {
        const int k0 = t << 6;
        char* Ad = (char*)As + ib * 16384;
        char* Bd = (char*)Bs + ib * 16384;
#pragma unroll
        for (int p = 0; p < 4; p++) {
            size_t roff = (size_t)(srow0 + p * 32) * (K * 2) + (size_t)k0 * 2 + srcc;
            gload16(Ab + roff, Ad + p * 4096 + ldst);
            gload16(Bb + roff, Bd + p * 4096 + ldst);
        }
    };

    // prologue
    stage(0, 0);
    asm volatile("s_waitcnt vmcnt(0)" ::: "memory");
    __builtin_amdgcn_s_barrier();

    int cur = 0;
    for (int t = 0; t < NK; t++) {
        if (t + 1 < NK) stage(cur ^ 1, t + 1);    // loads overlap this tile's compute
        const char* Ar = (const char*)As + cur * 16384;
        const char* Br = (const char*)Bs + cur * 16384;
#pragma unroll
        for (int kk = 0; kk < 2; kk++) {
            int colb = (kk * 64 + g * 16) ^ rswz;
            bf16x8 af[4], bfr[4];
#pragma unroll
            for (int i = 0; i < 4; i++)
                af[i] = *(const bf16x8*)(Ar + (wm * 64 + i * 16 + lr) * 128 + colb);
#pragma unroll
            for (int j = 0; j < 4; j++)
                bfr[j] = *(const bf16x8*)(Br + (wn * 64 + j * 16 + lr) * 128 + colb);
#pragma unroll
            for (int i = 0; i < 4; i++)
#pragma unroll
                for (int j = 0; j < 4; j++)
                    acc[i][j] = __builtin_amdgcn_mfma_f32_16x16x32_bf16(af[i], bfr[j], acc[i][j], 0, 0, 0);
        }
        asm volatile("s_waitcnt vmcnt(0)" ::: "memory");
        __builtin_amdgcn_sched_barrier(0);
        __builtin_amdgcn_s_barrier();
        __builtin_amdgcn_sched_barrier(0);
        cur ^= 1;
    }

    const int rq = lane >> 4;
#pragma unroll
    for (int j = 0; j < 4; j++) {
        int col = bn + wn * 64 + j * 16 + lr;
        float bv = bias[col];
#pragma unroll
        for (int i = 0; i < 4; i++) {
            int rowb = bm + wm * 64 + i * 16 + rq * 4;
#pragma unroll
            for (int r = 0; r < 4; r++) {
                float o = acc[i][j][r] + bv;
                if (ACT_GELU) o = gelu_f(o);
                if (OUT_BF16)
                    ((unsigned short*)Cv)[(size_t)(rowb + r) * N + col] = bfb(o);
                else
                    ((float*)Cv)[(size_t)(rowb + r) * N + col] = o;
            }
        }
    }
}

// ---------------- V head-transpose ----------------
__global__ __launch_bounds__(256) void vtrans_k(const unsigned short* __restrict__ packed,
        unsigned short* __restrict__ vt)
{
    int s0 = blockIdx.x * 64, h = blockIdx.y, b = blockIdx.z;
    int tid = threadIdx.x;
    __shared__ unsigned short t[64][72];
    int r = tid >> 3, dc = (tid & 7) * 8;
#pragma unroll
    for (int half = 0; half < 2; half++) {
        int rr = r + half * 32;
        const unsigned short* src = packed + (size_t)(b * SS + s0 + rr) * 3840 + 2 * DD + h * 64 + dc;
        *(uint4*)&t[rr][dc] = *(const uint4*)src;
    }
    __syncthreads();
    int d = tid >> 3, sc = (tid & 7) * 8;
#pragma unroll
    for (int half = 0; half < 2; half++) {
        int dd2 = d + half * 32;
        unsigned short v[8];
#pragma unroll
        for (int e = 0; e < 8; e++) v[e] = t[sc + e][dd2];
        unsigned short* dst = vt + (size_t)((b * HH + h) * 64 + dd2) * SS + s0 + sc;
        *(uint4*)dst = *(uint4*)v;
    }
}

// ---------------- MFMA sliding-window flash attention (128-q blocks, dbuf pipeline) ----------------
__global__ __launch_bounds__(256) void swin_mfma_k(
        const unsigned short* __restrict__ packed,
        const unsigned short* __restrict__ vt,
        const int* __restrict__ mask,
        unsigned short* __restrict__ O)
{
    __shared__ __align__(16) char smem[52736];
    const int c2 = blockIdx.x, h = blockIdx.y, b = blockIdx.z;
    const int tid = threadIdx.x;
    const int lane = tid & 63, wv = tid >> 6;
    const int l15 = lane & 15, g = lane >> 4;
    const int bh = b * HH + h;
    const int q0 = c2 * 128;

    char* PB = smem + 32768 + wv * 4096;
    float* maskAll = (float*)(smem + 49152);
    float* sA = (float*)(smem + 51712);
    float* sB = (float*)(smem + 52224);

    const char* pk_bytes = (const char*)packed;
    const char* vt_bytes = (const char*)vt;

    bf16x8 qf[2][2];
#pragma unroll
    for (int j = 0; j < 2; j++)
#pragma unroll
        for (int kk = 0; kk < 2; kk++)
            qf[j][kk] = *(const bf16x8*)(packed +
                (size_t)(b * SS + q0 + wv * 32 + j * 16 + l15) * 3840 + h * 64 + kk * 32 + g * 8);
    bf16x8 gkf[2];
#pragma unroll
    for (int kk = 0; kk < 2; kk++)
        gkf[kk] = *(const bf16x8*)(packed + (size_t)(b * SS) * 3840 + DD + h * 64 + kk * 32 + g * 8);
    float v0r[4];
#pragma unroll
    for (int jd = 0; jd < 4; jd++)
        v0r[jd] = bf2f(vt[(size_t)(bh * 64 + jd * 16 + l15) * SS]);

    f32x4 o_[2][4];
#pragma unroll
    for (int i = 0; i < 2; i++)
#pragma unroll
        for (int j = 0; j < 4; j++) o_[i][j] = (f32x4){0.f, 0.f, 0.f, 0.f};
    float m_[2] = { -1e20f, -1e20f };
    float l_[2] = { 0.f, 0.f };

    const int rswz = (l15 & 7) << 4;
    const int kt_s = max(0, 4 - 2 * c2);
    const int kt_e = min(10, 68 - 2 * c2);
    const int lo = wv >> 1;

    auto stage = [&](int ib, int kt) {
        const int kpos0 = q0 - 256 + kt * 64;
        char* KTd = smem + ib * 8192;
        char* VTd = smem + 16384 + ib * 8192;
        int off = tid * 16;
#pragma unroll
        for (int ch = 0; ch < 2; ch++) {
            int o2 = off + ch * 4096;
            int row = o2 >> 7, bc = o2 & 127;
            int srcc = bc ^ ((row & 7) << 4);
            gload16(pk_bytes + (size_t)(b * SS + kpos0 + row) * 7680 + 1536 + h * 128 + srcc,
                    KTd + o2);
            gload16(vt_bytes + (size_t)(bh * 64 + row) * 8192 + (size_t)(kpos0 * 2 + srcc),
                    VTd + o2);
        }
    };

    stage(0, kt_s);
    {
        int span = (kt_e - kt_s) * 64;
        int base_k = q0 - 256 + kt_s * 64;
        for (int idx = tid; idx < span; idx += 256) {
            int kp = base_k + idx;
            maskAll[kt_s * 64 + idx] = (mask[b * SS + kp] > 0) ? 0.f : -1e30f;
        }
    }
    __syncthreads();

    int cur = 0;
    for (int kt = kt_s; kt < kt_e; kt++) {
        if (kt + 1 < kt_e) stage(cur ^ 1, kt + 1);

        const int dl = kt - lo;
        if (dl >= 0 && dl <= 8) {
            const char* KT = smem + cur * 8192;
            const char* VT = smem + 16384 + cur * 8192;
            const bool edge = (dl == 0) || (dl == 8);

            f32x4 mrd[4];
#pragma unroll
            for (int i = 0; i < 4; i++)
                mrd[i] = *(const f32x4*)&maskAll[kt * 64 + i * 16 + g * 4];

            f32x4 s_[4][2];
#pragma unroll
            for (int i = 0; i < 4; i++)
#pragma unroll
                for (int j = 0; j < 2; j++) s_[i][j] = (f32x4){0.f, 0.f, 0.f, 0.f};
            __builtin_amdgcn_s_setprio(1);
#pragma unroll
            for (int kk = 0; kk < 2; kk++) {
                bf16x8 af[4];
#pragma unroll
                for (int i = 0; i < 4; i++)
                    af[i] = *(const bf16x8*)(KT + (i * 16 + l15) * 128 + ((kk * 64 + g * 16) ^ rswz));
#pragma unroll
                for (int i = 0; i < 4; i++)
#pragma unroll
                    for (int j = 0; j < 2; j++)
                        s_[i][j] = __builtin_amdgcn_mfma_f32_16x16x32_bf16(af[i], qf[j][kk], s_[i][j], 0, 0, 0);
            }
            __builtin_amdgcn_s_setprio(0);

#pragma unroll
            for (int j = 0; j < 2; j++) {
                float tm = -1e30f;
                if (edge) {
#pragma unroll
                    for (int i = 0; i < 4; i++) {
#pragma unroll
                        for (int r = 0; r < 4; r++) {
                            float v = fmaf(s_[i][j][r], 0.125f, mrd[i][r]);
                            int rel = kt * 64 - 256 + i * 16 + g * 4 + r - wv * 32 - j * 16 - l15;
                            v = (rel > 256 || rel < -256) ? -1e30f : v;
                            s_[i][j][r] = v;
                            tm = fmaxf(tm, v);
                        }
                    }
                } else {
#pragma unroll
                    for (int i = 0; i < 4; i++) {
#pragma unroll
                        for (int r = 0; r < 4; r++) {
                            float v = fmaf(s_[i][j][r], 0.125f, mrd[i][r]);
                            s_[i][j][r] = v;
                            tm = fmaxf(tm, v);
                        }
                    }
                }
                tm = fmaxf(tm, __shfl_xor(tm, 16));
                tm = fmaxf(tm, __shfl_xor(tm, 32));
                float mn = fmaxf(m_[j], tm);
                float fac = __expf(m_[j] - mn);
                m_[j] = mn;
                float ls = 0.f;
                int q32 = j * 16 + l15;
#pragma unroll
                for (int i = 0; i < 4; i++) {
                    float p0 = __expf(s_[i][j][0] - mn);
                    float p1 = __expf(s_[i][j][1] - mn);
                    float p2 = __expf(s_[i][j][2] - mn);
                    float p3 = __expf(s_[i][j][3] - mn);
                    ls += (p0 + p1) + (p2 + p3);
                    uint2 pw;
                    pw.x = (unsigned int)bfb(p0) | ((unsigned int)bfb(p1) << 16);
                    pw.y = (unsigned int)bfb(p2) | ((unsigned int)bfb(p3) << 16);
                    *(uint2*)(PB + q32 * 128 + ((i * 32 + g * 8) ^ rswz)) = pw;
                }
                ls += __shfl_xor(ls, 16);
                ls += __shfl_xor(ls, 32);
                l_[j] = l_[j] * fac + ls;
                if (g == 0) sA[wv * 32 + q32] = fac;
            }

#pragma unroll
            for (int iq = 0; iq < 2; iq++) {
                f32x4 fc = *(const f32x4*)&sA[wv * 32 + iq * 16 + g * 4];
#pragma unroll
                for (int jd = 0; jd < 4; jd++)
#pragma unroll
                    for (int r = 0; r < 4; r++) o_[iq][jd][r] *= fc[r];
            }
            __builtin_amdgcn_s_setprio(1);
#pragma unroll
            for (int kk = 0; kk < 2; kk++) {
                bf16x8 pa[2], vb[4];
#pragma unroll
                for (int iq = 0; iq < 2; iq++)
                    pa[iq] = *(const bf16x8*)(PB + (iq * 16 + l15) * 128 + ((kk * 64 + g * 16) ^ rswz));
#pragma unroll
                for (int jd = 0; jd < 4; jd++)
                    vb[jd] = *(const bf16x8*)(VT + (jd * 16 + l15) * 128 + ((kk * 64 + g * 16) ^ rswz));
#pragma unroll
                for (int iq = 0; iq < 2; iq++)
#pragma unroll
                    for (int jd = 0; jd < 4; jd++)
                        o_[iq][jd] = __builtin_amdgcn_mfma_f32_16x16x32_bf16(pa[iq], vb[jd], o_[iq][jd], 0, 0, 0);
            }
            __builtin_amdgcn_s_setprio(0);
        }

        asm volatile("s_waitcnt vmcnt(0)" ::: "memory");
        __builtin_amdgcn_sched_barrier(0);
        __builtin_amdgcn_s_barrier();
        __builtin_amdgcn_sched_barrier(0);
        cur ^= 1;
    }

#pragma unroll
    for (int j = 0; j < 2; j++) {
        float pd = 0.f;
#pragma unroll
        for (int kk = 0; kk < 2; kk++)
#pragma unroll
            for (int e = 0; e < 8; e++)
                pd += bf2f((unsigned short)qf[j][kk][e]) * bf2f((unsigned short)gkf[kk][e]);
        pd += __shfl_xor(pd, 16);
        pd += __shfl_xor(pd, 32);
        float sg = pd * 0.125f;
        float mf = fmaxf(m_[j], sg);
        float fac = __expf(m_[j] - mf);
        float pg = __expf(sg - mf);
        float lf = l_[j] * fac + pg;
        float inv = 1.f / lf;
        if (g == 0) {
            sA[wv * 32 + j * 16 + l15] = fac * inv;
            sB[wv * 32 + j * 16 + l15] = pg * inv;
        }
    }
#pragma unroll
    for (int iq = 0; iq < 2; iq++) {
        f32x4 fA = *(const f32x4*)&sA[wv * 32 + iq * 16 + g * 4];
        f32x4 fB = *(const f32x4*)&sB[wv * 32 + iq * 16 + g * 4];
#pragma unroll
        for (int jd = 0; jd < 4; jd++) {
#pragma unroll
            for (int r = 0; r < 4; r++) {
                float val = o_[iq][jd][r] * fA[r] + fB[r] * v0r[jd];
                int row = b * SS + q0 + wv * 32 + iq * 16 + g * 4 + r;
                O[(size_t)row * DD + h * 64 + jd * 16 + l15] = bfb(val);
            }
        }
    }
}

// ---------------- global-token attention, phase 1 ----------------
__global__ __launch_bounds__(256) void gattn1_k(const float* __restrict__ qg,
        const unsigned short* __restrict__ packed, const int* __restrict__ mask,
        float* __restrict__ pm, float* __restrict__ pl, float* __restrict__ po)
{
    int cc = blockIdx.x, h = blockIdx.y, b = blockIdx.z;
    int tid = threadIdx.x;
    __shared__ float qs[64], red[256], ps[256], ored[4][64];
    if (tid < 64) qs[tid] = qg[b * DD + h * 64 + tid];
    __syncthreads();
    int s = cc * 256 + tid;
    const unsigned short* kr = packed + (size_t)(b * SS + s) * 3840 + 3 * DD + h * 64;
    float a = 0.f;
#pragma unroll
    for (int d8 = 0; d8 < 8; d8++) {
        bf16x8 kv = *(const bf16x8*)(kr + d8 * 8);
#pragma unroll
        for (int e = 0; e < 8; e++)
            a = fmaf(qs[d8 * 8 + e], bf2f((unsigned short)kv[e]), a);
    }
    a *= 0.125f;
    float sv = (mask[b * SS + s] > 0) ? a : -1e9f;
    red[tid] = sv; __syncthreads();
    for (int o = 128; o > 0; o >>= 1) {
        if (tid < o) red[tid] = fmaxf(red[tid], red[tid + o]);
        __syncthreads();
    }
    float mx = red[0]; __syncthreads();
    float p = __expf(sv - mx);
    ps[tid] = p;
    red[tid] = p; __syncthreads();
    for (int o = 128; o > 0; o >>= 1) {
        if (tid < o) red[tid] += red[tid + o];
        __syncthreads();
    }
    float ls = red[0];
    int d = tid & 63, grp = tid >> 6;
    const unsigned short* vgb = packed + 4 * DD + h * 64 + d;
    float oa = 0.f;
    for (int t = 0; t < 64; t++) {
        int srow = cc * 256 + grp * 64 + t;
        oa = fmaf(ps[grp * 64 + t], bf2f(vgb[(size_t)(b * SS + srow) * 3840]), oa);
    }
    ored[grp][d] = oa; __syncthreads();
    if (tid < 64) {
        int idx = (b * HH + h) * 16 + cc;
        po[(size_t)idx * 64 + tid] = ored[0][tid] + ored[1][tid] + ored[2][tid] + ored[3][tid];
        if (tid == 0) { pm[idx] = mx; pl[idx] = ls; }
    }
}

// ---------------- global-token attention, phase 2 ----------------
__global__ __launch_bounds__(64) void gattn2_k(const float* __restrict__ pm,
        const float* __restrict__ pl, const float* __restrict__ po,
        unsigned short* __restrict__ O)
{
    int h = blockIdx.x, b = blockIdx.y;
    int tid = threadIdx.x;
    int base = (b * HH + h) * 16;
    float mx = -1e30f;
    for (int c2 = 0; c2 < 16; c2++) mx = fmaxf(mx, pm[base + c2]);
    float den = 0.f, oa = 0.f;
    for (int c2 = 0; c2 < 16; c2++) {
        float w = __expf(pm[base + c2] - mx);
        den = fmaf(pl[base + c2], w, den);
        oa = fmaf(po[(size_t)(base + c2) * 64 + tid], w, oa);
    }
    O[(size_t)(b * SS) * DD + h * 64 + tid] = bfb(oa / den);
}

// ---------------- row-GEMV ----------------
template<int ACT_TANH>
__global__ __launch_bounds__(256) void rowgemv_k(const float* __restrict__ x,
        size_t xstride, const float* __restrict__ W, const float* __restrict__ bias,
        float* __restrict__ dst, int N)
{
    int b = blockIdx.y;
    int colL = threadIdx.x & 63, part = threadIdx.x >> 6;
    int col = blockIdx.x * 64 + colL;
    __shared__ float partial[4][64];
    const float* xr = x + (size_t)b * xstride;
    float a = 0.f;
    for (int k = part * (DD / 4); k < (part + 1) * (DD / 4); k++)
        a = fmaf(xr[k], W[(size_t)k * N + col], a);
    partial[part][colL] = a; __syncthreads();
    if (part == 0) {
        float s = partial[0][colL] + partial[1][colL] + partial[2][colL] + partial[3][colL]
                + bias[col];
        if (ACT_TANH) s = tanhf(s);
        dst[b * N + col] = s;
    }
}

// ---------------- classifier ----------------
__global__ __launch_bounds__(256) void cls_k(const float* __restrict__ pooled,
        const float* __restrict__ Wc, const float* __restrict__ bc,
        float* __restrict__ out)
{
    int lane = threadIdx.x & 63, pair = threadIdx.x >> 6;
    int b = pair >> 1, cls = pair & 1;
    float a = 0.f;
#pragma unroll
    for (int j = 0; j < 12; j++) {
        int k = lane + j * 64;
        a = fmaf(pooled[b * DD + k], Wc[k * 2 + cls], a);
    }
#pragma unroll
    for (int o = 1; o < 64; o <<= 1) a += __shfl_xor(a, o);
    if (lane == 0) out[b * 2 + cls] = a + bc[cls];
}

extern "C" void kernel_launch(void* const* d_in, const int* in_sizes, int n_in,
                              void* d_out, int out_size, void* d_ws, size_t ws_size,
                              hipStream_t stream) {
    const int*   input_ids = (const int*)d_in[0];
    const int*   amask     = (const int*)d_in[1];
    const float* word_emb  = (const float*)d_in[2];
    const float* pos_emb   = (const float*)d_in[3];
    const float* ln_e_g    = (const float*)d_in[4];
    const float* ln_e_b    = (const float*)d_in[5];
    const float* Wq  = (const float*)d_in[6];  const float* bq  = (const float*)d_in[7];
    const float* Wk  = (const float*)d_in[8];  const float* bk  = (const float*)d_in[9];
    const float* Wv  = (const float*)d_in[10]; const float* bv  = (const float*)d_in[11];
    const float* Wqg = (const float*)d_in[12]; const float* bqg = (const float*)d_in[13];
    const float* Wkg = (const float*)d_in[14]; const float* bkg = (const float*)d_in[15];
    const float* Wvg = (const float*)d_in[16]; const float* bvg = (const float*)d_in[17];
    const float* Wo  = (const float*)d_in[18]; const float* bo  = (const float*)d_in[19];
    const float* ln1_g = (const float*)d_in[20]; const float* ln1_b = (const float*)d_in[21];
    const float* W1  = (const float*)d_in[22]; const float* bf1 = (const float*)d_in[23];
    const float* W2  = (const float*)d_in[24]; const float* bf2 = (const float*)d_in[25];
    const float* ln2_g = (const float*)d_in[26]; const float* ln2_b = (const float*)d_in[27];
    const float* Wp  = (const float*)d_in[28]; const float* bp  = (const float*)d_in[29];
    const float* Wc  = (const float*)d_in[30]; const float* bc  = (const float*)d_in[31];
    float* out = (float*)d_out;

    char* wsb = (char*)d_ws;
    float*          x      = (float*)(wsb + 0);
    unsigned short* xbf    = (unsigned short*)(wsb + 25165824);
    unsigned short* packed = (unsigned short*)(wsb + 37748736);
    unsigned short* vtb    = (unsigned short*)(wsb + 100663296);
    unsigned short* aout   = (unsigned short*)(wsb + 113246208);
    float*          hf     = (float*)(wsb + 125829120);
    char*           wts    = wsb + 150994944;
    float*          b5     = (float*)(wsb + 184025088);
    float*          qg     = (float*)(wsb + 184055808);
    float*          pm     = (float*)(wsb + 184061952);
    float*          pl     = (float*)(wsb + 184063488);
    float*          po     = (float*)(wsb + 184065024);
    float*          pooled = (float*)(wsb + 184163328);
    unsigned short* mid    = packed;

    const size_t SQ = (size_t)DD * DD;
    const size_t PER_L = (6 * SQ + 2 * (size_t)DD * FF) * 2;
    unsigned short* Wt5[2], *Wo_t[2], *W1_t[2], *W2_t[2];
    for (int l = 0; l < 2; l++) {
        char* base = wts + (size_t)l * PER_L;
        Wt5[l]  = (unsigned short*)base;
        Wo_t[l] = (unsigned short*)(base + 5 * SQ * 2);
        W1_t[l] = (unsigned short*)(base + 6 * SQ * 2);
        W2_t[l] = (unsigned short*)(base + 6 * SQ * 2 + (size_t)DD * FF * 2);
    }

    const int M = BB * SS;

    TP12 t12;
    for (int l = 0; l < 2; l++) {
        t12.s[l * 6 + 0] = Wq  + (size_t)l * SQ;  t12.d[l * 6 + 0] = Wt5[l] + 0 * SQ;
        t12.s[l * 6 + 1] = Wk  + (size_t)l * SQ;  t12.d[l * 6 + 1] = Wt5[l] + 1 * SQ;
        t12.s[l * 6 + 2] = Wv  + (size_t)l * SQ;  t12.d[l * 6 + 2] = Wt5[l] + 2 * SQ;
        t12.s[l * 6 + 3] = Wkg + (size_t)l * SQ;  t12.d[l * 6 + 3] = Wt5[l] + 3 * SQ;
        t12.s[l * 6 + 4] = Wvg + (size_t)l * SQ;  t12.d[l * 6 + 4] = Wt5[l] + 4 * SQ;
        t12.s[l * 6 + 5] = Wo  + (size_t)l * SQ;  t12.d[l * 6 + 5] = Wo_t[l];
    }
    TP4 t4;
    t4.s[0] = W1;                      t4.d[0] = W1_t[0];
    t4.s[1] = W1 + (size_t)DD * FF;    t4.d[1] = W1_t[1];
    t4.s[2] = W2;                      t4.d[2] = W2_t[0];
    t4.s[3] = W2 + (size_t)FF * DD;    t4.d[3] = W2_t[1];

    transpose12_k<<<dim3(24, 24, 12), 256, 0, stream>>>(t12);
    transposeR4_k<<<dim3(96, 24, 4), 256, 0, stream>>>(t4);
    pack_bias5_k<<<(2 * 5 * DD + 255) / 256, 256, 0, stream>>>(bq, bk, bv, bkg, bvg, b5);

    embed_ln_k<<<M, 256, 0, stream>>>(input_ids, word_emb, pos_emb, ln_e_g, ln_e_b, x, xbf);

    dim3 gqkv(M / 128, 3840 / 128);
    dim3 g768(M / 128, DD / 128);
    dim3 g3072(M / 128, FF / 128);

    for (int l = 0; l < 2; l++) {
        const float* Wqg_l = Wqg + (size_t)l * SQ; const float* bqg_l = bqg + (size_t)l * DD;
        const float* bo_l  = bo  + (size_t)l * DD;
        const float* bf1_l = bf1 + (size_t)l * FF;
        const float* bf2_l = bf2 + (size_t)l * DD;
        const float* g1_l  = ln1_g + (size_t)l * DD; const float* b1_l = ln1_b + (size_t)l * DD;
        const float* g2_l  = ln2_g + (size_t)l * DD; const float* b2_l = ln2_b + (size_t)l * DD;

        mfma_gemm_k<1, 0><<<gqkv, 256, 0, stream>>>(xbf, Wt5[l], b5 + (size_t)l * 3840,
                                                    packed, M, 3840, DD);
        vtrans_k<<<dim3(SS / 64, HH, BB), 256, 0, stream>>>(packed, vtb);
        rowgemv_k<0><<<dim3(DD / 64, BB), 256, 0, stream>>>(x, (size_t)SS * DD, Wqg_l, bqg_l, qg, DD);

        swin_mfma_k<<<dim3(SS / 128, HH, BB), 256, 0, stream>>>(packed, vtb, amask, aout);
        gattn1_k<<<dim3(16, HH, BB), 256, 0, stream>>>(qg, packed, amask, pm, pl, po);
        gattn2_k<<<dim3(HH, BB), 64, 0, stream>>>(pm, pl, po, aout);

        mfma_gemm_k<0, 0><<<g768, 256, 0, stream>>>(aout, Wo_t[l], bo_l, hf, M, DD, DD);
        add_ln_k<<<M, 256, 0, stream>>>(x, hf, g1_l, b1_l, x, xbf);

        mfma_gemm_k<1, 1><<<g3072, 256, 0, stream>>>(xbf, W1_t[l], bf1_l, mid, M, FF, DD);
        mfma_gemm_k<0, 0><<<g768, 256, 0, stream>>>(mid, W2_t[l], bf2_l, hf, M, DD, FF);
        add_ln_k<<<M, 256, 0, stream>>>(x, hf, g2_l, b2_l, x, xbf);
    }

    rowgemv_k<1><<<dim3(DD / 64, BB), 256, 0, stream>>>(x, (size_t)SS * DD, Wp, bp, pooled, DD);
    cls_k<<<1, 256, 0, stream>>>(pooled, Wc, bc, out);
}

// Round 12
// 682.228 us; speedup vs baseline: 8.6743x; 1.0059x over previous
//
#include <hip/hip_runtime.h>
#include <hip/hip_bf16.h>
#include <math.h>

#define BB 2
#define SS 4096
#define DD 768
#define HH 12
#define DHH 64
#define WW 256
#define CC 16
#define FF 3072

typedef __attribute__((ext_vector_type(8))) short bf16x8;
typedef __attribute__((ext_vector_type(4))) float f32x4;

struct TP12 { const float* s[12]; unsigned short* d[12]; };
struct TP4  { const float* s[4];  unsigned short* d[4];  };

// gelu(x) = 0.5x(1+tanh(u)) = x * sigmoid(2u), u = 0.79788456(x + 0.044715 x^3)
__device__ __forceinline__ float gelu_f(float x) {
    float u = 0.7978845608028654f * fmaf(0.044715f * x * x, x, x);
    return x / (1.f + __expf(-2.f * u));
}

__device__ __forceinline__ unsigned short bfb(float f) {
    __hip_bfloat16 h = __float2bfloat16(f);
    return *(unsigned short*)&h;
}

__device__ __forceinline__ float bf2f(unsigned short u) {
    return __uint_as_float(((unsigned int)u) << 16);
}

__device__ __forceinline__ void gload16(const void* g, void* l) {
    __builtin_amdgcn_global_load_lds(
        (const __attribute__((address_space(1))) unsigned int*)g,
        (__attribute__((address_space(3))) unsigned int*)l, 16, 0, 0);
}

// ---------------- fused weight transposes: fp32 [K][N] -> bf16 [N][K] ----------------
__global__ __launch_bounds__(256) void transpose12_k(TP12 p)
{
    __shared__ float t[32][33];
    int z = blockIdx.z;
    const float* Wsrc = p.s[z];
    unsigned short* Wt = p.d[z];
    const int K = DD, N = DD;
    int n0 = blockIdx.x * 32, k0 = blockIdx.y * 32;
    int tx = threadIdx.x & 31, ty = threadIdx.x >> 5;
#pragma unroll
    for (int i = 0; i < 32; i += 8)
        t[ty + i][tx] = Wsrc[(size_t)(k0 + ty + i) * N + n0 + tx];
    __syncthreads();
#pragma unroll
    for (int i = 0; i < 32; i += 8)
        Wt[(size_t)(n0 + ty + i) * K + k0 + tx] = bfb(t[tx][ty + i]);
}

__global__ __launch_bounds__(256) void transposeR4_k(TP4 p)
{
    __shared__ float t[32][33];
    int z = blockIdx.z;
    const float* Wsrc = p.s[z];
    unsigned short* Wt = p.d[z];
    int K, N, n0, k0;
    if (z < 2) { K = DD; N = FF; n0 = blockIdx.x * 32; k0 = blockIdx.y * 32; }
    else { K = FF; N = DD; int cell = blockIdx.y * 96 + blockIdx.x;
           n0 = (cell % 24) * 32; k0 = (cell / 24) * 32; }
    int tx = threadIdx.x & 31, ty = threadIdx.x >> 5;
#pragma unroll
    for (int i = 0; i < 32; i += 8)
        t[ty + i][tx] = Wsrc[(size_t)(k0 + ty + i) * N + n0 + tx];
    __syncthreads();
#pragma unroll
    for (int i = 0; i < 32; i += 8)
        Wt[(size_t)(n0 + ty + i) * K + k0 + tx] = bfb(t[tx][ty + i]);
}

// ---------------- pack 5 bias vectors [2][768] each -> [2][3840] ----------------
__global__ __launch_bounds__(256) void pack_bias5_k(const float* __restrict__ b0,
        const float* __restrict__ b1, const float* __restrict__ b2,
        const float* __restrict__ b3, const float* __restrict__ b4,
        float* __restrict__ dst)
{
    int gid = blockIdx.x * 256 + threadIdx.x;
    if (gid >= 2 * 5 * DD) return;
    int l = gid / (5 * DD), r = gid % (5 * DD), seg = r / DD, i = r % DD;
    const float* srcs[5] = { b0, b1, b2, b3, b4 };
    dst[gid] = srcs[seg][l * DD + i];
}

// ---------------- embedding + LayerNorm (float4 + shfl reduce, 1 barrier) ----------------
__global__ __launch_bounds__(256) void embed_ln_k(const int* __restrict__ ids,
        const float* __restrict__ wemb, const float* __restrict__ pemb,
        const float* __restrict__ g, const float* __restrict__ bta,
        float* __restrict__ x, unsigned short* __restrict__ xbf)
{
    int row = blockIdx.x;
    int s = row & (SS - 1);
    int tid = threadIdx.x;
    int lane = tid & 63, wvi = tid >> 6;
    __shared__ float red[8];
    float4 v = { 0.f, 0.f, 0.f, 0.f };
    if (tid < 192) {
        const float4* we = (const float4*)(wemb + (size_t)ids[row] * DD);
        const float4* pe = (const float4*)(pemb + (size_t)s * DD);
        float4 a = we[tid], b = pe[tid];
        v.x = a.x + b.x; v.y = a.y + b.y; v.z = a.z + b.z; v.w = a.w + b.w;
    }
    float sum = (v.x + v.y) + (v.z + v.w);
    float sq = fmaf(v.x, v.x, fmaf(v.y, v.y, fmaf(v.z, v.z, v.w * v.w)));
#pragma unroll
    for (int o = 1; o < 64; o <<= 1) {
        sum += __shfl_xor(sum, o);
        sq  += __shfl_xor(sq, o);
    }
    if (lane == 0) { red[wvi] = sum; red[4 + wvi] = sq; }
    __syncthreads();
    float S = (red[0] + red[1]) + (red[2] + red[3]);
    float Q = (red[4] + red[5]) + (red[6] + red[7]);
    float mean = S * (1.f / DD);
    float var = Q * (1.f / DD) - mean * mean;
    float rstd = rsqrtf(var + 1e-5f);
    if (tid < 192) {
        float4 gg = ((const float4*)g)[tid];
        float4 bb = ((const float4*)bta)[tid];
        float4 o;
        o.x = (v.x - mean) * rstd * gg.x + bb.x;
        o.y = (v.y - mean) * rstd * gg.y + bb.y;
        o.z = (v.z - mean) * rstd * gg.z + bb.z;
        o.w = (v.w - mean) * rstd * gg.w + bb.w;
        ((float4*)(x + (size_t)row * DD))[tid] = o;
        ushort4 ob = { bfb(o.x), bfb(o.y), bfb(o.z), bfb(o.w) };
        ((ushort4*)(xbf + (size_t)row * DD))[tid] = ob;
    }
}

// ---------------- residual add + LayerNorm (float4 + shfl reduce) ----------------
__global__ __launch_bounds__(256) void add_ln_k(const float* __restrict__ xin,
        const float* __restrict__ hin, const float* __restrict__ g,
        const float* __restrict__ bta, float* __restrict__ xout,
        unsigned short* __restrict__ xbf)
{
    int row = blockIdx.x;
    int tid = threadIdx.x;
    int lane = tid & 63, wvi = tid >> 6;
    __shared__ float red[8];
    float4 v = { 0.f, 0.f, 0.f, 0.f };
    if (tid < 192) {
        float4 a = ((const float4*)(xin + (size_t)row * DD))[tid];
        float4 b = ((const float4*)(hin + (size_t)row * DD))[tid];
        v.x = a.x + b.x; v.y = a.y + b.y; v.z = a.z + b.z; v.w = a.w + b.w;
    }
    float sum = (v.x + v.y) + (v.z + v.w);
    float sq = fmaf(v.x, v.x, fmaf(v.y, v.y, fmaf(v.z, v.z, v.w * v.w)));
#pragma unroll
    for (int o = 1; o < 64; o <<= 1) {
        sum += __shfl_xor(sum, o);
        sq  += __shfl_xor(sq, o);
    }
    if (lane == 0) { red[wvi] = sum; red[4 + wvi] = sq; }
    __syncthreads();
    float S = (red[0] + red[1]) + (red[2] + red[3]);
    float Q = (red[4] + red[5]) + (red[6] + red[7]);
    float mean = S * (1.f / DD);
    float var = Q * (1.f / DD) - mean * mean;
    float rstd = rsqrtf(var + 1e-5f);
    if (tid < 192) {
        float4 gg = ((const float4*)g)[tid];
        float4 bb = ((const float4*)bta)[tid];
        float4 o;
        o.x = (v.x - mean) * rstd * gg.x + bb.x;
        o.y = (v.y - mean) * rstd * gg.y + bb.y;
        o.z = (v.z - mean) * rstd * gg.z + bb.z;
        o.w = (v.w - mean) * rstd * gg.w + bb.w;
        ((float4*)(xout + (size_t)row * DD))[tid] = o;
        ushort4 ob = { bfb(o.x), bfb(o.y), bfb(o.z), bfb(o.w) };
        ((ushort4*)(xbf + (size_t)row * DD))[tid] = ob;
    }
}

// ---------------- bf16 MFMA GEMM, BK=64, XOR-swizzled LDS, bn-fast L2 tiling,
// dbuf + COUNTED vmcnt pipeline (T4): per iter stage(t+1) -> vmcnt(8) [tile-t's
// 8 loads done, 8 newest in flight] -> barrier -> compute(t) -> barrier (WAR). ----------------
template<int OUT_BF16, int ACT_GELU>
__global__ __launch_bounds__(256) void mfma_gemm_k(
        const unsigned short* __restrict__ A,
        const unsigned short* __restrict__ Bt,
        const float* __restrict__ bias,
        void* __restrict__ Cv, int M, int N, int K)
{
    __shared__ short As[2 * 128 * 64];   // 32 KB dbuf
    __shared__ short Bs[2 * 128 * 64];   // 32 KB dbuf
    const int tid = threadIdx.x;
    const int lane = tid & 63, wv = tid >> 6;
    // XCD-aware bijective swizzle (all grids have nwg % 8 == 0)
    int nbx = gridDim.x;
    int nby = gridDim.y;
    int nwg = nbx * nby;
    int lid = blockIdx.y * nbx + blockIdx.x;
    int nid = ((nwg & 7) == 0) ? ((lid & 7) * (nwg >> 3) + (lid >> 3)) : lid;
    const int bm = (nid / nby) * 128, bn = (nid % nby) * 128;   // bn fastest
    const int wm = wv >> 1, wn = wv & 1;

    const int srow0 = (tid * 16) >> 7;          // 0..31
    const int sbc   = (tid * 16) & 127;
    const int srcc  = sbc ^ ((srow0 & 7) << 4); // pre-swizzled source byte col
    const int ldst  = tid * 16;
    const char* Ab = (const char*)(A + (size_t)bm * K);
    const char* Bb = (const char*)(Bt + (size_t)bn * K);

    f32x4 acc[4][4];
#pragma unroll
    for (int i = 0; i < 4; i++)
#pragma unroll
        for (int j = 0; j < 4; j++) acc[i][j] = (f32x4){0.f, 0.f, 0.f, 0.f};

    const int lr = lane & 15;
    const int g = lane >> 4;
    const int rswz = (lr & 7) << 4;
    const int NK = K >> 6;

    auto stage = [&](int ib, int t) {
        const int k0 = t << 6;
        char* Ad = (char*)As + ib * 16384;
        char* Bd = (char*)Bs + ib * 16384;
#pragma unroll
        for (int p = 0; p < 4; p++) {
            size_t roff = (size_t)(srow0 + p * 32) * (K * 2) + (size_t)k0 * 2 + srcc;
            gload16(Ab + roff, Ad + p * 4096 + ldst);
            gload16(Bb + roff, Bd + p * 4096 + ldst);
        }
    };

    // prologue: issue tile 0 only; the wait happens at iter 0's top.
    stage(0, 0);

    int cur = 0;
    for (int t = 0; t < NK; t++) {
        if (t + 1 < NK) {
            stage(cur ^ 1, t + 1);                         // 8 newest loads
            asm volatile("s_waitcnt vmcnt(8)" ::: "memory"); // oldest 8 (tile t) done
        } else {
            asm volatile("s_waitcnt vmcnt(0)" ::: "memory"); // last tile: full drain
        }
        __builtin_amdgcn_sched_barrier(0);
        __builtin_amdgcn_s_barrier();                       // tile t visible to all waves
        __builtin_amdgcn_sched_barrier(0);

        const char* Ar = (const char*)As + cur * 16384;
        const char* Br = (const char*)Bs + cur * 16384;
#pragma unroll
        for (int kk = 0; kk < 2; kk++) {
            int colb = (kk * 64 + g * 16) ^ rswz;
            bf16x8 af[4], bfr[4];
#pragma unroll
            for (int i = 0; i < 4; i++)
                af[i] = *(const bf16x8*)(Ar + (wm * 64 + i * 16 + lr) * 128 + colb);
#pragma unroll
            for (int j = 0; j < 4; j++)
                bfr[j] = *(const bf16x8*)(Br + (wn * 64 + j * 16 + lr) * 128 + colb);
#pragma unroll
            for (int i = 0; i < 4; i++)
#pragma unroll
                for (int j = 0; j < 4; j++)
                    acc[i][j] = __builtin_amdgcn_mfma_f32_16x16x32_bf16(af[i], bfr[j], acc[i][j], 0, 0, 0);
        }
        __builtin_amdgcn_sched_barrier(0);
        __builtin_amdgcn_s_barrier();                       // WAR: done reading buf cur
        cur ^= 1;
    }

    const int rq = lane >> 4;
#pragma unroll
    for (int j = 0; j < 4; j++) {
        int col = bn + wn * 64 + j * 16 + lr;
        float bv = bias[col];
#pragma unroll
        for (int i = 0; i < 4; i++) {
            int rowb = bm + wm * 64 + i * 16 + rq * 4;
#pragma unroll
            for (int r = 0; r < 4; r++) {
                float o = acc[i][j][r] + bv;
                if (ACT_GELU) o = gelu_f(o);
                if (OUT_BF16)
                    ((unsigned short*)Cv)[(size_t)(rowb + r) * N + col] = bfb(o);
                else
                    ((float*)Cv)[(size_t)(rowb + r) * N + col] = o;
            }
        }
    }
}

// ---------------- V head-transpose ----------------
__global__ __launch_bounds__(256) void vtrans_k(const unsigned short* __restrict__ packed,
        unsigned short* __restrict__ vt)
{
    int s0 = blockIdx.x * 64, h = blockIdx.y, b = blockIdx.z;
    int tid = threadIdx.x;
    __shared__ unsigned short t[64][72];
    int r = tid >> 3, dc = (tid & 7) * 8;
#pragma unroll
    for (int half = 0; half < 2; half++) {
        int rr = r + half * 32;
        const unsigned short* src = packed + (size_t)(b * SS + s0 + rr) * 3840 + 2 * DD + h * 64 + dc;
        *(uint4*)&t[rr][dc] = *(const uint4*)src;
    }
    __syncthreads();
    int d = tid >> 3, sc = (tid & 7) * 8;
#pragma unroll
    for (int half = 0; half < 2; half++) {
        int dd2 = d + half * 32;
        unsigned short v[8];
#pragma unroll
        for (int e = 0; e < 8; e++) v[e] = t[sc + e][dd2];
        unsigned short* dst = vt + (size_t)((b * HH + h) * 64 + dd2) * SS + s0 + sc;
        *(uint4*)dst = *(uint4*)v;
    }
}

// ---------------- MFMA sliding-window flash attention (128-q blocks, dbuf pipeline) ----------------
__global__ __launch_bounds__(256) void swin_mfma_k(
        const unsigned short* __restrict__ packed,
        const unsigned short* __restrict__ vt,
        const int* __restrict__ mask,
        unsigned short* __restrict__ O)
{
    __shared__ __align__(16) char smem[52736];
    const int c2 = blockIdx.x, h = blockIdx.y, b = blockIdx.z;
    const int tid = threadIdx.x;
    const int lane = tid & 63, wv = tid >> 6;
    const int l15 = lane & 15, g = lane >> 4;
    const int bh = b * HH + h;
    const int q0 = c2 * 128;

    char* PB = smem + 32768 + wv * 4096;
    float* maskAll = (float*)(smem + 49152);
    float* sA = (float*)(smem + 51712);
    float* sB = (float*)(smem + 52224);

    const char* pk_bytes = (const char*)packed;
    const char* vt_bytes = (const char*)vt;

    bf16x8 qf[2][2];
#pragma unroll
    for (int j = 0; j < 2; j++)
#pragma unroll
        for (int kk = 0; kk < 2; kk++)
            qf[j][kk] = *(const bf16x8*)(packed +
                (size_t)(b * SS + q0 + wv * 32 + j * 16 + l15) * 3840 + h * 64 + kk * 32 + g * 8);
    bf16x8 gkf[2];
#pragma unroll
    for (int kk = 0; kk < 2; kk++)
        gkf[kk] = *(const bf16x8*)(packed + (size_t)(b * SS) * 3840 + DD + h * 64 + kk * 32 + g * 8);
    float v0r[4];
#pragma unroll
    for (int jd = 0; jd < 4; jd++)
        v0r[jd] = bf2f(vt[(size_t)(bh * 64 + jd * 16 + l15) * SS]);

    f32x4 o_[2][4];
#pragma unroll
    for (int i = 0; i < 2; i++)
#pragma unroll
        for (int j = 0; j < 4; j++) o_[i][j] = (f32x4){0.f, 0.f, 0.f, 0.f};
    float m_[2] = { -1e20f, -1e20f };
    float l_[2] = { 0.f, 0.f };

    const int rswz = (l15 & 7) << 4;
    const int kt_s = max(0, 4 - 2 * c2);
    const int kt_e = min(10, 68 - 2 * c2);
    const int lo = wv >> 1;

    auto stage = [&](int ib, int kt) {
        const int kpos0 = q0 - 256 + kt * 64;
        char* KTd = smem + ib * 8192;
        char* VTd = smem + 16384 + ib * 8192;
        int off = tid * 16;
#pragma unroll
        for (int ch = 0; ch < 2; ch++) {
            int o2 = off + ch * 4096;
            int row = o2 >> 7, bc = o2 & 127;
            int srcc = bc ^ ((row & 7) << 4);
            gload16(pk_bytes + (size_t)(b * SS + kpos0 + row) * 7680 + 1536 + h * 128 + srcc,
                    KTd + o2);
            gload16(vt_bytes + (size_t)(bh * 64 + row) * 8192 + (size_t)(kpos0 * 2 + srcc),
                    VTd + o2);
        }
    };

    stage(0, kt_s);
    {
        int span = (kt_e - kt_s) * 64;
        int base_k = q0 - 256 + kt_s * 64;
        for (int idx = tid; idx < span; idx += 256) {
            int kp = base_k + idx;
            maskAll[kt_s * 64 + idx] = (mask[b * SS + kp] > 0) ? 0.f : -1e30f;
        }
    }
    __syncthreads();

    int cur = 0;
    for (int kt = kt_s; kt < kt_e; kt++) {
        if (kt + 1 < kt_e) stage(cur ^ 1, kt + 1);

        const int dl = kt - lo;
        if (dl >= 0 && dl <= 8) {
            const char* KT = smem + cur * 8192;
            const char* VT = smem + 16384 + cur * 8192;
            const bool edge = (dl == 0) || (dl == 8);

            f32x4 mrd[4];
#pragma unroll
            for (int i = 0; i < 4; i++)
                mrd[i] = *(const f32x4*)&maskAll[kt * 64 + i * 16 + g * 4];

            f32x4 s_[4][2];
#pragma unroll
            for (int i = 0; i < 4; i++)
#pragma unroll
                for (int j = 0; j < 2; j++) s_[i][j] = (f32x4){0.f, 0.f, 0.f, 0.f};
            __builtin_amdgcn_s_setprio(1);
#pragma unroll
            for (int kk = 0; kk < 2; kk++) {
                bf16x8 af[4];
#pragma unroll
                for (int i = 0; i < 4; i++)
                    af[i] = *(const bf16x8*)(KT + (i * 16 + l15) * 128 + ((kk * 64 + g * 16) ^ rswz));
#pragma unroll
                for (int i = 0; i < 4; i++)
#pragma unroll
                    for (int j = 0; j < 2; j++)
                        s_[i][j] = __builtin_amdgcn_mfma_f32_16x16x32_bf16(af[i], qf[j][kk], s_[i][j], 0, 0, 0);
            }
            __builtin_amdgcn_s_setprio(0);

#pragma unroll
            for (int j = 0; j < 2; j++) {
                float tm = -1e30f;
                if (edge) {
#pragma unroll
                    for (int i = 0; i < 4; i++) {
#pragma unroll
                        for (int r = 0; r < 4; r++) {
                            float v = fmaf(s_[i][j][r], 0.125f, mrd[i][r]);
                            int rel = kt * 64 - 256 + i * 16 + g * 4 + r - wv * 32 - j * 16 - l15;
                            v = (rel > 256 || rel < -256) ? -1e30f : v;
                            s_[i][j][r] = v;
                            tm = fmaxf(tm, v);
                        }
                    }
                } else {
#pragma unroll
                    for (int i = 0; i < 4; i++) {
#pragma unroll
                        for (int r = 0; r < 4; r++) {
                            float v = fmaf(s_[i][j][r], 0.125f, mrd[i][r]);
                            s_[i][j][r] = v;
                            tm = fmaxf(tm, v);
                        }
                    }
                }
                tm = fmaxf(tm, __shfl_xor(tm, 16));
                tm = fmaxf(tm, __shfl_xor(tm, 32));
                float mn = fmaxf(m_[j], tm);
                float fac = __expf(m_[j] - mn);
                m_[j] = mn;
                float ls = 0.f;
                int q32 = j * 16 + l15;
#pragma unroll
                for (int i = 0; i < 4; i++) {
                    float p0 = __expf(s_[i][j][0] - mn);
                    float p1 = __expf(s_[i][j][1] - mn);
                    float p2 = __expf(s_[i][j][2] - mn);
                    float p3 = __expf(s_[i][j][3] - mn);
                    ls += (p0 + p1) + (p2 + p3);
                    uint2 pw;
                    pw.x = (unsigned int)bfb(p0) | ((unsigned int)bfb(p1) << 16);
                    pw.y = (unsigned int)bfb(p2) | ((unsigned int)bfb(p3) << 16);
                    *(uint2*)(PB + q32 * 128 + ((i * 32 + g * 8) ^ rswz)) = pw;
                }
                ls += __shfl_xor(ls, 16);
                ls += __shfl_xor(ls, 32);
                l_[j] = l_[j] * fac + ls;
                if (g == 0) sA[wv * 32 + q32] = fac;
            }

#pragma unroll
            for (int iq = 0; iq < 2; iq++) {
                f32x4 fc = *(const f32x4*)&sA[wv * 32 + iq * 16 + g * 4];
#pragma unroll
                for (int jd = 0; jd < 4; jd++)
#pragma unroll
                    for (int r = 0; r < 4; r++) o_[iq][jd][r] *= fc[r];
            }
            __builtin_amdgcn_s_setprio(1);
#pragma unroll
            for (int kk = 0; kk < 2; kk++) {
                bf16x8 pa[2], vb[4];
#pragma unroll
                for (int iq = 0; iq < 2; iq++)
                    pa[iq] = *(const bf16x8*)(PB + (iq * 16 + l15) * 128 + ((kk * 64 + g * 16) ^ rswz));
#pragma unroll
                for (int jd = 0; jd < 4; jd++)
                    vb[jd] = *(const bf16x8*)(VT + (jd * 16 + l15) * 128 + ((kk * 64 + g * 16) ^ rswz));
#pragma unroll
                for (int iq = 0; iq < 2; iq++)
#pragma unroll
                    for (int jd = 0; jd < 4; jd++)
                        o_[iq][jd] = __builtin_amdgcn_mfma_f32_16x16x32_bf16(pa[iq], vb[jd], o_[iq][jd], 0, 0, 0);
            }
            __builtin_amdgcn_s_setprio(0);
        }

        asm volatile("s_waitcnt vmcnt(0)" ::: "memory");
        __builtin_amdgcn_sched_barrier(0);
        __builtin_amdgcn_s_barrier();
        __builtin_amdgcn_sched_barrier(0);
        cur ^= 1;
    }

#pragma unroll
    for (int j = 0; j < 2; j++) {
        float pd = 0.f;
#pragma unroll
        for (int kk = 0; kk < 2; kk++)
#pragma unroll
            for (int e = 0; e < 8; e++)
                pd += bf2f((unsigned short)qf[j][kk][e]) * bf2f((unsigned short)gkf[kk][e]);
        pd += __shfl_xor(pd, 16);
        pd += __shfl_xor(pd, 32);
        float sg = pd * 0.125f;
        float mf = fmaxf(m_[j], sg);
        float fac = __expf(m_[j] - mf);
        float pg = __expf(sg - mf);
        float lf = l_[j] * fac + pg;
        float inv = 1.f / lf;
        if (g == 0) {
            sA[wv * 32 + j * 16 + l15] = fac * inv;
            sB[wv * 32 + j * 16 + l15] = pg * inv;
        }
    }
#pragma unroll
    for (int iq = 0; iq < 2; iq++) {
        f32x4 fA = *(const f32x4*)&sA[wv * 32 + iq * 16 + g * 4];
        f32x4 fB = *(const f32x4*)&sB[wv * 32 + iq * 16 + g * 4];
#pragma unroll
        for (int jd = 0; jd < 4; jd++) {
#pragma unroll
            for (int r = 0; r < 4; r++) {
                float val = o_[iq][jd][r] * fA[r] + fB[r] * v0r[jd];
                int row = b * SS + q0 + wv * 32 + iq * 16 + g * 4 + r;
                O[(size_t)row * DD + h * 64 + jd * 16 + l15] = bfb(val);
            }
        }
    }
}

// ---------------- global-token attention, phase 1 ----------------
__global__ __launch_bounds__(256) void gattn1_k(const float* __restrict__ qg,
        const unsigned short* __restrict__ packed, const int* __restrict__ mask,
        float* __restrict__ pm, float* __restrict__ pl, float* __restrict__ po)
{
    int cc = blockIdx.x, h = blockIdx.y, b = blockIdx.z;
    int tid = threadIdx.x;
    __shared__ float qs[64], red[256], ps[256], ored[4][64];
    if (tid < 64) qs[tid] = qg[b * DD + h * 64 + tid];
    __syncthreads();
    int s = cc * 256 + tid;
    const unsigned short* kr = packed + (size_t)(b * SS + s) * 3840 + 3 * DD + h * 64;
    float a = 0.f;
#pragma unroll
    for (int d8 = 0; d8 < 8; d8++) {
        bf16x8 kv = *(const bf16x8*)(kr + d8 * 8);
#pragma unroll
        for (int e = 0; e < 8; e++)
            a = fmaf(qs[d8 * 8 + e], bf2f((unsigned short)kv[e]), a);
    }
    a *= 0.125f;
    float sv = (mask[b * SS + s] > 0) ? a : -1e9f;
    red[tid] = sv; __syncthreads();
    for (int o = 128; o > 0; o >>= 1) {
        if (tid < o) red[tid] = fmaxf(red[tid], red[tid + o]);
        __syncthreads();
    }
    float mx = red[0]; __syncthreads();
    float p = __expf(sv - mx);
    ps[tid] = p;
    red[tid] = p; __syncthreads();
    for (int o = 128; o > 0; o >>= 1) {
        if (tid < o) red[tid] += red[tid + o];
        __syncthreads();
    }
    float ls = red[0];
    int d = tid & 63, grp = tid >> 6;
    const unsigned short* vgb = packed + 4 * DD + h * 64 + d;
    float oa = 0.f;
    for (int t = 0; t < 64; t++) {
        int srow = cc * 256 + grp * 64 + t;
        oa = fmaf(ps[grp * 64 + t], bf2f(vgb[(size_t)(b * SS + srow) * 3840]), oa);
    }
    ored[grp][d] = oa; __syncthreads();
    if (tid < 64) {
        int idx = (b * HH + h) * 16 + cc;
        po[(size_t)idx * 64 + tid] = ored[0][tid] + ored[1][tid] + ored[2][tid] + ored[3][tid];
        if (tid == 0) { pm[idx] = mx; pl[idx] = ls; }
    }
}

// ---------------- global-token attention, phase 2 ----------------
__global__ __launch_bounds__(64) void gattn2_k(const float* __restrict__ pm,
        const float* __restrict__ pl, const float* __restrict__ po,
        unsigned short* __restrict__ O)
{
    int h = blockIdx.x, b = blockIdx.y;
    int tid = threadIdx.x;
    int base = (b * HH + h) * 16;
    float mx = -1e30f;
    for (int c2 = 0; c2 < 16; c2++) mx = fmaxf(mx, pm[base + c2]);
    float den = 0.f, oa = 0.f;
    for (int c2 = 0; c2 < 16; c2++) {
        float w = __expf(pm[base + c2] - mx);
        den = fmaf(pl[base + c2], w, den);
        oa = fmaf(po[(size_t)(base + c2) * 64 + tid], w, oa);
    }
    O[(size_t)(b * SS) * DD + h * 64 + tid] = bfb(oa / den);
}

// ---------------- row-GEMV ----------------
template<int ACT_TANH>
__global__ __launch_bounds__(256) void rowgemv_k(const float* __restrict__ x,
        size_t xstride, const float* __restrict__ W, const float* __restrict__ bias,
        float* __restrict__ dst, int N)
{
    int b = blockIdx.y;
    int colL = threadIdx.x & 63, part = threadIdx.x >> 6;
    int col = blockIdx.x * 64 + colL;
    __shared__ float partial[4][64];
    const float* xr = x + (size_t)b * xstride;
    float a = 0.f;
    for (int k = part * (DD / 4); k < (part + 1) * (DD / 4); k++)
        a = fmaf(xr[k], W[(size_t)k * N + col], a);
    partial[part][colL] = a; __syncthreads();
    if (part == 0) {
        float s = partial[0][colL] + partial[1][colL] + partial[2][colL] + partial[3][colL]
                + bias[col];
        if (ACT_TANH) s = tanhf(s);
        dst[b * N + col] = s;
    }
}

// ---------------- classifier ----------------
__global__ __launch_bounds__(256) void cls_k(const float* __restrict__ pooled,
        const float* __restrict__ Wc, const float* __restrict__ bc,
        float* __restrict__ out)
{
    int lane = threadIdx.x & 63, pair = threadIdx.x >> 6;
    int b = pair >> 1, cls = pair & 1;
    float a = 0.f;
#pragma unroll
    for (int j = 0; j < 12; j++) {
        int k = lane + j * 64;
        a = fmaf(pooled[b * DD + k], Wc[k * 2 + cls], a);
    }
#pragma unroll
    for (int o = 1; o < 64; o <<= 1) a += __shfl_xor(a, o);
    if (lane == 0) out[b * 2 + cls] = a + bc[cls];
}

extern "C" void kernel_launch(void* const* d_in, const int* in_sizes, int n_in,
                              void* d_out, int out_size, void* d_ws, size_t ws_size,
                              hipStream_t stream) {
    const int*   input_ids = (const int*)d_in[0];
    const int*   amask     = (const int*)d_in[1];
    const float* word_emb  = (const float*)d_in[2];
    const float* pos_emb   = (const float*)d_in[3];
    const float* ln_e_g    = (const float*)d_in[4];
    const float* ln_e_b    = (const float*)d_in[5];
    const float* Wq  = (const float*)d_in[6];  const float* bq  = (const float*)d_in[7];
    const float* Wk  = (const float*)d_in[8];  const float* bk  = (const float*)d_in[9];
    const float* Wv  = (const float*)d_in[10]; const float* bv  = (const float*)d_in[11];
    const float* Wqg = (const float*)d_in[12]; const float* bqg = (const float*)d_in[13];
    const float* Wkg = (const float*)d_in[14]; const float* bkg = (const float*)d_in[15];
    const float* Wvg = (const float*)d_in[16]; const float* bvg = (const float*)d_in[17];
    const float* Wo  = (const float*)d_in[18]; const float* bo  = (const float*)d_in[19];
    const float* ln1_g = (const float*)d_in[20]; const float* ln1_b = (const float*)d_in[21];
    const float* W1  = (const float*)d_in[22]; const float* bf1 = (const float*)d_in[23];
    const float* W2  = (const float*)d_in[24]; const float* bf2 = (const float*)d_in[25];
    const float* ln2_g = (const float*)d_in[26]; const float* ln2_b = (const float*)d_in[27];
    const float* Wp  = (const float*)d_in[28]; const float* bp  = (const float*)d_in[29];
    const float* Wc  = (const float*)d_in[30]; const float* bc  = (const float*)d_in[31];
    float* out = (float*)d_out;

    char* wsb = (char*)d_ws;
    float*          x      = (float*)(wsb + 0);
    unsigned short* xbf    = (unsigned short*)(wsb + 25165824);
    unsigned short* packed = (unsigned short*)(wsb + 37748736);
    unsigned short* vtb    = (unsigned short*)(wsb + 100663296);
    unsigned short* aout   = (unsigned short*)(wsb + 113246208);
    float*          hf     = (float*)(wsb + 125829120);
    char*           wts    = wsb + 150994944;
    float*          b5     = (float*)(wsb + 184025088);
    float*          qg     = (float*)(wsb + 184055808);
    float*          pm     = (float*)(wsb + 184061952);
    float*          pl     = (float*)(wsb + 184063488);
    float*          po     = (float*)(wsb + 184065024);
    float*          pooled = (float*)(wsb + 184163328);
    unsigned short* mid    = packed;

    const size_t SQ = (size_t)DD * DD;
    const size_t PER_L = (6 * SQ + 2 * (size_t)DD * FF) * 2;
    unsigned short* Wt5[2], *Wo_t[2], *W1_t[2], *W2_t[2];
    for (int l = 0; l < 2; l++) {
        char* base = wts + (size_t)l * PER_L;
        Wt5[l]  = (unsigned short*)base;
        Wo_t[l] = (unsigned short*)(base + 5 * SQ * 2);
        W1_t[l] = (unsigned short*)(base + 6 * SQ * 2);
        W2_t[l] = (unsigned short*)(base + 6 * SQ * 2 + (size_t)DD * FF * 2);
    }

    const int M = BB * SS;

    TP12 t12;
    for (int l = 0; l < 2; l++) {
        t12.s[l * 6 + 0] = Wq  + (size_t)l * SQ;  t12.d[l * 6 + 0] = Wt5[l] + 0 * SQ;
        t12.s[l * 6 + 1] = Wk  + (size_t)l * SQ;  t12.d[l * 6 + 1] = Wt5[l] + 1 * SQ;
        t12.s[l * 6 + 2] = Wv  + (size_t)l * SQ;  t12.d[l * 6 + 2] = Wt5[l] + 2 * SQ;
        t12.s[l * 6 + 3] = Wkg + (size_t)l * SQ;  t12.d[l * 6 + 3] = Wt5[l] + 3 * SQ;
        t12.s[l * 6 + 4] = Wvg + (size_t)l * SQ;  t12.d[l * 6 + 4] = Wt5[l] + 4 * SQ;
        t12.s[l * 6 + 5] = Wo  + (size_t)l * SQ;  t12.d[l * 6 + 5] = Wo_t[l];
    }
    TP4 t4;
    t4.s[0] = W1;                      t4.d[0] = W1_t[0];
    t4.s[1] = W1 + (size_t)DD * FF;    t4.d[1] = W1_t[1];
    t4.s[2] = W2;                      t4.d[2] = W2_t[0];
    t4.s[3] = W2 + (size_t)FF * DD;    t4.d[3] = W2_t[1];

    transpose12_k<<<dim3(24, 24, 12), 256, 0, stream>>>(t12);
    transposeR4_k<<<dim3(96, 24, 4), 256, 0, stream>>>(t4);
    pack_bias5_k<<<(2 * 5 * DD + 255) / 256, 256, 0, stream>>>(bq, bk, bv, bkg, bvg, b5);

    embed_ln_k<<<M, 256, 0, stream>>>(input_ids, word_emb, pos_emb, ln_e_g, ln_e_b, x, xbf);

    dim3 gqkv(M / 128, 3840 / 128);
    dim3 g768(M / 128, DD / 128);
    dim3 g3072(M / 128, FF / 128);

    for (int l = 0; l < 2; l++) {
        const float* Wqg_l = Wqg + (size_t)l * SQ; const float* bqg_l = bqg + (size_t)l * DD;
        const float* bo_l  = bo  + (size_t)l * DD;
        const float* bf1_l = bf1 + (size_t)l * FF;
        const float* bf2_l = bf2 + (size_t)l * DD;
        const float* g1_l  = ln1_g + (size_t)l * DD; const float* b1_l = ln1_b + (size_t)l * DD;
        const float* g2_l  = ln2_g + (size_t)l * DD; const float* b2_l = ln2_b + (size_t)l * DD;

        mfma_gemm_k<1, 0><<<gqkv, 256, 0, stream>>>(xbf, Wt5[l], b5 + (size_t)l * 3840,
                                                    packed, M, 3840, DD);
        vtrans_k<<<dim3(SS / 64, HH, BB), 256, 0, stream>>>(packed, vtb);
        rowgemv_k<0><<<dim3(DD / 64, BB), 256, 0, stream>>>(x, (size_t)SS * DD, Wqg_l, bqg_l, qg, DD);

        swin_mfma_k<<<dim3(SS / 128, HH, BB), 256, 0, stream>>>(packed, vtb, amask, aout);
        gattn1_k<<<dim3(16, HH, BB), 256, 0, stream>>>(qg, packed, amask, pm, pl, po);
        gattn2_k<<<dim3(HH, BB), 64, 0, stream>>>(pm, pl, po, aout);

        mfma_gemm_k<0, 0><<<g768, 256, 0, stream>>>(aout, Wo_t[l], bo_l, hf, M, DD, DD);
        add_ln_k<<<M, 256, 0, stream>>>(x, hf, g1_l, b1_l, x, xbf);

        mfma_gemm_k<1, 1><<<g3072, 256, 0, stream>>>(xbf, W1_t[l], bf1_l, mid, M, FF, DD);
        mfma_gemm_k<0, 0><<<g768, 256, 0, stream>>>(mid, W2_t[l], bf2_l, hf, M, DD, FF);
        add_ln_k<<<M, 256, 0, stream>>>(x, hf, g2_l, b2_l, x, xbf);
    }

    rowgemv_k<1><<<dim3(DD / 64, BB), 256, 0, stream>>>(x, (size_t)SS * DD, Wp, bp, pooled, DD);
    cls_k<<<1, 256, 0, stream>>>(pooled, Wc, bc, out);
}